// Round 1
// baseline (17944.736 us; speedup 1.0000x reference)
//
#include <hip/hip_runtime.h>

static constexpr int TT = 20;     // timesteps
static constexpr int FF = 64;     // input features
static constexpr int HD = 256;    // hidden dim
static constexpr int G4 = 1024;   // 4*HD

enum { ACT_NONE = 0, ACT_RELU = 1, ACT_TANH = 2 };

static __device__ __forceinline__ float sigf(float x) { return 1.f / (1.f + expf(-x)); }

// ---------------- feature-LN stats: rows of 64, one wave per row ----------------
__global__ void k_lnstats(const float* __restrict__ x, float* __restrict__ mu,
                          float* __restrict__ rstd, int rows) {
  int row = blockIdx.x * 4 + (threadIdx.x >> 6);
  int lane = threadIdx.x & 63;
  if (row >= rows) return;
  float v = x[(size_t)row * 64 + lane];
  float s = v, s2 = v * v;
  for (int o = 32; o; o >>= 1) { s += __shfl_xor(s, o); s2 += __shfl_xor(s2, o); }
  if (lane == 0) {
    float m = s * (1.f / 64.f);
    float var = s2 * (1.f / 64.f) - m * m;
    mu[row] = m;
    rstd[row] = rsqrtf(var + 1e-5f);
  }
}

// ---------------- build fused LSTM weights: wcat[k, hd*4+g] = W[g*HD+hd, k] ----------------
__global__ void k_build_wcat(const float* __restrict__ w_ih, const float* __restrict__ w_hh,
                             const float* __restrict__ b_ih, const float* __restrict__ b_hh,
                             float* __restrict__ wcat, float* __restrict__ bcat,
                             int KI, int KH) {
  int ktot = KI + KH;
  int total = ktot * G4;
  for (int idx = blockIdx.x * blockDim.x + threadIdx.x; idx < total;
       idx += gridDim.x * blockDim.x) {
    int k = idx / G4;
    int col = idx % G4;
    int hd = col >> 2, g = col & 3;
    int orow = g * HD + hd;
    float v = (k < KI) ? w_ih[(size_t)orow * KI + k] : w_hh[(size_t)orow * KH + (k - KI)];
    wcat[(size_t)k * G4 + col] = v;
    if (k == 0) bcat[col] = b_ih[orow] + b_hh[orow];
  }
}

// ---------------- fused LSTM step: gates GEMM (M x 1024, K=320/512) + gate epilogue ----------------
template <int LAYER>
__global__ __launch_bounds__(256) void k_lstm_step(
    const float* __restrict__ xs,     // L0: x_stock (N,T,F); L1: h0 current (N,HD)
    const float* __restrict__ mu, const float* __restrict__ rstd,
    const float* __restrict__ lng, const float* __restrict__ lnb,
    const float* __restrict__ hprev,  // (N,HD)
    const float* __restrict__ wcat, const float* __restrict__ bcat,
    float* __restrict__ cstate, float* __restrict__ hnext,
    int M, int t) {
  constexpr int K = (LAYER == 0) ? (FF + HD) : (2 * HD);
  __shared__ float As[16][132];
  __shared__ float Bs[16][68];
  const int tid = threadIdx.x;
  const int tx = tid & 15, ty = tid >> 4;
  const int m0 = blockIdx.x * 128;
  const int n0 = blockIdx.y * 64;
  float acc[8][4] = {};
  for (int k0 = 0; k0 < K; k0 += 16) {
#pragma unroll
    for (int i = 0; i < 8; i++) {
      int idx = i * 256 + tid;
      int mm = idx >> 4, kk = idx & 15;
      int row = m0 + mm, kg = k0 + kk;
      float v = 0.f;
      if (row < M) {
        if (LAYER == 0) {
          if (kg < FF) {
            int r = row * TT + t;
            v = (xs[(size_t)row * (TT * FF) + t * FF + kg] - mu[r]) * rstd[r] * lng[kg] + lnb[kg];
          } else {
            v = hprev[(size_t)row * HD + (kg - FF)];
          }
        } else {
          v = (kg < HD) ? xs[(size_t)row * HD + kg] : hprev[(size_t)row * HD + (kg - HD)];
        }
      }
      As[kk][mm] = v;
    }
#pragma unroll
    for (int i = 0; i < 4; i++) {
      int idx = i * 256 + tid;
      int kk = idx >> 6, nn = idx & 63;
      Bs[kk][nn] = wcat[(size_t)(k0 + kk) * G4 + n0 + nn];
    }
    __syncthreads();
#pragma unroll
    for (int kk = 0; kk < 16; kk++) {
      float4 a0 = *(const float4*)&As[kk][ty * 8];
      float4 a1 = *(const float4*)&As[kk][ty * 8 + 4];
      float4 b4 = *(const float4*)&Bs[kk][tx * 4];
      float av[8] = {a0.x, a0.y, a0.z, a0.w, a1.x, a1.y, a1.z, a1.w};
      float bv[4] = {b4.x, b4.y, b4.z, b4.w};
#pragma unroll
      for (int i = 0; i < 8; i++)
#pragma unroll
        for (int j = 0; j < 4; j++) acc[i][j] = fmaf(av[i], bv[j], acc[i][j]);
    }
    __syncthreads();
  }
  const int hd = (n0 >> 2) + tx;  // 4 gate cols per hd unit
  const float4 bb = *(const float4*)&bcat[n0 + tx * 4];
#pragma unroll
  for (int i = 0; i < 8; i++) {
    int row = m0 + ty * 8 + i;
    if (row >= M) continue;
    float gi = acc[i][0] + bb.x;
    float gf_ = acc[i][1] + bb.y;
    float gg = acc[i][2] + bb.z;
    float go = acc[i][3] + bb.w;
    size_t ix = (size_t)row * HD + hd;
    float cn = sigf(gf_) * cstate[ix] + sigf(gi) * tanhf(gg);
    cstate[ix] = cn;
    hnext[ix] = sigf(go) * tanhf(cn);
  }
}

// ---------------- generic f32 GEMM: C = act(A@B + bias), 128x64 tile ----------------
__global__ __launch_bounds__(256) void k_gemm(
    const float* __restrict__ A, int lda, const float* __restrict__ B, int ldb,
    const float* __restrict__ bias, float* __restrict__ C, int ldc,
    int M, int Nn, int K, int act) {
  __shared__ float As[16][132];
  __shared__ float Bs[16][68];
  const int tid = threadIdx.x;
  const int tx = tid & 15, ty = tid >> 4;
  const int m0 = blockIdx.x * 128;
  const int n0 = blockIdx.y * 64;
  float acc[8][4] = {};
  for (int k0 = 0; k0 < K; k0 += 16) {
#pragma unroll
    for (int i = 0; i < 8; i++) {
      int idx = i * 256 + tid;
      int mm = idx >> 4, kk = idx & 15;
      int row = m0 + mm;
      As[kk][mm] = (row < M) ? A[(size_t)row * lda + k0 + kk] : 0.f;
    }
#pragma unroll
    for (int i = 0; i < 4; i++) {
      int idx = i * 256 + tid;
      int kk = idx >> 6, nn = idx & 63;
      Bs[kk][nn] = B[(size_t)(k0 + kk) * ldb + n0 + nn];
    }
    __syncthreads();
#pragma unroll
    for (int kk = 0; kk < 16; kk++) {
      float4 a0 = *(const float4*)&As[kk][ty * 8];
      float4 a1 = *(const float4*)&As[kk][ty * 8 + 4];
      float4 b4 = *(const float4*)&Bs[kk][tx * 4];
      float av[8] = {a0.x, a0.y, a0.z, a0.w, a1.x, a1.y, a1.z, a1.w};
      float bv[4] = {b4.x, b4.y, b4.z, b4.w};
#pragma unroll
      for (int i = 0; i < 8; i++)
#pragma unroll
        for (int j = 0; j < 4; j++) acc[i][j] = fmaf(av[i], bv[j], acc[i][j]);
    }
    __syncthreads();
  }
#pragma unroll
  for (int i = 0; i < 8; i++) {
    int row = m0 + ty * 8 + i;
    if (row >= M) continue;
#pragma unroll
    for (int j = 0; j < 4; j++) {
      int col = n0 + tx * 4 + j;
      float v = acc[i][j] + bias[col];
      if (act == ACT_RELU) v = fmaxf(v, 0.f);
      else if (act == ACT_TANH) v = tanhf(v);
      C[(size_t)row * ldc + col] = v;
    }
  }
}

// ---------------- per-row LN over 256 + optional act (0 none, 1 relu, 2 elu) ----------------
__global__ __launch_bounds__(256) void k_ln_rows(
    const float* __restrict__ in, float* __restrict__ out,
    const float* __restrict__ g, const float* __restrict__ b, int rows, int act) {
  int row = blockIdx.x;
  if (row >= rows) return;
  int tid = threadIdx.x, lane = tid & 63, wv = tid >> 6;
  float v = in[(size_t)row * HD + tid];
  float s = v, s2 = v * v;
  for (int o = 32; o; o >>= 1) { s += __shfl_xor(s, o); s2 += __shfl_xor(s2, o); }
  __shared__ float ws1[4], ws2[4];
  if (lane == 0) { ws1[wv] = s; ws2[wv] = s2; }
  __syncthreads();
  float S1 = ws1[0] + ws1[1] + ws1[2] + ws1[3];
  float S2 = ws2[0] + ws2[1] + ws2[2] + ws2[3];
  float m = S1 * (1.f / 256.f);
  float var = S2 * (1.f / 256.f) - m * m;
  float r = rsqrtf(var + 1e-5f);
  float y = (v - m) * r * g[tid] + b[tid];
  if (act == 1) y = fmaxf(y, 0.f);
  else if (act == 2) y = (y > 0.f) ? y : (expf(y) - 1.f);
  out[(size_t)row * HD + tid] = y;
}

// ---------------- CSR build ----------------
__global__ void k_hist_edges(const int* __restrict__ dst, int E, int n, int* __restrict__ cnt) {
  int tot = E + n;
  for (int i = blockIdx.x * blockDim.x + threadIdx.x; i < tot; i += gridDim.x * blockDim.x) {
    int d = (i < E) ? dst[i] : (i - E);
    atomicAdd(&cnt[d], 1);
  }
}

__global__ void k_hist_arr(const int* __restrict__ a, int n, int* __restrict__ cnt) {
  for (int i = blockIdx.x * blockDim.x + threadIdx.x; i < n; i += gridDim.x * blockDim.x)
    atomicAdd(&cnt[a[i]], 1);
}

// single-block exclusive scan, ptr[n] = total
__global__ void k_scan_excl(const int* __restrict__ cnt, int* __restrict__ ptr, int n) {
  __shared__ int sm[1024];
  __shared__ int carry_s;
  int tid = threadIdx.x;
  if (tid == 0) carry_s = 0;
  __syncthreads();
  for (int base = 0; base < n; base += 1024) {
    int i = base + tid;
    int v = (i < n) ? cnt[i] : 0;
    sm[tid] = v;
    __syncthreads();
    for (int off = 1; off < 1024; off <<= 1) {
      int tval = (tid >= off) ? sm[tid - off] : 0;
      __syncthreads();
      sm[tid] += tval;
      __syncthreads();
    }
    int carry = carry_s;
    if (i < n) ptr[i] = carry + sm[tid] - v;
    __syncthreads();
    if (tid == 1023) carry_s = carry + sm[1023];
    __syncthreads();
  }
  if (tid == 0) ptr[n] = carry_s;
}

__global__ void k_scatter_edges(const int* __restrict__ src, const int* __restrict__ dst,
                                int E, int n, const int* __restrict__ rowptr,
                                int* __restrict__ fill, int* __restrict__ esrc) {
  int tot = E + n;
  for (int i = blockIdx.x * blockDim.x + threadIdx.x; i < tot; i += gridDim.x * blockDim.x) {
    int d, s;
    if (i < E) { d = dst[i]; s = src[i]; } else { d = i - E; s = i - E; }
    int pos = rowptr[d] + atomicAdd(&fill[d], 1);
    esrc[pos] = s;
  }
}

// ---------------- fused GATv2 layer, one block per dst node ----------------
__global__ __launch_bounds__(256) void k_gat_node(
    const float* __restrict__ xin, const float* __restrict__ xlr,
    const int* __restrict__ rowptr, const int* __restrict__ esrc,
    const float* __restrict__ att, const float* __restrict__ bias,
    const float* __restrict__ lng, const float* __restrict__ lnb,
    float* __restrict__ xout, float* __restrict__ scbuf, int n_nodes) {
  const int nd = blockIdx.x;
  const int tid = threadIdx.x, lane = tid & 63, wv = tid >> 6;
  __shared__ float xr_s[256], att_s[256], out_s[256];
  __shared__ float wred[4][4], zred[4][4];
  __shared__ float ws1[4], ws2[4];
  xr_s[tid] = xlr[(size_t)nd * 512 + 256 + tid];
  att_s[tid] = att[tid];
  out_s[tid] = 0.f;
  __syncthreads();
  const int rs = rowptr[nd];
  const int deg = rowptr[nd + 1] - rs;
  // phase 1: scores + per-wave max
  float wmax[4] = {-3e38f, -3e38f, -3e38f, -3e38f};
  for (int p = wv; p < deg; p += 4) {
    const float* xl = xlr + (size_t)esrc[rs + p] * 512;
    float sh[4];
#pragma unroll
    for (int h = 0; h < 4; h++) {
      float v = xl[h * 64 + lane] + xr_s[h * 64 + lane];
      v = (v > 0.f) ? v : 0.2f * v;  // leaky_relu 0.2
      sh[h] = v * att_s[h * 64 + lane];
    }
#pragma unroll
    for (int h = 0; h < 4; h++) {
      for (int o = 32; o; o >>= 1) sh[h] += __shfl_xor(sh[h], o);
      wmax[h] = fmaxf(wmax[h], sh[h]);
    }
    if (lane == 0) {
#pragma unroll
      for (int h = 0; h < 4; h++) scbuf[(size_t)(rs + p) * 4 + h] = sh[h];
    }
  }
  if (lane == 0) {
#pragma unroll
    for (int h = 0; h < 4; h++) wred[wv][h] = wmax[h];
  }
  __syncthreads();
  float m[4];
#pragma unroll
  for (int h = 0; h < 4; h++)
    m[h] = fmaxf(fmaxf(wred[0][h], wred[1][h]), fmaxf(wred[2][h], wred[3][h]));
  // phase 2: z
  float zl[4] = {0, 0, 0, 0};
  for (int p = tid; p < deg; p += 256) {
#pragma unroll
    for (int h = 0; h < 4; h++) zl[h] += expf(scbuf[(size_t)(rs + p) * 4 + h] - m[h]);
  }
#pragma unroll
  for (int h = 0; h < 4; h++)
    for (int o = 32; o; o >>= 1) zl[h] += __shfl_xor(zl[h], o);
  if (lane == 0) {
#pragma unroll
    for (int h = 0; h < 4; h++) zred[wv][h] = zl[h];
  }
  __syncthreads();
  float zinv[4];
#pragma unroll
  for (int h = 0; h < 4; h++)
    zinv[h] = 1.f / (zred[0][h] + zred[1][h] + zred[2][h] + zred[3][h] + 1e-16f);
  // phase 3: aggregate
  float acc[4] = {0, 0, 0, 0};
  for (int p = wv; p < deg; p += 4) {
    const float* xl = xlr + (size_t)esrc[rs + p] * 512;
#pragma unroll
    for (int h = 0; h < 4; h++) {
      float wgt = expf(scbuf[(size_t)(rs + p) * 4 + h] - m[h]) * zinv[h];
      acc[h] += wgt * xl[h * 64 + lane];
    }
  }
#pragma unroll
  for (int h = 0; h < 4; h++) atomicAdd(&out_s[h * 64 + lane], acc[h]);
  __syncthreads();
  // epilogue: +bias, +residual, LN, ELU
  float v = out_s[tid] + bias[tid] + xin[(size_t)nd * 256 + tid];
  float s = v, s2 = v * v;
  for (int o = 32; o; o >>= 1) { s += __shfl_xor(s, o); s2 += __shfl_xor(s2, o); }
  if (lane == 0) { ws1[wv] = s; ws2[wv] = s2; }
  __syncthreads();
  float S1 = ws1[0] + ws1[1] + ws1[2] + ws1[3];
  float S2 = ws2[0] + ws2[1] + ws2[2] + ws2[3];
  float mean = S1 * (1.f / 256.f);
  float var = S2 * (1.f / 256.f) - mean * mean;
  float r = rsqrtf(var + 1e-5f);
  float y = (v - mean) * r * lng[tid] + lnb[tid];
  y = (y > 0.f) ? y : (expf(y) - 1.f);
  xout[(size_t)nd * 256 + tid] = y;
}

// ---------------- small row-dot heads: out[n,o] = act(dot(in[n,:],W[:,o]) + b[o]) ----------------
// act: 0 none, 3 tanh*0.1, 4 sigmoid
__global__ void k_rowdot(const float* __restrict__ in, const float* __restrict__ W,
                         const float* __restrict__ bias, float* __restrict__ out,
                         int rows, int K, int OC, int act) {
  int row = blockIdx.x * 4 + (threadIdx.x >> 6);
  if (row >= rows) return;
  int lane = threadIdx.x & 63;
  for (int o = 0; o < OC; o++) {
    float s = 0.f;
    for (int k = lane; k < K; k += 64) s += in[(size_t)row * K + k] * W[(size_t)k * OC + o];
    for (int off = 32; off; off >>= 1) s += __shfl_xor(s, off);
    if (lane == 0) {
      float v = s + bias[o];
      if (act == 3) v = tanhf(v) * 0.1f;
      else if (act == 4) v = 1.f / (1.f + expf(-v));
      out[(size_t)row * OC + o] = v;
    }
  }
}

// ---------------- sector attention pooling ----------------
__global__ __launch_bounds__(256) void k_sector_pool(
    const float* __restrict__ x, const float* __restrict__ sc,
    const int* __restrict__ bptr, float* __restrict__ se, int S) {
  const int s = blockIdx.x, tid = threadIdx.x, lane = tid & 63, wv = tid >> 6;
  const int rs = bptr[s], re = bptr[s + 1];
  const int cnt = re - rs;
  __shared__ float r1[4], r2[4], wch[256];
  float mx = -3e38f;
  for (int i = rs + tid; i < re; i += 256) mx = fmaxf(mx, sc[i]);
  for (int o = 32; o; o >>= 1) mx = fmaxf(mx, __shfl_xor(mx, o));
  if (lane == 0) r1[wv] = mx;
  __syncthreads();
  float m = fmaxf(fmaxf(r1[0], r1[1]), fmaxf(r1[2], r1[3]));
  if (cnt == 0) m = 0.f;
  float z = 0.f;
  for (int i = rs + tid; i < re; i += 256) z += expf(sc[i] - m);
  for (int o = 32; o; o >>= 1) z += __shfl_xor(z, o);
  if (lane == 0) r2[wv] = z;
  __syncthreads();
  float zinv = 1.f / (r2[0] + r2[1] + r2[2] + r2[3] + 1e-16f);
  float acc = 0.f;
  for (int base = rs; base < re; base += 256) {
    int i = base + tid;
    wch[tid] = (i < re) ? expf(sc[i] - m) * zinv : 0.f;
    __syncthreads();
    int lim = re - base; if (lim > 256) lim = 256;
    for (int q = 0; q < lim; q++) acc += wch[q] * x[(size_t)(base + q) * HD + tid];
    __syncthreads();
  }
  se[(size_t)s * HD + tid] = acc / fmaxf((float)cnt, 1.f);
}

// ---------------- comb = [x | se[batch]] ----------------
__global__ void k_comb(const float* __restrict__ x, const float* __restrict__ se,
                       const int* __restrict__ batch, float* __restrict__ comb, int n) {
  int total = n * 512;
  for (int i = blockIdx.x * blockDim.x + threadIdx.x; i < total; i += gridDim.x * blockDim.x) {
    int row = i >> 9, col = i & 511;
    comb[i] = (col < HD) ? x[(size_t)row * HD + col]
                         : se[(size_t)batch[row] * HD + (col - HD)];
  }
}

extern "C" void kernel_launch(void* const* d_in, const int* in_sizes, int n_in,
                              void* d_out, int out_size, void* d_ws, size_t ws_size,
                              hipStream_t stream) {
  const float* x_stock   = (const float*)d_in[0];
  const int*   ei_stock  = (const int*)d_in[1];
  const int*   batch     = (const int*)d_in[2];
  const int*   ei_sector = (const int*)d_in[4];
  const float* ln_feat_g = (const float*)d_in[5];
  const float* ln_feat_b = (const float*)d_in[6];
  const float* w_ih0 = (const float*)d_in[7];
  const float* w_hh0 = (const float*)d_in[8];
  const float* b_ih0 = (const float*)d_in[9];
  const float* b_hh0 = (const float*)d_in[10];
  const float* w_ih1 = (const float*)d_in[11];
  const float* w_hh1 = (const float*)d_in[12];
  const float* b_ih1 = (const float*)d_in[13];
  const float* b_hh1 = (const float*)d_in[14];
  const float* ln_t_g = (const float*)d_in[15];
  const float* ln_t_b = (const float*)d_in[16];
  const float* W_in = (const float*)d_in[17];
  const float* b_in = (const float*)d_in[18];
  const float* stock_Wl = (const float*)d_in[19];
  const float* stock_bl = (const float*)d_in[20];
  const float* stock_Wr = (const float*)d_in[21];
  const float* stock_br = (const float*)d_in[22];
  const float* stock_att = (const float*)d_in[23];
  const float* stock_bias = (const float*)d_in[24];
  const float* stock_g = (const float*)d_in[25];
  const float* stock_b = (const float*)d_in[26];
  const float* sector_Wl = (const float*)d_in[27];
  const float* sector_bl = (const float*)d_in[28];
  const float* sector_Wr = (const float*)d_in[29];
  const float* sector_br = (const float*)d_in[30];
  const float* sector_att = (const float*)d_in[31];
  const float* sector_bias = (const float*)d_in[32];
  const float* sector_g = (const float*)d_in[33];
  const float* sector_b = (const float*)d_in[34];
  const float* Wa1 = (const float*)d_in[35];
  const float* ba1 = (const float*)d_in[36];
  const float* Wa2 = (const float*)d_in[37];
  const float* ba2 = (const float*)d_in[38];
  const float* Wf  = (const float*)d_in[39];
  const float* bf  = (const float*)d_in[40];
  const float* gf  = (const float*)d_in[41];
  const float* bef = (const float*)d_in[42];
  const float* W_regf = (const float*)d_in[43];
  const float* b_regf = (const float*)d_in[44];
  const float* g_regf = (const float*)d_in[45];
  const float* be_regf = (const float*)d_in[46];
  const float* W_clff = (const float*)d_in[47];
  const float* b_clff = (const float*)d_in[48];
  const float* g_clff = (const float*)d_in[49];
  const float* be_clff = (const float*)d_in[50];
  const float* W_rnkf = (const float*)d_in[51];
  const float* b_rnkf = (const float*)d_in[52];
  const float* g_rnkf = (const float*)d_in[53];
  const float* be_rnkf = (const float*)d_in[54];
  const float* Wr1 = (const float*)d_in[55];
  const float* br1 = (const float*)d_in[56];
  const float* Wr2 = (const float*)d_in[57];
  const float* br2 = (const float*)d_in[58];
  const float* Wr3 = (const float*)d_in[59];
  const float* br3 = (const float*)d_in[60];
  const float* Wc1 = (const float*)d_in[61];
  const float* bc1 = (const float*)d_in[62];
  const float* Wc2 = (const float*)d_in[63];
  const float* bc2 = (const float*)d_in[64];
  const float* Wk1 = (const float*)d_in[65];
  const float* bk1 = (const float*)d_in[66];
  const float* Wk2 = (const float*)d_in[67];
  const float* bk2 = (const float*)d_in[68];

  const int N  = in_sizes[0] / (TT * FF);
  const int E  = in_sizes[1] / 2;
  const int S  = in_sizes[3] / HD;
  const int ES = in_sizes[4] / 2;
  const int Ep = E + N, ESp = ES + S;
  const int NT = N * TT;

  char* wsb = (char*)d_ws;
  size_t off = 0;
  auto alloc = [&](size_t bytes) -> char* {
    char* p = wsb + off;
    off += (bytes + 255) & ~(size_t)255;
    return p;
  };
  // zero-init float group (contiguous from 0)
  float* h0a = (float*)alloc((size_t)N * HD * 4);
  float* c0  = (float*)alloc((size_t)N * HD * 4);
  float* h1a = (float*)alloc((size_t)N * HD * 4);
  float* c1  = (float*)alloc((size_t)N * HD * 4);
  size_t zf_bytes = off;
  float* h0b = (float*)alloc((size_t)N * HD * 4);
  float* h1b = (float*)alloc((size_t)N * HD * 4);
  float* mu   = (float*)alloc((size_t)NT * 4);
  float* rstd = (float*)alloc((size_t)NT * 4);
  float* wcat0 = (float*)alloc((size_t)(FF + HD) * G4 * 4);
  float* bcat0 = (float*)alloc((size_t)G4 * 4);
  float* wcat1 = (float*)alloc((size_t)(2 * HD) * G4 * 4);
  float* bcat1 = (float*)alloc((size_t)G4 * 4);
  float* xA  = (float*)alloc((size_t)N * HD * 4);
  float* xB  = (float*)alloc((size_t)N * HD * 4);
  float* xlr = (float*)alloc((size_t)N * 512 * 4);     // xl|xr; later reused as comb
  float* scbuf = (float*)alloc((size_t)Ep * 4 * 4);    // per-edge scores; later reused as hA
  float* selr = (float*)alloc((size_t)S * 512 * 4);
  float* seA  = (float*)alloc((size_t)S * HD * 4);
  float* seB  = (float*)alloc((size_t)S * HD * 4);
  float* scpool = (float*)alloc((size_t)N * 4);
  float* tmpY    = (float*)alloc((size_t)N * HD * 4);  // t128/t64 alias inside
  float* headbuf = (float*)alloc((size_t)N * HD * 4);
  size_t zi_start = off;
  int* cnt   = (int*)alloc((size_t)(N + 1) * 4);
  int* fill  = (int*)alloc((size_t)N * 4);
  int* cntS  = (int*)alloc((size_t)(S + 1) * 4);
  int* fillS = (int*)alloc((size_t)S * 4);
  int* bcnt  = (int*)alloc((size_t)(S + 1) * 4);
  size_t zi_bytes = off - zi_start;
  int* rowptr = (int*)alloc((size_t)(N + 1) * 4);
  int* esrc   = (int*)alloc((size_t)Ep * 4);
  int* rptrS  = (int*)alloc((size_t)(S + 1) * 4);
  int* esrcS  = (int*)alloc((size_t)ESp * 4);
  int* bptr   = (int*)alloc((size_t)(S + 1) * 4);

  float* hA   = scbuf;                       // N*128 <= Ep*4, lifetimes disjoint
  float* comb = xlr;
  float* t128 = tmpY;
  float* t64  = tmpY + (size_t)N * 128;
  float* out_ret = (float*)d_out;
  float* out_mov = out_ret + N;
  float* out_rnk = out_ret + 3 * (size_t)N;
  float* out_c   = out_ret + 4 * (size_t)N;

  hipMemsetAsync(d_ws, 0, zf_bytes, stream);
  hipMemsetAsync(wsb + zi_start, 0, zi_bytes, stream);

  auto gemm = [&](const float* A, int lda, const float* B, int ldb, const float* bias,
                  float* C, int ldc, int M, int Nn, int K, int act) {
    dim3 g((M + 127) / 128, Nn / 64);
    k_gemm<<<g, dim3(256), 0, stream>>>(A, lda, B, ldb, bias, C, ldc, M, Nn, K, act);
  };

  // 1. feature LN stats
  k_lnstats<<<dim3((NT + 3) / 4), dim3(256), 0, stream>>>(x_stock, mu, rstd, NT);
  // 2. fused LSTM weights (gate-interleaved layout)
  k_build_wcat<<<dim3(((FF + HD) * G4 + 255) / 256), dim3(256), 0, stream>>>(
      w_ih0, w_hh0, b_ih0, b_hh0, wcat0, bcat0, FF, HD);
  k_build_wcat<<<dim3(((2 * HD) * G4 + 255) / 256), dim3(256), 0, stream>>>(
      w_ih1, w_hh1, b_ih1, b_hh1, wcat1, bcat1, HD, HD);
  // 3. LSTM (both layers pipelined per timestep)
  {
    dim3 gl((N + 127) / 128, G4 / 64);
    float* h0c = h0a; float* h0n = h0b;
    float* h1c = h1a; float* h1n = h1b;
    for (int t = 0; t < TT; t++) {
      k_lstm_step<0><<<gl, dim3(256), 0, stream>>>(x_stock, mu, rstd, ln_feat_g, ln_feat_b,
                                                   h0c, wcat0, bcat0, c0, h0n, N, t);
      k_lstm_step<1><<<gl, dim3(256), 0, stream>>>(h0n, nullptr, nullptr, nullptr, nullptr,
                                                   h1c, wcat1, bcat1, c1, h1n, N, t);
      float* tp = h0c; h0c = h0n; h0n = tp;
      tp = h1c; h1c = h1n; h1n = tp;
    }
    k_ln_rows<<<dim3(N), dim3(256), 0, stream>>>(h1c, tmpY, ln_t_g, ln_t_b, N, 0);
  }
  gemm(tmpY, HD, W_in, HD, b_in, xA, HD, N, HD, HD, ACT_NONE);

  // 4. stock CSR (with self loops)
  k_hist_edges<<<dim3(2048), dim3(256), 0, stream>>>(ei_stock + E, E, N, cnt);
  k_scan_excl<<<dim3(1), dim3(1024), 0, stream>>>(cnt, rowptr, N);
  k_scatter_edges<<<dim3(2048), dim3(256), 0, stream>>>(ei_stock, ei_stock + E, E, N,
                                                        rowptr, fill, esrc);
  // 5. stock GAT x2
  float* xc = xA; float* xn = xB;
  for (int l = 0; l < 2; l++) {
    const float* Wl = stock_Wl + (size_t)l * HD * HD;
    const float* bl = stock_bl + (size_t)l * HD;
    const float* Wr = stock_Wr + (size_t)l * HD * HD;
    const float* br = stock_br + (size_t)l * HD;
    const float* at = stock_att + (size_t)l * HD;
    const float* bi = stock_bias + (size_t)l * HD;
    const float* lg = stock_g + (size_t)l * HD;
    const float* lb = stock_b + (size_t)l * HD;
    gemm(xc, HD, Wl, HD, bl, xlr, 512, N, HD, HD, ACT_NONE);
    gemm(xc, HD, Wr, HD, br, xlr + 256, 512, N, HD, HD, ACT_NONE);
    k_gat_node<<<dim3(N), dim3(256), 0, stream>>>(xc, xlr, rowptr, esrc, at, bi, lg, lb,
                                                  xn, scbuf, N);
    float* tp = xc; xc = xn; xn = tp;
  }
  // 6. attention pooling to sectors
  gemm(xc, HD, Wa1, 128, ba1, hA, 128, N, 128, HD, ACT_TANH);
  k_rowdot<<<dim3((N + 3) / 4), dim3(256), 0, stream>>>(hA, Wa2, ba2, scpool, N, 128, 1, 0);
  k_hist_arr<<<dim3(512), dim3(256), 0, stream>>>(batch, N, bcnt);
  k_scan_excl<<<dim3(1), dim3(1024), 0, stream>>>(bcnt, bptr, S);
  k_sector_pool<<<dim3(S), dim3(256), 0, stream>>>(xc, scpool, bptr, seA, S);
  // 7. sector CSR + GAT x2
  k_hist_edges<<<dim3(64), dim3(256), 0, stream>>>(ei_sector + ES, ES, S, cntS);
  k_scan_excl<<<dim3(1), dim3(1024), 0, stream>>>(cntS, rptrS, S);
  k_scatter_edges<<<dim3(64), dim3(256), 0, stream>>>(ei_sector, ei_sector + ES, ES, S,
                                                      rptrS, fillS, esrcS);
  float* sec = seA; float* sen = seB;
  for (int l = 0; l < 2; l++) {
    const float* Wl = sector_Wl + (size_t)l * HD * HD;
    const float* bl = sector_bl + (size_t)l * HD;
    const float* Wr = sector_Wr + (size_t)l * HD * HD;
    const float* br = sector_br + (size_t)l * HD;
    const float* at = sector_att + (size_t)l * HD;
    const float* bi = sector_bias + (size_t)l * HD;
    const float* lg = sector_g + (size_t)l * HD;
    const float* lb = sector_b + (size_t)l * HD;
    gemm(sec, HD, Wl, HD, bl, selr, 512, S, HD, HD, ACT_NONE);
    gemm(sec, HD, Wr, HD, br, selr + 256, 512, S, HD, HD, ACT_NONE);
    k_gat_node<<<dim3(S), dim3(256), 0, stream>>>(sec, selr, rptrS, esrcS, at, bi, lg, lb,
                                                  sen, scbuf, S);
    float* tp = sec; sec = sen; sen = tp;
  }
  // 8. fusion -> c (output)
  k_comb<<<dim3(4096), dim3(256), 0, stream>>>(xc, sec, batch, comb, N);
  gemm(comb, 512, Wf, HD, bf, tmpY, HD, N, HD, 512, ACT_NONE);
  k_ln_rows<<<dim3(N), dim3(256), 0, stream>>>(tmpY, out_c, gf, bef, N, 2);
  // 9a. regression head
  gemm(out_c, HD, W_regf, HD, b_regf, tmpY, HD, N, HD, HD, ACT_NONE);
  k_ln_rows<<<dim3(N), dim3(256), 0, stream>>>(tmpY, headbuf, g_regf, be_regf, N, 1);
  gemm(headbuf, HD, Wr1, 128, br1, t128, 128, N, 128, HD, ACT_RELU);
  gemm(t128, 128, Wr2, 64, br2, t64, 64, N, 64, 128, ACT_RELU);
  k_rowdot<<<dim3((N + 3) / 4), dim3(256), 0, stream>>>(t64, Wr3, br3, out_ret, N, 64, 1, 3);
  // 9b. classification head
  gemm(out_c, HD, W_clff, HD, b_clff, tmpY, HD, N, HD, HD, ACT_NONE);
  k_ln_rows<<<dim3(N), dim3(256), 0, stream>>>(tmpY, headbuf, g_clff, be_clff, N, 1);
  gemm(headbuf, HD, Wc1, 128, bc1, t128, 128, N, 128, HD, ACT_RELU);
  k_rowdot<<<dim3((N + 3) / 4), dim3(256), 0, stream>>>(t128, Wc2, bc2, out_mov, N, 128, 2, 0);
  // 9c. ranking head
  gemm(out_c, HD, W_rnkf, HD, b_rnkf, tmpY, HD, N, HD, HD, ACT_NONE);
  k_ln_rows<<<dim3(N), dim3(256), 0, stream>>>(tmpY, headbuf, g_rnkf, be_rnkf, N, 1);
  gemm(headbuf, HD, Wk1, 128, bk1, t128, 128, N, 128, HD, ACT_RELU);
  k_rowdot<<<dim3((N + 3) / 4), dim3(256), 0, stream>>>(t128, Wk2, bk2, out_rnk, N, 128, 1, 4);
}

// Round 2
// 4588.589 us; speedup vs baseline: 3.9107x; 3.9107x over previous
//
#include <hip/hip_runtime.h>
#include <stdint.h>

static constexpr int TT = 20;     // timesteps
static constexpr int FF = 64;     // input features
static constexpr int HD = 256;    // hidden dim

enum { ACT_NONE = 0, ACT_RELU = 1, ACT_TANH = 2 };

typedef __attribute__((ext_vector_type(8))) short short8;
typedef __attribute__((ext_vector_type(4))) float f32x4;

static __device__ __forceinline__ float sigf(float x) { return 1.f / (1.f + expf(-x)); }

static __device__ __forceinline__ ushort f2bf(float f) {
  uint32_t u = __float_as_uint(f);
  return (ushort)((u + 0x7fffu + ((u >> 16) & 1u)) >> 16);
}
static __device__ __forceinline__ float bf2f(ushort u) {
  return __uint_as_float(((uint32_t)u) << 16);
}
static __device__ __forceinline__ void gl16(const void* g, void* l) {
  __builtin_amdgcn_global_load_lds(
      (const __attribute__((address_space(1))) uint32_t*)g,
      (__attribute__((address_space(3))) uint32_t*)l, 16, 0, 0);
}

// ---------------- feature LN + bf16 convert: one wave per 64-wide row ----------------
__global__ void k_lncvt(const float* __restrict__ x, const float* __restrict__ g,
                        const float* __restrict__ b, ushort* __restrict__ y, int rows) {
  int row = blockIdx.x * 4 + (threadIdx.x >> 6);
  int lane = threadIdx.x & 63;
  if (row >= rows) return;
  float v = x[(size_t)row * 64 + lane];
  float s = v, s2 = v * v;
  for (int o = 32; o; o >>= 1) { s += __shfl_xor(s, o); s2 += __shfl_xor(s2, o); }
  float m = s * (1.f / 64.f);
  float var = s2 * (1.f / 64.f) - m * m;
  float rs = rsqrtf(var + 1e-5f);
  y[(size_t)row * 64 + lane] = f2bf((v - m) * rs * g[lane] + b[lane]);
}

// ---------------- build pre-tiled/swizzled bf16 gate weights ----------------
// layout: chunk idx = ((nb*KT + kt)*512 + r*4 + chunk_sw), 16B each.
// column permutation: col = hdblk*64 + g*16 + hdlo  (hd = hdblk*16 + hdlo)
__global__ void k_build_wtile(const float* __restrict__ w_ih, const float* __restrict__ w_hh,
                              ushort* __restrict__ wt, int KI, int KT) {
  int total = 8 * KT * 512;
  for (int idx = blockIdx.x * blockDim.x + threadIdx.x; idx < total;
       idx += gridDim.x * blockDim.x) {
    int nb = idx / (KT * 512);
    int rem = idx % (KT * 512);
    int kt = rem / 512;
    int q = rem % 512;
    int r = q >> 2, csw = q & 3;
    int ch = csw ^ ((r >> 1) & 3);
    int col = nb * 128 + r;
    int hdblk = col >> 6, gg = (col >> 4) & 3, hd = hdblk * 16 + (col & 15);
    int orow = gg * HD + hd;
    int k = kt * 32 + ch * 8;
    const float* src = (k < KI) ? (w_ih + (size_t)orow * KI + k)
                                : (w_hh + (size_t)orow * HD + (k - KI));
    ushort* dst = wt + (size_t)idx * 8;
#pragma unroll
    for (int j = 0; j < 8; j++) dst[j] = f2bf(src[j]);
  }
}

__global__ void k_build_bcp(const float* __restrict__ bi, const float* __restrict__ bh,
                            float* __restrict__ bcp) {
  int col = blockIdx.x * blockDim.x + threadIdx.x;
  if (col >= 1024) return;
  int hdblk = col >> 6, gg = (col >> 4) & 3, hd = hdblk * 16 + (col & 15);
  int orow = gg * HD + hd;
  bcp[col] = bi[orow] + bh[orow];
}

// ---------------- MFMA LSTM step: gates = [a0|a1] @ Wt, fused gate epilogue ----------------
// tile 128x128, 4 waves (2x2 of 64x64), BK=32, mfma_f32_16x16x32_bf16
template <int LAYER>
__global__ __launch_bounds__(256) void k_lstm_mfma(
    const ushort* __restrict__ a0,  // L0: xln (N,T,64) at t; L1: h0 current (N,HD)
    const ushort* __restrict__ a1,  // h_prev (N,HD)
    const ushort* __restrict__ wt, const float* __restrict__ bcp,
    float* __restrict__ cst, ushort* __restrict__ hnext, int M, int t) {
  constexpr int K = (LAYER == 0) ? 320 : 512;
  constexpr int KT = K / 32;
  constexpr int SEG0 = (LAYER == 0) ? 64 : 256;
  constexpr int LDA0 = (LAYER == 0) ? (TT * FF) : HD;
  __shared__ ushort At[128 * 32];
  __shared__ ushort Bt[128 * 32];
  const int tid = threadIdx.x;
  const int lane = tid & 63, wid = tid >> 6;
  const int wr = wid >> 1, wc = wid & 1;
  const int m0 = blockIdx.x * 128;
  const int nb = blockIdx.y;
  const int a0t = (LAYER == 0) ? t * FF : 0;

  f32x4 acc[4][4];
#pragma unroll
  for (int i = 0; i < 4; i++)
#pragma unroll
    for (int j = 0; j < 4; j++) acc[i][j] = (f32x4){0.f, 0.f, 0.f, 0.f};

  int rown[2], chn[2];
#pragma unroll
  for (int e = 0; e < 2; e++) {
    int q = e * 256 + tid;
    int r = q >> 2, csw = q & 3;
    rown[e] = r;
    chn[e] = csw ^ ((r >> 1) & 3);
  }
  const size_t wtbase = (size_t)nb * KT * 512;

  for (int kt = 0; kt < KT; ++kt) {
    __syncthreads();
    const int k0 = kt * 32;
#pragma unroll
    for (int e = 0; e < 2; e++) {
      int q = e * 256 + tid;
      int r = rown[e];
      int kg = k0 + chn[e] * 8;
      int grow = m0 + r;
      grow = (grow < M) ? grow : (M - 1);
      const ushort* src = (kg < SEG0)
                              ? (a0 + (size_t)grow * LDA0 + a0t + kg)
                              : (a1 + (size_t)grow * HD + (kg - SEG0));
      gl16(src, &At[q * 8]);
      gl16(wt + (wtbase + (size_t)kt * 512 + q) * 8, &Bt[q * 8]);
    }
    __syncthreads();
    short8 af[4], bfr[4];
#pragma unroll
    for (int i = 0; i < 4; i++) {
      int rA = wr * 64 + i * 16 + (lane & 15);
      int swa = (lane >> 4) ^ ((rA >> 1) & 3);
      af[i] = *(const short8*)&At[rA * 32 + swa * 8];
      int rB = wc * 64 + i * 16 + (lane & 15);
      int swb = (lane >> 4) ^ ((rB >> 1) & 3);
      bfr[i] = *(const short8*)&Bt[rB * 32 + swb * 8];
    }
#pragma unroll
    for (int i = 0; i < 4; i++)
#pragma unroll
      for (int j = 0; j < 4; j++)
        acc[i][j] = __builtin_amdgcn_mfma_f32_16x16x32_bf16(af[i], bfr[j], acc[i][j], 0, 0, 0);
  }
  // gate epilogue: acc[mi][0..3] = i,f,g,o for the same (row, hd)
  const int hdlo = lane & 15;
  const int rb = (lane >> 4) * 4;
  const int colb = nb * 128 + wc * 64;
  const float bI = bcp[colb + hdlo];
  const float bF = bcp[colb + 16 + hdlo];
  const float bG = bcp[colb + 32 + hdlo];
  const float bO = bcp[colb + 48 + hdlo];
  const int hd = (nb * 2 + wc) * 16 + hdlo;
#pragma unroll
  for (int i = 0; i < 4; i++) {
#pragma unroll
    for (int r = 0; r < 4; r++) {
      int row = m0 + wr * 64 + i * 16 + rb + r;
      if (row >= M) continue;
      float gi = acc[i][0][r] + bI;
      float gf = acc[i][1][r] + bF;
      float gg = acc[i][2][r] + bG;
      float go = acc[i][3][r] + bO;
      size_t ix = (size_t)row * HD + hd;
      float c = sigf(gf) * cst[ix] + sigf(gi) * tanhf(gg);
      cst[ix] = c;
      hnext[ix] = f2bf(sigf(go) * tanhf(c));
    }
  }
}

// ---------------- generic f32 GEMM: C = act(A@B + bias), 128x64 tile ----------------
__global__ __launch_bounds__(256) void k_gemm(
    const float* __restrict__ A, int lda, const float* __restrict__ B, int ldb,
    const float* __restrict__ bias, float* __restrict__ C, int ldc,
    int M, int Nn, int K, int act) {
  __shared__ float As[16][132];
  __shared__ float Bs[16][68];
  const int tid = threadIdx.x;
  const int tx = tid & 15, ty = tid >> 4;
  const int m0 = blockIdx.x * 128;
  const int n0 = blockIdx.y * 64;
  float acc[8][4] = {};
  for (int k0 = 0; k0 < K; k0 += 16) {
#pragma unroll
    for (int i = 0; i < 8; i++) {
      int idx = i * 256 + tid;
      int mm = idx >> 4, kk = idx & 15;
      int row = m0 + mm;
      As[kk][mm] = (row < M) ? A[(size_t)row * lda + k0 + kk] : 0.f;
    }
#pragma unroll
    for (int i = 0; i < 4; i++) {
      int idx = i * 256 + tid;
      int kk = idx >> 6, nn = idx & 63;
      Bs[kk][nn] = B[(size_t)(k0 + kk) * ldb + n0 + nn];
    }
    __syncthreads();
#pragma unroll
    for (int kk = 0; kk < 16; kk++) {
      float4 a0 = *(const float4*)&As[kk][ty * 8];
      float4 a1 = *(const float4*)&As[kk][ty * 8 + 4];
      float4 b4 = *(const float4*)&Bs[kk][tx * 4];
      float av[8] = {a0.x, a0.y, a0.z, a0.w, a1.x, a1.y, a1.z, a1.w};
      float bv[4] = {b4.x, b4.y, b4.z, b4.w};
#pragma unroll
      for (int i = 0; i < 8; i++)
#pragma unroll
        for (int j = 0; j < 4; j++) acc[i][j] = fmaf(av[i], bv[j], acc[i][j]);
    }
    __syncthreads();
  }
#pragma unroll
  for (int i = 0; i < 8; i++) {
    int row = m0 + ty * 8 + i;
    if (row >= M) continue;
#pragma unroll
    for (int j = 0; j < 4; j++) {
      int col = n0 + tx * 4 + j;
      float v = acc[i][j] + bias[col];
      if (act == ACT_RELU) v = fmaxf(v, 0.f);
      else if (act == ACT_TANH) v = tanhf(v);
      C[(size_t)row * ldc + col] = v;
    }
  }
}

// ---------------- per-row LN over 256 + optional act (0 none, 1 relu, 2 elu) ----------------
__global__ __launch_bounds__(256) void k_ln_rows(
    const float* __restrict__ in, float* __restrict__ out,
    const float* __restrict__ g, const float* __restrict__ b, int rows, int act) {
  int row = blockIdx.x;
  if (row >= rows) return;
  int tid = threadIdx.x, lane = tid & 63, wv = tid >> 6;
  float v = in[(size_t)row * HD + tid];
  float s = v, s2 = v * v;
  for (int o = 32; o; o >>= 1) { s += __shfl_xor(s, o); s2 += __shfl_xor(s2, o); }
  __shared__ float ws1[4], ws2[4];
  if (lane == 0) { ws1[wv] = s; ws2[wv] = s2; }
  __syncthreads();
  float S1 = ws1[0] + ws1[1] + ws1[2] + ws1[3];
  float S2 = ws2[0] + ws2[1] + ws2[2] + ws2[3];
  float m = S1 * (1.f / 256.f);
  float var = S2 * (1.f / 256.f) - m * m;
  float r = rsqrtf(var + 1e-5f);
  float y = (v - m) * r * g[tid] + b[tid];
  if (act == 1) y = fmaxf(y, 0.f);
  else if (act == 2) y = (y > 0.f) ? y : (expf(y) - 1.f);
  out[(size_t)row * HD + tid] = y;
}

// bf16-input variant
__global__ __launch_bounds__(256) void k_ln_rows_b16(
    const ushort* __restrict__ in, float* __restrict__ out,
    const float* __restrict__ g, const float* __restrict__ b, int rows, int act) {
  int row = blockIdx.x;
  if (row >= rows) return;
  int tid = threadIdx.x, lane = tid & 63, wv = tid >> 6;
  float v = bf2f(in[(size_t)row * HD + tid]);
  float s = v, s2 = v * v;
  for (int o = 32; o; o >>= 1) { s += __shfl_xor(s, o); s2 += __shfl_xor(s2, o); }
  __shared__ float ws1[4], ws2[4];
  if (lane == 0) { ws1[wv] = s; ws2[wv] = s2; }
  __syncthreads();
  float S1 = ws1[0] + ws1[1] + ws1[2] + ws1[3];
  float S2 = ws2[0] + ws2[1] + ws2[2] + ws2[3];
  float m = S1 * (1.f / 256.f);
  float var = S2 * (1.f / 256.f) - m * m;
  float r = rsqrtf(var + 1e-5f);
  float y = (v - m) * r * g[tid] + b[tid];
  if (act == 1) y = fmaxf(y, 0.f);
  else if (act == 2) y = (y > 0.f) ? y : (expf(y) - 1.f);
  out[(size_t)row * HD + tid] = y;
}

// ---------------- CSR build ----------------
__global__ void k_hist_edges(const int* __restrict__ dst, int E, int n, int* __restrict__ cnt) {
  int tot = E + n;
  for (int i = blockIdx.x * blockDim.x + threadIdx.x; i < tot; i += gridDim.x * blockDim.x) {
    int d = (i < E) ? dst[i] : (i - E);
    atomicAdd(&cnt[d], 1);
  }
}

__global__ void k_hist_arr(const int* __restrict__ a, int n, int* __restrict__ cnt) {
  for (int i = blockIdx.x * blockDim.x + threadIdx.x; i < n; i += gridDim.x * blockDim.x)
    atomicAdd(&cnt[a[i]], 1);
}

__global__ void k_scan_excl(const int* __restrict__ cnt, int* __restrict__ ptr, int n) {
  __shared__ int sm[1024];
  __shared__ int carry_s;
  int tid = threadIdx.x;
  if (tid == 0) carry_s = 0;
  __syncthreads();
  for (int base = 0; base < n; base += 1024) {
    int i = base + tid;
    int v = (i < n) ? cnt[i] : 0;
    sm[tid] = v;
    __syncthreads();
    for (int off = 1; off < 1024; off <<= 1) {
      int tval = (tid >= off) ? sm[tid - off] : 0;
      __syncthreads();
      sm[tid] += tval;
      __syncthreads();
    }
    int carry = carry_s;
    if (i < n) ptr[i] = carry + sm[tid] - v;
    __syncthreads();
    if (tid == 1023) carry_s = carry + sm[1023];
    __syncthreads();
  }
  if (tid == 0) ptr[n] = carry_s;
}

__global__ void k_scatter_edges(const int* __restrict__ src, const int* __restrict__ dst,
                                int E, int n, const int* __restrict__ rowptr,
                                int* __restrict__ fill, int* __restrict__ esrc) {
  int tot = E + n;
  for (int i = blockIdx.x * blockDim.x + threadIdx.x; i < tot; i += gridDim.x * blockDim.x) {
    int d, s;
    if (i < E) { d = dst[i]; s = src[i]; } else { d = i - E; s = i - E; }
    int pos = rowptr[d] + atomicAdd(&fill[d], 1);
    esrc[pos] = s;
  }
}

// ---------------- fused GATv2 layer, one block per dst node ----------------
__global__ __launch_bounds__(256) void k_gat_node(
    const float* __restrict__ xin, const float* __restrict__ xlr,
    const int* __restrict__ rowptr, const int* __restrict__ esrc,
    const float* __restrict__ att, const float* __restrict__ bias,
    const float* __restrict__ lng, const float* __restrict__ lnb,
    float* __restrict__ xout, float* __restrict__ scbuf, int n_nodes) {
  const int nd = blockIdx.x;
  const int tid = threadIdx.x, lane = tid & 63, wv = tid >> 6;
  __shared__ float xr_s[256], att_s[256], out_s[256];
  __shared__ float wred[4][4], zred[4][4];
  __shared__ float ws1[4], ws2[4];
  xr_s[tid] = xlr[(size_t)nd * 512 + 256 + tid];
  att_s[tid] = att[tid];
  out_s[tid] = 0.f;
  __syncthreads();
  const int rs = rowptr[nd];
  const int deg = rowptr[nd + 1] - rs;
  float wmax[4] = {-3e38f, -3e38f, -3e38f, -3e38f};
  for (int p = wv; p < deg; p += 4) {
    const float* xl = xlr + (size_t)esrc[rs + p] * 512;
    float sh[4];
#pragma unroll
    for (int h = 0; h < 4; h++) {
      float v = xl[h * 64 + lane] + xr_s[h * 64 + lane];
      v = (v > 0.f) ? v : 0.2f * v;
      sh[h] = v * att_s[h * 64 + lane];
    }
#pragma unroll
    for (int h = 0; h < 4; h++) {
      for (int o = 32; o; o >>= 1) sh[h] += __shfl_xor(sh[h], o);
      wmax[h] = fmaxf(wmax[h], sh[h]);
    }
    if (lane == 0) {
#pragma unroll
      for (int h = 0; h < 4; h++) scbuf[(size_t)(rs + p) * 4 + h] = sh[h];
    }
  }
  if (lane == 0) {
#pragma unroll
    for (int h = 0; h < 4; h++) wred[wv][h] = wmax[h];
  }
  __syncthreads();
  float m[4];
#pragma unroll
  for (int h = 0; h < 4; h++)
    m[h] = fmaxf(fmaxf(wred[0][h], wred[1][h]), fmaxf(wred[2][h], wred[3][h]));
  float zl[4] = {0, 0, 0, 0};
  for (int p = tid; p < deg; p += 256) {
#pragma unroll
    for (int h = 0; h < 4; h++) zl[h] += expf(scbuf[(size_t)(rs + p) * 4 + h] - m[h]);
  }
#pragma unroll
  for (int h = 0; h < 4; h++)
    for (int o = 32; o; o >>= 1) zl[h] += __shfl_xor(zl[h], o);
  if (lane == 0) {
#pragma unroll
    for (int h = 0; h < 4; h++) zred[wv][h] = zl[h];
  }
  __syncthreads();
  float zinv[4];
#pragma unroll
  for (int h = 0; h < 4; h++)
    zinv[h] = 1.f / (zred[0][h] + zred[1][h] + zred[2][h] + zred[3][h] + 1e-16f);
  float acc[4] = {0, 0, 0, 0};
  for (int p = wv; p < deg; p += 4) {
    const float* xl = xlr + (size_t)esrc[rs + p] * 512;
#pragma unroll
    for (int h = 0; h < 4; h++) {
      float wgt = expf(scbuf[(size_t)(rs + p) * 4 + h] - m[h]) * zinv[h];
      acc[h] += wgt * xl[h * 64 + lane];
    }
  }
#pragma unroll
  for (int h = 0; h < 4; h++) atomicAdd(&out_s[h * 64 + lane], acc[h]);
  __syncthreads();
  float v = out_s[tid] + bias[tid] + xin[(size_t)nd * 256 + tid];
  float s = v, s2 = v * v;
  for (int o = 32; o; o >>= 1) { s += __shfl_xor(s, o); s2 += __shfl_xor(s2, o); }
  if (lane == 0) { ws1[wv] = s; ws2[wv] = s2; }
  __syncthreads();
  float S1 = ws1[0] + ws1[1] + ws1[2] + ws1[3];
  float S2 = ws2[0] + ws2[1] + ws2[2] + ws2[3];
  float mean = S1 * (1.f / 256.f);
  float var = S2 * (1.f / 256.f) - mean * mean;
  float r = rsqrtf(var + 1e-5f);
  float y = (v - mean) * r * lng[tid] + lnb[tid];
  y = (y > 0.f) ? y : (expf(y) - 1.f);
  xout[(size_t)nd * 256 + tid] = y;
}

// ---------------- small row-dot heads ----------------
__global__ void k_rowdot(const float* __restrict__ in, const float* __restrict__ W,
                         const float* __restrict__ bias, float* __restrict__ out,
                         int rows, int K, int OC, int act) {
  int row = blockIdx.x * 4 + (threadIdx.x >> 6);
  if (row >= rows) return;
  int lane = threadIdx.x & 63;
  for (int o = 0; o < OC; o++) {
    float s = 0.f;
    for (int k = lane; k < K; k += 64) s += in[(size_t)row * K + k] * W[(size_t)k * OC + o];
    for (int off = 32; off; off >>= 1) s += __shfl_xor(s, off);
    if (lane == 0) {
      float v = s + bias[o];
      if (act == 3) v = tanhf(v) * 0.1f;
      else if (act == 4) v = 1.f / (1.f + expf(-v));
      out[(size_t)row * OC + o] = v;
    }
  }
}

// ---------------- sector attention pooling ----------------
__global__ __launch_bounds__(256) void k_sector_pool(
    const float* __restrict__ x, const float* __restrict__ sc,
    const int* __restrict__ bptr, float* __restrict__ se, int S) {
  const int s = blockIdx.x, tid = threadIdx.x, lane = tid & 63, wv = tid >> 6;
  const int rs = bptr[s], re = bptr[s + 1];
  const int cnt = re - rs;
  __shared__ float r1[4], r2[4], wch[256];
  float mx = -3e38f;
  for (int i = rs + tid; i < re; i += 256) mx = fmaxf(mx, sc[i]);
  for (int o = 32; o; o >>= 1) mx = fmaxf(mx, __shfl_xor(mx, o));
  if (lane == 0) r1[wv] = mx;
  __syncthreads();
  float m = fmaxf(fmaxf(r1[0], r1[1]), fmaxf(r1[2], r1[3]));
  if (cnt == 0) m = 0.f;
  float z = 0.f;
  for (int i = rs + tid; i < re; i += 256) z += expf(sc[i] - m);
  for (int o = 32; o; o >>= 1) z += __shfl_xor(z, o);
  if (lane == 0) r2[wv] = z;
  __syncthreads();
  float zinv = 1.f / (r2[0] + r2[1] + r2[2] + r2[3] + 1e-16f);
  float acc = 0.f;
  for (int base = rs; base < re; base += 256) {
    int i = base + tid;
    wch[tid] = (i < re) ? expf(sc[i] - m) * zinv : 0.f;
    __syncthreads();
    int lim = re - base; if (lim > 256) lim = 256;
    for (int q = 0; q < lim; q++) acc += wch[q] * x[(size_t)(base + q) * HD + tid];
    __syncthreads();
  }
  se[(size_t)s * HD + tid] = acc / fmaxf((float)cnt, 1.f);
}

// ---------------- comb = [x | se[batch]] ----------------
__global__ void k_comb(const float* __restrict__ x, const float* __restrict__ se,
                       const int* __restrict__ batch, float* __restrict__ comb, int n) {
  int total = n * 512;
  for (int i = blockIdx.x * blockDim.x + threadIdx.x; i < total; i += gridDim.x * blockDim.x) {
    int row = i >> 9, col = i & 511;
    comb[i] = (col < HD) ? x[(size_t)row * HD + col]
                         : se[(size_t)batch[row] * HD + (col - HD)];
  }
}

extern "C" void kernel_launch(void* const* d_in, const int* in_sizes, int n_in,
                              void* d_out, int out_size, void* d_ws, size_t ws_size,
                              hipStream_t stream) {
  const float* x_stock   = (const float*)d_in[0];
  const int*   ei_stock  = (const int*)d_in[1];
  const int*   batch     = (const int*)d_in[2];
  const int*   ei_sector = (const int*)d_in[4];
  const float* ln_feat_g = (const float*)d_in[5];
  const float* ln_feat_b = (const float*)d_in[6];
  const float* w_ih0 = (const float*)d_in[7];
  const float* w_hh0 = (const float*)d_in[8];
  const float* b_ih0 = (const float*)d_in[9];
  const float* b_hh0 = (const float*)d_in[10];
  const float* w_ih1 = (const float*)d_in[11];
  const float* w_hh1 = (const float*)d_in[12];
  const float* b_ih1 = (const float*)d_in[13];
  const float* b_hh1 = (const float*)d_in[14];
  const float* ln_t_g = (const float*)d_in[15];
  const float* ln_t_b = (const float*)d_in[16];
  const float* W_in = (const float*)d_in[17];
  const float* b_in = (const float*)d_in[18];
  const float* stock_Wl = (const float*)d_in[19];
  const float* stock_bl = (const float*)d_in[20];
  const float* stock_Wr = (const float*)d_in[21];
  const float* stock_br = (const float*)d_in[22];
  const float* stock_att = (const float*)d_in[23];
  const float* stock_bias = (const float*)d_in[24];
  const float* stock_g = (const float*)d_in[25];
  const float* stock_b = (const float*)d_in[26];
  const float* sector_Wl = (const float*)d_in[27];
  const float* sector_bl = (const float*)d_in[28];
  const float* sector_Wr = (const float*)d_in[29];
  const float* sector_br = (const float*)d_in[30];
  const float* sector_att = (const float*)d_in[31];
  const float* sector_bias = (const float*)d_in[32];
  const float* sector_g = (const float*)d_in[33];
  const float* sector_b = (const float*)d_in[34];
  const float* Wa1 = (const float*)d_in[35];
  const float* ba1 = (const float*)d_in[36];
  const float* Wa2 = (const float*)d_in[37];
  const float* ba2 = (const float*)d_in[38];
  const float* Wf  = (const float*)d_in[39];
  const float* bf  = (const float*)d_in[40];
  const float* gf  = (const float*)d_in[41];
  const float* bef = (const float*)d_in[42];
  const float* W_regf = (const float*)d_in[43];
  const float* b_regf = (const float*)d_in[44];
  const float* g_regf = (const float*)d_in[45];
  const float* be_regf = (const float*)d_in[46];
  const float* W_clff = (const float*)d_in[47];
  const float* b_clff = (const float*)d_in[48];
  const float* g_clff = (const float*)d_in[49];
  const float* be_clff = (const float*)d_in[50];
  const float* W_rnkf = (const float*)d_in[51];
  const float* b_rnkf = (const float*)d_in[52];
  const float* g_rnkf = (const float*)d_in[53];
  const float* be_rnkf = (const float*)d_in[54];
  const float* Wr1 = (const float*)d_in[55];
  const float* br1 = (const float*)d_in[56];
  const float* Wr2 = (const float*)d_in[57];
  const float* br2 = (const float*)d_in[58];
  const float* Wr3 = (const float*)d_in[59];
  const float* br3 = (const float*)d_in[60];
  const float* Wc1 = (const float*)d_in[61];
  const float* bc1 = (const float*)d_in[62];
  const float* Wc2 = (const float*)d_in[63];
  const float* bc2 = (const float*)d_in[64];
  const float* Wk1 = (const float*)d_in[65];
  const float* bk1 = (const float*)d_in[66];
  const float* Wk2 = (const float*)d_in[67];
  const float* bk2 = (const float*)d_in[68];

  const int N  = in_sizes[0] / (TT * FF);
  const int E  = in_sizes[1] / 2;
  const int S  = in_sizes[3] / HD;
  const int ES = in_sizes[4] / 2;
  const int Ep = E + N, ESp = ES + S;
  const int NT = N * TT;
  const int KT0 = 10, KT1 = 16;

  char* wsb = (char*)d_ws;
  size_t off = 0;
  auto alloc = [&](size_t bytes) -> char* {
    char* p = wsb + off;
    off += (bytes + 255) & ~(size_t)255;
    return p;
  };
  // zero-init group (h/c states)
  ushort* h0a = (ushort*)alloc((size_t)N * HD * 2);
  ushort* h1a = (ushort*)alloc((size_t)N * HD * 2);
  float*  c0  = (float*)alloc((size_t)N * HD * 4);
  float*  c1  = (float*)alloc((size_t)N * HD * 4);
  size_t zf_bytes = off;
  ushort* h0b = (ushort*)alloc((size_t)N * HD * 2);
  ushort* h1b = (ushort*)alloc((size_t)N * HD * 2);
  ushort* wt0 = (ushort*)alloc((size_t)8 * KT0 * 512 * 16);
  ushort* wt1 = (ushort*)alloc((size_t)8 * KT1 * 512 * 16);
  float* bcp0 = (float*)alloc(1024 * 4);
  float* bcp1 = (float*)alloc(1024 * 4);
  float* xA  = (float*)alloc((size_t)N * HD * 4);
  float* xB  = (float*)alloc((size_t)N * HD * 4);
  float* xlr = (float*)alloc((size_t)N * 512 * 4);     // xl|xr; later reused as comb
  float* scbuf = (float*)alloc((size_t)Ep * 4 * 4);    // per-edge scores; later reused as hA
  float* selr = (float*)alloc((size_t)S * 512 * 4);
  float* seA  = (float*)alloc((size_t)S * HD * 4);
  float* seB  = (float*)alloc((size_t)S * HD * 4);
  float* scpool = (float*)alloc((size_t)N * 4);
  // big region: xln (LSTM phase) then tmpY+headbuf (post-LSTM)
  char* bigraw = alloc((size_t)N * TT * FF * 2);
  ushort* xln    = (ushort*)bigraw;
  float*  tmpY   = (float*)bigraw;
  float*  headbuf = (float*)(bigraw + (size_t)N * HD * 4);
  size_t zi_start = off;
  int* cnt   = (int*)alloc((size_t)(N + 1) * 4);
  int* fill  = (int*)alloc((size_t)N * 4);
  int* cntS  = (int*)alloc((size_t)(S + 1) * 4);
  int* fillS = (int*)alloc((size_t)S * 4);
  int* bcnt  = (int*)alloc((size_t)(S + 1) * 4);
  size_t zi_bytes = off - zi_start;
  int* rowptr = (int*)alloc((size_t)(N + 1) * 4);
  int* esrc   = (int*)alloc((size_t)Ep * 4);
  int* rptrS  = (int*)alloc((size_t)(S + 1) * 4);
  int* esrcS  = (int*)alloc((size_t)ESp * 4);
  int* bptr   = (int*)alloc((size_t)(S + 1) * 4);

  float* hA   = scbuf;
  float* comb = xlr;
  float* t128 = tmpY;
  float* t64  = tmpY + (size_t)N * 128;
  float* out_ret = (float*)d_out;
  float* out_mov = out_ret + N;
  float* out_rnk = out_ret + 3 * (size_t)N;
  float* out_c   = out_ret + 4 * (size_t)N;

  hipMemsetAsync(d_ws, 0, zf_bytes, stream);
  hipMemsetAsync(wsb + zi_start, 0, zi_bytes, stream);

  auto gemm = [&](const float* A, int lda, const float* B, int ldb, const float* bias,
                  float* C, int ldc, int M, int Nn, int K, int act) {
    dim3 g((M + 127) / 128, Nn / 64);
    k_gemm<<<g, dim3(256), 0, stream>>>(A, lda, B, ldb, bias, C, ldc, M, Nn, K, act);
  };

  // 1. feature-LN + bf16 convert; prebuild tiled bf16 gate weights
  k_lncvt<<<dim3((NT + 3) / 4), dim3(256), 0, stream>>>(x_stock, ln_feat_g, ln_feat_b, xln, NT);
  k_build_wtile<<<dim3((8 * KT0 * 512 + 255) / 256), dim3(256), 0, stream>>>(w_ih0, w_hh0, wt0, FF, KT0);
  k_build_wtile<<<dim3((8 * KT1 * 512 + 255) / 256), dim3(256), 0, stream>>>(w_ih1, w_hh1, wt1, HD, KT1);
  k_build_bcp<<<dim3(4), dim3(256), 0, stream>>>(b_ih0, b_hh0, bcp0);
  k_build_bcp<<<dim3(4), dim3(256), 0, stream>>>(b_ih1, b_hh1, bcp1);

  // 2. LSTM via MFMA
  {
    const int MB = (N + 127) / 128;
    dim3 gl(MB, 8);
    ushort *h0c = h0a, *h0n = h0b, *h1c = h1a, *h1n = h1b;
    for (int t = 0; t < TT; t++) {
      k_lstm_mfma<0><<<gl, dim3(256), 0, stream>>>(xln, h0c, wt0, bcp0, c0, h0n, N, t);
      k_lstm_mfma<1><<<gl, dim3(256), 0, stream>>>(h0n, h1c, wt1, bcp1, c1, h1n, N, 0);
      ushort* tp = h0c; h0c = h0n; h0n = tp;
      tp = h1c; h1c = h1n; h1n = tp;
    }
    k_ln_rows_b16<<<dim3(N), dim3(256), 0, stream>>>(h1c, tmpY, ln_t_g, ln_t_b, N, 0);
  }
  gemm(tmpY, HD, W_in, HD, b_in, xA, HD, N, HD, HD, ACT_NONE);

  // 3. stock CSR (with self loops)
  k_hist_edges<<<dim3(2048), dim3(256), 0, stream>>>(ei_stock + E, E, N, cnt);
  k_scan_excl<<<dim3(1), dim3(1024), 0, stream>>>(cnt, rowptr, N);
  k_scatter_edges<<<dim3(2048), dim3(256), 0, stream>>>(ei_stock, ei_stock + E, E, N,
                                                        rowptr, fill, esrc);
  // 4. stock GAT x2
  float* xc = xA; float* xn = xB;
  for (int l = 0; l < 2; l++) {
    const float* Wl = stock_Wl + (size_t)l * HD * HD;
    const float* bl = stock_bl + (size_t)l * HD;
    const float* Wr = stock_Wr + (size_t)l * HD * HD;
    const float* br = stock_br + (size_t)l * HD;
    const float* at = stock_att + (size_t)l * HD;
    const float* bi = stock_bias + (size_t)l * HD;
    const float* lg = stock_g + (size_t)l * HD;
    const float* lb = stock_b + (size_t)l * HD;
    gemm(xc, HD, Wl, HD, bl, xlr, 512, N, HD, HD, ACT_NONE);
    gemm(xc, HD, Wr, HD, br, xlr + 256, 512, N, HD, HD, ACT_NONE);
    k_gat_node<<<dim3(N), dim3(256), 0, stream>>>(xc, xlr, rowptr, esrc, at, bi, lg, lb,
                                                  xn, scbuf, N);
    float* tp = xc; xc = xn; xn = tp;
  }
  // 5. attention pooling to sectors
  gemm(xc, HD, Wa1, 128, ba1, hA, 128, N, 128, HD, ACT_TANH);
  k_rowdot<<<dim3((N + 3) / 4), dim3(256), 0, stream>>>(hA, Wa2, ba2, scpool, N, 128, 1, 0);
  k_hist_arr<<<dim3(512), dim3(256), 0, stream>>>(batch, N, bcnt);
  k_scan_excl<<<dim3(1), dim3(1024), 0, stream>>>(bcnt, bptr, S);
  k_sector_pool<<<dim3(S), dim3(256), 0, stream>>>(xc, scpool, bptr, seA, S);
  // 6. sector CSR + GAT x2
  k_hist_edges<<<dim3(64), dim3(256), 0, stream>>>(ei_sector + ES, ES, S, cntS);
  k_scan_excl<<<dim3(1), dim3(1024), 0, stream>>>(cntS, rptrS, S);
  k_scatter_edges<<<dim3(64), dim3(256), 0, stream>>>(ei_sector, ei_sector + ES, ES, S,
                                                      rptrS, fillS, esrcS);
  float* sec = seA; float* sen = seB;
  for (int l = 0; l < 2; l++) {
    const float* Wl = sector_Wl + (size_t)l * HD * HD;
    const float* bl = sector_bl + (size_t)l * HD;
    const float* Wr = sector_Wr + (size_t)l * HD * HD;
    const float* br = sector_br + (size_t)l * HD;
    const float* at = sector_att + (size_t)l * HD;
    const float* bi = sector_bias + (size_t)l * HD;
    const float* lg = sector_g + (size_t)l * HD;
    const float* lb = sector_b + (size_t)l * HD;
    gemm(sec, HD, Wl, HD, bl, selr, 512, S, HD, HD, ACT_NONE);
    gemm(sec, HD, Wr, HD, br, selr + 256, 512, S, HD, HD, ACT_NONE);
    k_gat_node<<<dim3(S), dim3(256), 0, stream>>>(sec, selr, rptrS, esrcS, at, bi, lg, lb,
                                                  sen, scbuf, S);
    float* tp = sec; sec = sen; sen = tp;
  }
  // 7. fusion -> c (output)
  k_comb<<<dim3(4096), dim3(256), 0, stream>>>(xc, sec, batch, comb, N);
  gemm(comb, 512, Wf, HD, bf, tmpY, HD, N, HD, 512, ACT_NONE);
  k_ln_rows<<<dim3(N), dim3(256), 0, stream>>>(tmpY, out_c, gf, bef, N, 2);
  // 8a. regression head
  gemm(out_c, HD, W_regf, HD, b_regf, tmpY, HD, N, HD, HD, ACT_NONE);
  k_ln_rows<<<dim3(N), dim3(256), 0, stream>>>(tmpY, headbuf, g_regf, be_regf, N, 1);
  gemm(headbuf, HD, Wr1, 128, br1, t128, 128, N, 128, HD, ACT_RELU);
  gemm(t128, 128, Wr2, 64, br2, t64, 64, N, 64, 128, ACT_RELU);
  k_rowdot<<<dim3((N + 3) / 4), dim3(256), 0, stream>>>(t64, Wr3, br3, out_ret, N, 64, 1, 3);
  // 8b. classification head
  gemm(out_c, HD, W_clff, HD, b_clff, tmpY, HD, N, HD, HD, ACT_NONE);
  k_ln_rows<<<dim3(N), dim3(256), 0, stream>>>(tmpY, headbuf, g_clff, be_clff, N, 1);
  gemm(headbuf, HD, Wc1, 128, bc1, t128, 128, N, 128, HD, ACT_RELU);
  k_rowdot<<<dim3((N + 3) / 4), dim3(256), 0, stream>>>(t128, Wc2, bc2, out_mov, N, 128, 2, 0);
  // 8c. ranking head
  gemm(out_c, HD, W_rnkf, HD, b_rnkf, tmpY, HD, N, HD, HD, ACT_NONE);
  k_ln_rows<<<dim3(N), dim3(256), 0, stream>>>(tmpY, headbuf, g_rnkf, be_rnkf, N, 1);
  gemm(headbuf, HD, Wk1, 128, bk1, t128, 128, N, 128, HD, ACT_RELU);
  k_rowdot<<<dim3((N + 3) / 4), dim3(256), 0, stream>>>(t128, Wk2, bk2, out_rnk, N, 128, 1, 4);
}

// Round 3
// 3893.616 us; speedup vs baseline: 4.6088x; 1.1785x over previous
//
#include <hip/hip_runtime.h>
#include <stdint.h>

static constexpr int TT = 20;     // timesteps
static constexpr int FF = 64;     // input features
static constexpr int HD = 256;    // hidden dim

enum { ACT_NONE = 0, ACT_RELU = 1, ACT_TANH = 2 };

typedef __attribute__((ext_vector_type(8))) short short8;
typedef __attribute__((ext_vector_type(4))) float f32x4;

static __device__ __forceinline__ float sigf(float x) { return 1.f / (1.f + expf(-x)); }

static __device__ __forceinline__ ushort f2bf(float f) {
  uint32_t u = __float_as_uint(f);
  return (ushort)((u + 0x7fffu + ((u >> 16) & 1u)) >> 16);
}
static __device__ __forceinline__ float bf2f(ushort u) {
  return __uint_as_float(((uint32_t)u) << 16);
}
static __device__ __forceinline__ void gl16(const void* g, void* l) {
  __builtin_amdgcn_global_load_lds(
      (const __attribute__((address_space(1))) uint32_t*)g,
      (__attribute__((address_space(3))) uint32_t*)l, 16, 0, 0);
}

// ---------------- feature LN + bf16 convert: one wave per 64-wide row ----------------
__global__ void k_lncvt(const float* __restrict__ x, const float* __restrict__ g,
                        const float* __restrict__ b, ushort* __restrict__ y, int rows) {
  int row = blockIdx.x * 4 + (threadIdx.x >> 6);
  int lane = threadIdx.x & 63;
  if (row >= rows) return;
  float v = x[(size_t)row * 64 + lane];
  float s = v, s2 = v * v;
  for (int o = 32; o; o >>= 1) { s += __shfl_xor(s, o); s2 += __shfl_xor(s2, o); }
  float m = s * (1.f / 64.f);
  float var = s2 * (1.f / 64.f) - m * m;
  float rs = rsqrtf(var + 1e-5f);
  y[(size_t)row * 64 + lane] = f2bf((v - m) * rs * g[lane] + b[lane]);
}

// ---------------- build pre-tiled/swizzled bf16 gate weights (LSTM) ----------------
__global__ void k_build_wtile(const float* __restrict__ w_ih, const float* __restrict__ w_hh,
                              ushort* __restrict__ wt, int KI, int KT) {
  int total = 8 * KT * 512;
  for (int idx = blockIdx.x * blockDim.x + threadIdx.x; idx < total;
       idx += gridDim.x * blockDim.x) {
    int nb = idx / (KT * 512);
    int rem = idx % (KT * 512);
    int kt = rem / 512;
    int q = rem % 512;
    int r = q >> 2, csw = q & 3;
    int ch = csw ^ ((r >> 1) & 3);
    int col = nb * 128 + r;
    int hdblk = col >> 6, gg = (col >> 4) & 3, hd = hdblk * 16 + (col & 15);
    int orow = gg * HD + hd;
    int k = kt * 32 + ch * 8;
    const float* src = (k < KI) ? (w_ih + (size_t)orow * KI + k)
                                : (w_hh + (size_t)orow * HD + (k - KI));
    ushort* dst = wt + (size_t)idx * 8;
#pragma unroll
    for (int j = 0; j < 8; j++) dst[j] = f2bf(src[j]);
  }
}

__global__ void k_build_bcp(const float* __restrict__ bi, const float* __restrict__ bh,
                            float* __restrict__ bcp) {
  int col = blockIdx.x * blockDim.x + threadIdx.x;
  if (col >= 1024) return;
  int hdblk = col >> 6, gg = (col >> 4) & 3, hd = hdblk * 16 + (col & 15);
  int orow = gg * HD + hd;
  bcp[col] = bi[orow] + bh[orow];
}

// ---------------- build tiled bf16 B for generic GEMM: B f32 [K][Nn] -> [nb][kt][512]x8 ----------------
__global__ void k_build_btile(const float* __restrict__ B, ushort* __restrict__ bt,
                              int K, int Nn, int NB) {
  int KTb = K / 32;
  int total = NB * KTb * 512;
  for (int idx = blockIdx.x * blockDim.x + threadIdx.x; idx < total;
       idx += gridDim.x * blockDim.x) {
    int nb = idx / (KTb * 512);
    int rem = idx % (KTb * 512);
    int kt = rem / 512;
    int q = rem % 512;
    int r = q >> 2, csw = q & 3;
    int ch = csw ^ ((r >> 1) & 3);
    int col = nb * 128 + r;
    int k = kt * 32 + ch * 8;
    ushort* dst = bt + (size_t)idx * 8;
#pragma unroll
    for (int j = 0; j < 8; j++)
      dst[j] = (col < Nn) ? f2bf(B[(size_t)(k + j) * Nn + col]) : (ushort)0;
  }
}

// ---------------- MFMA LSTM step ----------------
template <int LAYER>
__global__ __launch_bounds__(256) void k_lstm_mfma(
    const ushort* __restrict__ a0, const ushort* __restrict__ a1,
    const ushort* __restrict__ wt, const float* __restrict__ bcp,
    float* __restrict__ cst, ushort* __restrict__ hnext, int M, int t) {
  constexpr int K = (LAYER == 0) ? 320 : 512;
  constexpr int KT = K / 32;
  constexpr int SEG0 = (LAYER == 0) ? 64 : 256;
  constexpr int LDA0 = (LAYER == 0) ? (TT * FF) : HD;
  __shared__ ushort At[128 * 32];
  __shared__ ushort Bt[128 * 32];
  const int tid = threadIdx.x;
  const int lane = tid & 63, wid = tid >> 6;
  const int wr = wid >> 1, wc = wid & 1;
  const int m0 = blockIdx.x * 128;
  const int nb = blockIdx.y;
  const int a0t = (LAYER == 0) ? t * FF : 0;

  f32x4 acc[4][4];
#pragma unroll
  for (int i = 0; i < 4; i++)
#pragma unroll
    for (int j = 0; j < 4; j++) acc[i][j] = (f32x4){0.f, 0.f, 0.f, 0.f};

  int rown[2], chn[2];
#pragma unroll
  for (int e = 0; e < 2; e++) {
    int q = e * 256 + tid;
    int r = q >> 2, csw = q & 3;
    rown[e] = r;
    chn[e] = csw ^ ((r >> 1) & 3);
  }
  const size_t wtbase = (size_t)nb * KT * 512;

  for (int kt = 0; kt < KT; ++kt) {
    __syncthreads();
    const int k0 = kt * 32;
#pragma unroll
    for (int e = 0; e < 2; e++) {
      int q = e * 256 + tid;
      int r = rown[e];
      int kg = k0 + chn[e] * 8;
      int grow = m0 + r;
      grow = (grow < M) ? grow : (M - 1);
      const ushort* src = (kg < SEG0)
                              ? (a0 + (size_t)grow * LDA0 + a0t + kg)
                              : (a1 + (size_t)grow * HD + (kg - SEG0));
      gl16(src, &At[q * 8]);
      gl16(wt + (wtbase + (size_t)kt * 512 + q) * 8, &Bt[q * 8]);
    }
    __syncthreads();
    short8 af[4], bfr[4];
#pragma unroll
    for (int i = 0; i < 4; i++) {
      int rA = wr * 64 + i * 16 + (lane & 15);
      int swa = (lane >> 4) ^ ((rA >> 1) & 3);
      af[i] = *(const short8*)&At[rA * 32 + swa * 8];
      int rB = wc * 64 + i * 16 + (lane & 15);
      int swb = (lane >> 4) ^ ((rB >> 1) & 3);
      bfr[i] = *(const short8*)&Bt[rB * 32 + swb * 8];
    }
#pragma unroll
    for (int i = 0; i < 4; i++)
#pragma unroll
      for (int j = 0; j < 4; j++)
        acc[i][j] = __builtin_amdgcn_mfma_f32_16x16x32_bf16(af[i], bfr[j], acc[i][j], 0, 0, 0);
  }
  const int hdlo = lane & 15;
  const int rb = (lane >> 4) * 4;
  const int colb = nb * 128 + wc * 64;
  const float bI = bcp[colb + hdlo];
  const float bF = bcp[colb + 16 + hdlo];
  const float bG = bcp[colb + 32 + hdlo];
  const float bO = bcp[colb + 48 + hdlo];
  const int hd = (nb * 2 + wc) * 16 + hdlo;
#pragma unroll
  for (int i = 0; i < 4; i++) {
#pragma unroll
    for (int r = 0; r < 4; r++) {
      int row = m0 + wr * 64 + i * 16 + rb + r;
      if (row >= M) continue;
      float gi = acc[i][0][r] + bI;
      float gf = acc[i][1][r] + bF;
      float gg = acc[i][2][r] + bG;
      float go = acc[i][3][r] + bO;
      size_t ix = (size_t)row * HD + hd;
      float c = sigf(gf) * cst[ix] + sigf(gi) * tanhf(gg);
      cst[ix] = c;
      hnext[ix] = f2bf(sigf(go) * tanhf(c));
    }
  }
}

// ---------------- generic bf16 MFMA GEMM: C = act(A@B + bias) ----------------
// A: f32 [M][lda] (converted in staging). Bt: pre-tiled bf16. 128x128 tile, 4 waves.
template <bool BF16OUT>
__global__ __launch_bounds__(256) void k_gemm_mfma(
    const float* __restrict__ A, int lda, const ushort* __restrict__ BtG,
    const float* __restrict__ bias, void* __restrict__ Cv, int ldc,
    int M, int Nn, int K, int act) {
  const int KTb = K / 32;
  __shared__ ushort At[128 * 32];
  __shared__ ushort Bts[128 * 32];
  const int tid = threadIdx.x;
  const int lane = tid & 63, wid = tid >> 6;
  const int wr = wid >> 1, wc = wid & 1;
  const int m0 = blockIdx.x * 128;
  const int nb = blockIdx.y;

  f32x4 acc[4][4];
#pragma unroll
  for (int i = 0; i < 4; i++)
#pragma unroll
    for (int j = 0; j < 4; j++) acc[i][j] = (f32x4){0.f, 0.f, 0.f, 0.f};

  const size_t btbase = (size_t)nb * KTb * 512;

  for (int kt = 0; kt < KTb; ++kt) {
    __syncthreads();
    const int k0 = kt * 32;
#pragma unroll
    for (int e = 0; e < 2; e++) {
      int q = e * 256 + tid;
      int r = q >> 2, csw = q & 3;
      int ch = csw ^ ((r >> 1) & 3);
      int row = m0 + r;
      row = (row < M) ? row : (M - 1);
      const float* src = A + (size_t)row * lda + k0 + ch * 8;
      float4 f0 = *(const float4*)src;
      float4 f1 = *(const float4*)(src + 4);
      short8 s;
      s[0] = (short)f2bf(f0.x); s[1] = (short)f2bf(f0.y);
      s[2] = (short)f2bf(f0.z); s[3] = (short)f2bf(f0.w);
      s[4] = (short)f2bf(f1.x); s[5] = (short)f2bf(f1.y);
      s[6] = (short)f2bf(f1.z); s[7] = (short)f2bf(f1.w);
      *(short8*)&At[q * 8] = s;
      gl16(BtG + (btbase + (size_t)kt * 512 + q) * 8, &Bts[q * 8]);
    }
    __syncthreads();
    short8 af[4], bfr[4];
#pragma unroll
    for (int i = 0; i < 4; i++) {
      int rA = wr * 64 + i * 16 + (lane & 15);
      int swa = (lane >> 4) ^ ((rA >> 1) & 3);
      af[i] = *(const short8*)&At[rA * 32 + swa * 8];
      int rB = wc * 64 + i * 16 + (lane & 15);
      int swb = (lane >> 4) ^ ((rB >> 1) & 3);
      bfr[i] = *(const short8*)&Bts[rB * 32 + swb * 8];
    }
#pragma unroll
    for (int i = 0; i < 4; i++)
#pragma unroll
      for (int j = 0; j < 4; j++)
        acc[i][j] = __builtin_amdgcn_mfma_f32_16x16x32_bf16(af[i], bfr[j], acc[i][j], 0, 0, 0);
  }
  const int rb = (lane >> 4) * 4;
  const int cl = lane & 15;
#pragma unroll
  for (int i = 0; i < 4; i++) {
#pragma unroll
    for (int j = 0; j < 4; j++) {
      int col = nb * 128 + wc * 64 + j * 16 + cl;
      if (col >= Nn) continue;
      float bv = bias[col];
#pragma unroll
      for (int r = 0; r < 4; r++) {
        int row = m0 + wr * 64 + i * 16 + rb + r;
        if (row >= M) continue;
        float v = acc[i][j][r] + bv;
        if (act == ACT_RELU) v = fmaxf(v, 0.f);
        else if (act == ACT_TANH) v = tanhf(v);
        if (BF16OUT) ((ushort*)Cv)[(size_t)row * ldc + col] = f2bf(v);
        else ((float*)Cv)[(size_t)row * ldc + col] = v;
      }
    }
  }
}

// ---------------- per-row LN over 256 + optional act (0 none, 1 relu, 2 elu) ----------------
__global__ __launch_bounds__(256) void k_ln_rows(
    const float* __restrict__ in, float* __restrict__ out,
    const float* __restrict__ g, const float* __restrict__ b, int rows, int act) {
  int row = blockIdx.x;
  if (row >= rows) return;
  int tid = threadIdx.x, lane = tid & 63, wv = tid >> 6;
  float v = in[(size_t)row * HD + tid];
  float s = v, s2 = v * v;
  for (int o = 32; o; o >>= 1) { s += __shfl_xor(s, o); s2 += __shfl_xor(s2, o); }
  __shared__ float ws1[4], ws2[4];
  if (lane == 0) { ws1[wv] = s; ws2[wv] = s2; }
  __syncthreads();
  float S1 = ws1[0] + ws1[1] + ws1[2] + ws1[3];
  float S2 = ws2[0] + ws2[1] + ws2[2] + ws2[3];
  float m = S1 * (1.f / 256.f);
  float var = S2 * (1.f / 256.f) - m * m;
  float r = rsqrtf(var + 1e-5f);
  float y = (v - m) * r * g[tid] + b[tid];
  if (act == 1) y = fmaxf(y, 0.f);
  else if (act == 2) y = (y > 0.f) ? y : (expf(y) - 1.f);
  out[(size_t)row * HD + tid] = y;
}

__global__ __launch_bounds__(256) void k_ln_rows_b16(
    const ushort* __restrict__ in, float* __restrict__ out,
    const float* __restrict__ g, const float* __restrict__ b, int rows, int act) {
  int row = blockIdx.x;
  if (row >= rows) return;
  int tid = threadIdx.x, lane = tid & 63, wv = tid >> 6;
  float v = bf2f(in[(size_t)row * HD + tid]);
  float s = v, s2 = v * v;
  for (int o = 32; o; o >>= 1) { s += __shfl_xor(s, o); s2 += __shfl_xor(s2, o); }
  __shared__ float ws1[4], ws2[4];
  if (lane == 0) { ws1[wv] = s; ws2[wv] = s2; }
  __syncthreads();
  float S1 = ws1[0] + ws1[1] + ws1[2] + ws1[3];
  float S2 = ws2[0] + ws2[1] + ws2[2] + ws2[3];
  float m = S1 * (1.f / 256.f);
  float var = S2 * (1.f / 256.f) - m * m;
  float r = rsqrtf(var + 1e-5f);
  float y = (v - m) * r * g[tid] + b[tid];
  if (act == 1) y = fmaxf(y, 0.f);
  else if (act == 2) y = (y > 0.f) ? y : (expf(y) - 1.f);
  out[(size_t)row * HD + tid] = y;
}

// ---------------- CSR build ----------------
__global__ void k_hist_edges(const int* __restrict__ dst, int E, int n, int* __restrict__ cnt) {
  int tot = E + n;
  for (int i = blockIdx.x * blockDim.x + threadIdx.x; i < tot; i += gridDim.x * blockDim.x) {
    int d = (i < E) ? dst[i] : (i - E);
    atomicAdd(&cnt[d], 1);
  }
}

__global__ void k_hist_arr(const int* __restrict__ a, int n, int* __restrict__ cnt) {
  for (int i = blockIdx.x * blockDim.x + threadIdx.x; i < n; i += gridDim.x * blockDim.x)
    atomicAdd(&cnt[a[i]], 1);
}

__global__ void k_scan_excl(const int* __restrict__ cnt, int* __restrict__ ptr, int n) {
  __shared__ int sm[1024];
  __shared__ int carry_s;
  int tid = threadIdx.x;
  if (tid == 0) carry_s = 0;
  __syncthreads();
  for (int base = 0; base < n; base += 1024) {
    int i = base + tid;
    int v = (i < n) ? cnt[i] : 0;
    sm[tid] = v;
    __syncthreads();
    for (int off = 1; off < 1024; off <<= 1) {
      int tval = (tid >= off) ? sm[tid - off] : 0;
      __syncthreads();
      sm[tid] += tval;
      __syncthreads();
    }
    int carry = carry_s;
    if (i < n) ptr[i] = carry + sm[tid] - v;
    __syncthreads();
    if (tid == 1023) carry_s = carry + sm[1023];
    __syncthreads();
  }
  if (tid == 0) ptr[n] = carry_s;
}

__global__ void k_scatter_edges(const int* __restrict__ src, const int* __restrict__ dst,
                                int E, int n, const int* __restrict__ rowptr,
                                int* __restrict__ fill, int* __restrict__ esrc) {
  int tot = E + n;
  for (int i = blockIdx.x * blockDim.x + threadIdx.x; i < tot; i += gridDim.x * blockDim.x) {
    int d, s;
    if (i < E) { d = dst[i]; s = src[i]; } else { d = i - E; s = i - E; }
    int pos = rowptr[d] + atomicAdd(&fill[d], 1);
    esrc[pos] = s;
  }
}

// ---------------- fused GATv2 layer (bf16 xl/xr), one block per dst node ----------------
__global__ __launch_bounds__(256) void k_gat_node(
    const float* __restrict__ xin, const ushort* __restrict__ xlr,
    const int* __restrict__ rowptr, const int* __restrict__ esrc,
    const float* __restrict__ att, const float* __restrict__ bias,
    const float* __restrict__ lng, const float* __restrict__ lnb,
    float* __restrict__ xout, float* __restrict__ scbuf, int n_nodes) {
  const int nd = blockIdx.x;
  const int tid = threadIdx.x, lane = tid & 63, wv = tid >> 6;
  __shared__ float xr_s[256], att_s[256], out_s[256];
  __shared__ float wred[4][4], zred[4][4];
  __shared__ float ws1[4], ws2[4];
  xr_s[tid] = bf2f(xlr[(size_t)nd * 512 + 256 + tid]);
  att_s[tid] = att[tid];
  out_s[tid] = 0.f;
  __syncthreads();
  const int rs = rowptr[nd];
  const int deg = rowptr[nd + 1] - rs;
  float wmax[4] = {-3e38f, -3e38f, -3e38f, -3e38f};
  for (int p = wv; p < deg; p += 4) {
    const ushort* xl = xlr + (size_t)esrc[rs + p] * 512;
    float sh[4];
#pragma unroll
    for (int h = 0; h < 4; h++) {
      float v = bf2f(xl[h * 64 + lane]) + xr_s[h * 64 + lane];
      v = (v > 0.f) ? v : 0.2f * v;
      sh[h] = v * att_s[h * 64 + lane];
    }
#pragma unroll
    for (int h = 0; h < 4; h++) {
      for (int o = 32; o; o >>= 1) sh[h] += __shfl_xor(sh[h], o);
      wmax[h] = fmaxf(wmax[h], sh[h]);
    }
    if (lane == 0) {
#pragma unroll
      for (int h = 0; h < 4; h++) scbuf[(size_t)(rs + p) * 4 + h] = sh[h];
    }
  }
  if (lane == 0) {
#pragma unroll
    for (int h = 0; h < 4; h++) wred[wv][h] = wmax[h];
  }
  __syncthreads();
  float m[4];
#pragma unroll
  for (int h = 0; h < 4; h++)
    m[h] = fmaxf(fmaxf(wred[0][h], wred[1][h]), fmaxf(wred[2][h], wred[3][h]));
  float zl[4] = {0, 0, 0, 0};
  for (int p = tid; p < deg; p += 256) {
#pragma unroll
    for (int h = 0; h < 4; h++) zl[h] += expf(scbuf[(size_t)(rs + p) * 4 + h] - m[h]);
  }
#pragma unroll
  for (int h = 0; h < 4; h++)
    for (int o = 32; o; o >>= 1) zl[h] += __shfl_xor(zl[h], o);
  if (lane == 0) {
#pragma unroll
    for (int h = 0; h < 4; h++) zred[wv][h] = zl[h];
  }
  __syncthreads();
  float zinv[4];
#pragma unroll
  for (int h = 0; h < 4; h++)
    zinv[h] = 1.f / (zred[0][h] + zred[1][h] + zred[2][h] + zred[3][h] + 1e-16f);
  float acc[4] = {0, 0, 0, 0};
  for (int p = wv; p < deg; p += 4) {
    const ushort* xl = xlr + (size_t)esrc[rs + p] * 512;
#pragma unroll
    for (int h = 0; h < 4; h++) {
      float wgt = expf(scbuf[(size_t)(rs + p) * 4 + h] - m[h]) * zinv[h];
      acc[h] += wgt * bf2f(xl[h * 64 + lane]);
    }
  }
#pragma unroll
  for (int h = 0; h < 4; h++) atomicAdd(&out_s[h * 64 + lane], acc[h]);
  __syncthreads();
  float v = out_s[tid] + bias[tid] + xin[(size_t)nd * 256 + tid];
  float s = v, s2 = v * v;
  for (int o = 32; o; o >>= 1) { s += __shfl_xor(s, o); s2 += __shfl_xor(s2, o); }
  if (lane == 0) { ws1[wv] = s; ws2[wv] = s2; }
  __syncthreads();
  float S1 = ws1[0] + ws1[1] + ws1[2] + ws1[3];
  float S2 = ws2[0] + ws2[1] + ws2[2] + ws2[3];
  float mean = S1 * (1.f / 256.f);
  float var = S2 * (1.f / 256.f) - mean * mean;
  float r = rsqrtf(var + 1e-5f);
  float y = (v - mean) * r * lng[tid] + lnb[tid];
  y = (y > 0.f) ? y : (expf(y) - 1.f);
  xout[(size_t)nd * 256 + tid] = y;
}

// ---------------- small row-dot heads ----------------
__global__ void k_rowdot(const float* __restrict__ in, const float* __restrict__ W,
                         const float* __restrict__ bias, float* __restrict__ out,
                         int rows, int K, int OC, int act) {
  int row = blockIdx.x * 4 + (threadIdx.x >> 6);
  if (row >= rows) return;
  int lane = threadIdx.x & 63;
  for (int o = 0; o < OC; o++) {
    float s = 0.f;
    for (int k = lane; k < K; k += 64) s += in[(size_t)row * K + k] * W[(size_t)k * OC + o];
    for (int off = 32; off; off >>= 1) s += __shfl_xor(s, off);
    if (lane == 0) {
      float v = s + bias[o];
      if (act == 3) v = tanhf(v) * 0.1f;
      else if (act == 4) v = 1.f / (1.f + expf(-v));
      out[(size_t)row * OC + o] = v;
    }
  }
}

// ---------------- sector attention pooling ----------------
__global__ __launch_bounds__(256) void k_sector_pool(
    const float* __restrict__ x, const float* __restrict__ sc,
    const int* __restrict__ bptr, float* __restrict__ se, int S) {
  const int s = blockIdx.x, tid = threadIdx.x, lane = tid & 63, wv = tid >> 6;
  const int rs = bptr[s], re = bptr[s + 1];
  const int cnt = re - rs;
  __shared__ float r1[4], r2[4], wch[256];
  float mx = -3e38f;
  for (int i = rs + tid; i < re; i += 256) mx = fmaxf(mx, sc[i]);
  for (int o = 32; o; o >>= 1) mx = fmaxf(mx, __shfl_xor(mx, o));
  if (lane == 0) r1[wv] = mx;
  __syncthreads();
  float m = fmaxf(fmaxf(r1[0], r1[1]), fmaxf(r1[2], r1[3]));
  if (cnt == 0) m = 0.f;
  float z = 0.f;
  for (int i = rs + tid; i < re; i += 256) z += expf(sc[i] - m);
  for (int o = 32; o; o >>= 1) z += __shfl_xor(z, o);
  if (lane == 0) r2[wv] = z;
  __syncthreads();
  float zinv = 1.f / (r2[0] + r2[1] + r2[2] + r2[3] + 1e-16f);
  float acc = 0.f;
  for (int base = rs; base < re; base += 256) {
    int i = base + tid;
    wch[tid] = (i < re) ? expf(sc[i] - m) * zinv : 0.f;
    __syncthreads();
    int lim = re - base; if (lim > 256) lim = 256;
    for (int q = 0; q < lim; q++) acc += wch[q] * x[(size_t)(base + q) * HD + tid];
    __syncthreads();
  }
  se[(size_t)s * HD + tid] = acc / fmaxf((float)cnt, 1.f);
}

// ---------------- comb = [x | se[batch]] ----------------
__global__ void k_comb(const float* __restrict__ x, const float* __restrict__ se,
                       const int* __restrict__ batch, float* __restrict__ comb, int n) {
  int total = n * 512;
  for (int i = blockIdx.x * blockDim.x + threadIdx.x; i < total; i += gridDim.x * blockDim.x) {
    int row = i >> 9, col = i & 511;
    comb[i] = (col < HD) ? x[(size_t)row * HD + col]
                         : se[(size_t)batch[row] * HD + (col - HD)];
  }
}

extern "C" void kernel_launch(void* const* d_in, const int* in_sizes, int n_in,
                              void* d_out, int out_size, void* d_ws, size_t ws_size,
                              hipStream_t stream) {
  const float* x_stock   = (const float*)d_in[0];
  const int*   ei_stock  = (const int*)d_in[1];
  const int*   batch     = (const int*)d_in[2];
  const int*   ei_sector = (const int*)d_in[4];
  const float* ln_feat_g = (const float*)d_in[5];
  const float* ln_feat_b = (const float*)d_in[6];
  const float* w_ih0 = (const float*)d_in[7];
  const float* w_hh0 = (const float*)d_in[8];
  const float* b_ih0 = (const float*)d_in[9];
  const float* b_hh0 = (const float*)d_in[10];
  const float* w_ih1 = (const float*)d_in[11];
  const float* w_hh1 = (const float*)d_in[12];
  const float* b_ih1 = (const float*)d_in[13];
  const float* b_hh1 = (const float*)d_in[14];
  const float* ln_t_g = (const float*)d_in[15];
  const float* ln_t_b = (const float*)d_in[16];
  const float* W_in = (const float*)d_in[17];
  const float* b_in = (const float*)d_in[18];
  const float* stock_Wl = (const float*)d_in[19];
  const float* stock_bl = (const float*)d_in[20];
  const float* stock_Wr = (const float*)d_in[21];
  const float* stock_br = (const float*)d_in[22];
  const float* stock_att = (const float*)d_in[23];
  const float* stock_bias = (const float*)d_in[24];
  const float* stock_g = (const float*)d_in[25];
  const float* stock_b = (const float*)d_in[26];
  const float* sector_Wl = (const float*)d_in[27];
  const float* sector_bl = (const float*)d_in[28];
  const float* sector_Wr = (const float*)d_in[29];
  const float* sector_br = (const float*)d_in[30];
  const float* sector_att = (const float*)d_in[31];
  const float* sector_bias = (const float*)d_in[32];
  const float* sector_g = (const float*)d_in[33];
  const float* sector_b = (const float*)d_in[34];
  const float* Wa1 = (const float*)d_in[35];
  const float* ba1 = (const float*)d_in[36];
  const float* Wa2 = (const float*)d_in[37];
  const float* ba2 = (const float*)d_in[38];
  const float* Wf  = (const float*)d_in[39];
  const float* bf  = (const float*)d_in[40];
  const float* gf  = (const float*)d_in[41];
  const float* bef = (const float*)d_in[42];
  const float* W_regf = (const float*)d_in[43];
  const float* b_regf = (const float*)d_in[44];
  const float* g_regf = (const float*)d_in[45];
  const float* be_regf = (const float*)d_in[46];
  const float* W_clff = (const float*)d_in[47];
  const float* b_clff = (const float*)d_in[48];
  const float* g_clff = (const float*)d_in[49];
  const float* be_clff = (const float*)d_in[50];
  const float* W_rnkf = (const float*)d_in[51];
  const float* b_rnkf = (const float*)d_in[52];
  const float* g_rnkf = (const float*)d_in[53];
  const float* be_rnkf = (const float*)d_in[54];
  const float* Wr1 = (const float*)d_in[55];
  const float* br1 = (const float*)d_in[56];
  const float* Wr2 = (const float*)d_in[57];
  const float* br2 = (const float*)d_in[58];
  const float* Wr3 = (const float*)d_in[59];
  const float* br3 = (const float*)d_in[60];
  const float* Wc1 = (const float*)d_in[61];
  const float* bc1 = (const float*)d_in[62];
  const float* Wc2 = (const float*)d_in[63];
  const float* bc2 = (const float*)d_in[64];
  const float* Wk1 = (const float*)d_in[65];
  const float* bk1 = (const float*)d_in[66];
  const float* Wk2 = (const float*)d_in[67];
  const float* bk2 = (const float*)d_in[68];

  const int N  = in_sizes[0] / (TT * FF);
  const int E  = in_sizes[1] / 2;
  const int S  = in_sizes[3] / HD;
  const int ES = in_sizes[4] / 2;
  const int Ep = E + N, ESp = ES + S;
  const int NT = N * TT;
  const int KT0 = 10, KT1 = 16;

  char* wsb = (char*)d_ws;
  size_t off = 0;
  auto alloc = [&](size_t bytes) -> char* {
    char* p = wsb + off;
    off += (bytes + 255) & ~(size_t)255;
    return p;
  };
  // zero-init group (h/c states)
  ushort* h0a = (ushort*)alloc((size_t)N * HD * 2);
  ushort* h1a = (ushort*)alloc((size_t)N * HD * 2);
  float*  c0  = (float*)alloc((size_t)N * HD * 4);
  float*  c1  = (float*)alloc((size_t)N * HD * 4);
  size_t zf_bytes = off;
  ushort* h0b = (ushort*)alloc((size_t)N * HD * 2);
  ushort* h1b = (ushort*)alloc((size_t)N * HD * 2);
  ushort* wt0 = (ushort*)alloc((size_t)8 * KT0 * 512 * 16);
  ushort* wt1 = (ushort*)alloc((size_t)8 * KT1 * 512 * 16);
  float* bcp0 = (float*)alloc(1024 * 4);
  float* bcp1 = (float*)alloc(1024 * 4);
  float* xA  = (float*)alloc((size_t)N * HD * 4);
  float* xB  = (float*)alloc((size_t)N * HD * 4);
  char*  xlr_raw = alloc((size_t)N * 512 * 4);          // bf16 xl|xr; later f32 comb
  float* scbuf = (float*)alloc((size_t)Ep * 4 * 4);     // per-edge scores; later hA
  char*  selr_raw = alloc((size_t)S * 512 * 4);
  float* seA  = (float*)alloc((size_t)S * HD * 4);
  float* seB  = (float*)alloc((size_t)S * HD * 4);
  float* scpool = (float*)alloc((size_t)N * 4);
  // big region: xln (LSTM phase) then tmpY+headbuf (post-LSTM)
  char* bigraw = alloc((size_t)N * TT * FF * 2);
  ushort* xln    = (ushort*)bigraw;
  float*  tmpY   = (float*)bigraw;
  float*  headbuf = (float*)(bigraw + (size_t)N * HD * 4);
  // tiled bf16 weights for generic GEMMs
  auto alloc_bt = [&](int K, int Nn) -> ushort* {
    int NB = (Nn + 127) / 128;
    return (ushort*)alloc((size_t)NB * (K / 32) * 512 * 16);
  };
  ushort* bt_Win  = alloc_bt(256, 256);
  ushort* bt_sWl0 = alloc_bt(256, 256);
  ushort* bt_sWr0 = alloc_bt(256, 256);
  ushort* bt_sWl1 = alloc_bt(256, 256);
  ushort* bt_sWr1 = alloc_bt(256, 256);
  ushort* bt_eWl0 = alloc_bt(256, 256);
  ushort* bt_eWr0 = alloc_bt(256, 256);
  ushort* bt_eWl1 = alloc_bt(256, 256);
  ushort* bt_eWr1 = alloc_bt(256, 256);
  ushort* bt_Wa1  = alloc_bt(256, 128);
  ushort* bt_Wf   = alloc_bt(512, 256);
  ushort* bt_Wreg = alloc_bt(256, 256);
  ushort* bt_Wclf = alloc_bt(256, 256);
  ushort* bt_Wrnk = alloc_bt(256, 256);
  ushort* bt_Wr1  = alloc_bt(256, 128);
  ushort* bt_Wr2  = alloc_bt(128, 64);
  ushort* bt_Wc1  = alloc_bt(256, 128);
  ushort* bt_Wk1  = alloc_bt(256, 128);
  size_t zi_start = off;
  int* cnt   = (int*)alloc((size_t)(N + 1) * 4);
  int* fill  = (int*)alloc((size_t)N * 4);
  int* cntS  = (int*)alloc((size_t)(S + 1) * 4);
  int* fillS = (int*)alloc((size_t)S * 4);
  int* bcnt  = (int*)alloc((size_t)(S + 1) * 4);
  size_t zi_bytes = off - zi_start;
  int* rowptr = (int*)alloc((size_t)(N + 1) * 4);
  int* esrc   = (int*)alloc((size_t)Ep * 4);
  int* rptrS  = (int*)alloc((size_t)(S + 1) * 4);
  int* esrcS  = (int*)alloc((size_t)ESp * 4);
  int* bptr   = (int*)alloc((size_t)(S + 1) * 4);

  ushort* xlr_b = (ushort*)xlr_raw;
  float*  comb  = (float*)xlr_raw;
  ushort* selr_b = (ushort*)selr_raw;
  float* hA   = scbuf;
  float* t128 = tmpY;
  float* t64  = tmpY + (size_t)N * 128;
  float* out_ret = (float*)d_out;
  float* out_mov = out_ret + N;
  float* out_rnk = out_ret + 3 * (size_t)N;
  float* out_c   = out_ret + 4 * (size_t)N;

  hipMemsetAsync(d_ws, 0, zf_bytes, stream);
  hipMemsetAsync(wsb + zi_start, 0, zi_bytes, stream);

  auto build_bt = [&](const float* W, ushort* bt, int K, int Nn) {
    int NB = (Nn + 127) / 128;
    int total = NB * (K / 32) * 512;
    k_build_btile<<<dim3((total + 255) / 256), dim3(256), 0, stream>>>(W, bt, K, Nn, NB);
  };
  auto gemm_f = [&](const float* A, int lda, const ushort* bt, const float* bias,
                    float* C, int ldc, int M, int Nn, int K, int act) {
    dim3 g((M + 127) / 128, (Nn + 127) / 128);
    k_gemm_mfma<false><<<g, dim3(256), 0, stream>>>(A, lda, bt, bias, C, ldc, M, Nn, K, act);
  };
  auto gemm_b = [&](const float* A, int lda, const ushort* bt, const float* bias,
                    ushort* C, int ldc, int M, int Nn, int K, int act) {
    dim3 g((M + 127) / 128, (Nn + 127) / 128);
    k_gemm_mfma<true><<<g, dim3(256), 0, stream>>>(A, lda, bt, bias, C, ldc, M, Nn, K, act);
  };

  // 1. feature-LN + bf16 convert; prebuild all tiled bf16 weights
  k_lncvt<<<dim3((NT + 3) / 4), dim3(256), 0, stream>>>(x_stock, ln_feat_g, ln_feat_b, xln, NT);
  k_build_wtile<<<dim3((8 * KT0 * 512 + 255) / 256), dim3(256), 0, stream>>>(w_ih0, w_hh0, wt0, FF, KT0);
  k_build_wtile<<<dim3((8 * KT1 * 512 + 255) / 256), dim3(256), 0, stream>>>(w_ih1, w_hh1, wt1, HD, KT1);
  k_build_bcp<<<dim3(4), dim3(256), 0, stream>>>(b_ih0, b_hh0, bcp0);
  k_build_bcp<<<dim3(4), dim3(256), 0, stream>>>(b_ih1, b_hh1, bcp1);
  build_bt(W_in, bt_Win, 256, 256);
  build_bt(stock_Wl, bt_sWl0, 256, 256);
  build_bt(stock_Wr, bt_sWr0, 256, 256);
  build_bt(stock_Wl + HD * HD, bt_sWl1, 256, 256);
  build_bt(stock_Wr + HD * HD, bt_sWr1, 256, 256);
  build_bt(sector_Wl, bt_eWl0, 256, 256);
  build_bt(sector_Wr, bt_eWr0, 256, 256);
  build_bt(sector_Wl + HD * HD, bt_eWl1, 256, 256);
  build_bt(sector_Wr + HD * HD, bt_eWr1, 256, 256);
  build_bt(Wa1, bt_Wa1, 256, 128);
  build_bt(Wf, bt_Wf, 512, 256);
  build_bt(W_regf, bt_Wreg, 256, 256);
  build_bt(W_clff, bt_Wclf, 256, 256);
  build_bt(W_rnkf, bt_Wrnk, 256, 256);
  build_bt(Wr1, bt_Wr1, 256, 128);
  build_bt(Wr2, bt_Wr2, 128, 64);
  build_bt(Wc1, bt_Wc1, 256, 128);
  build_bt(Wk1, bt_Wk1, 256, 128);

  // 2. LSTM via MFMA
  {
    const int MB = (N + 127) / 128;
    dim3 gl(MB, 8);
    ushort *h0c = h0a, *h0n = h0b, *h1c = h1a, *h1n = h1b;
    for (int t = 0; t < TT; t++) {
      k_lstm_mfma<0><<<gl, dim3(256), 0, stream>>>(xln, h0c, wt0, bcp0, c0, h0n, N, t);
      k_lstm_mfma<1><<<gl, dim3(256), 0, stream>>>(h0n, h1c, wt1, bcp1, c1, h1n, N, 0);
      ushort* tp = h0c; h0c = h0n; h0n = tp;
      tp = h1c; h1c = h1n; h1n = tp;
    }
    k_ln_rows_b16<<<dim3(N), dim3(256), 0, stream>>>(h1c, tmpY, ln_t_g, ln_t_b, N, 0);
  }
  gemm_f(tmpY, HD, bt_Win, b_in, xA, HD, N, 256, 256, ACT_NONE);

  // 3. stock CSR (with self loops)
  k_hist_edges<<<dim3(2048), dim3(256), 0, stream>>>(ei_stock + E, E, N, cnt);
  k_scan_excl<<<dim3(1), dim3(1024), 0, stream>>>(cnt, rowptr, N);
  k_scatter_edges<<<dim3(2048), dim3(256), 0, stream>>>(ei_stock, ei_stock + E, E, N,
                                                        rowptr, fill, esrc);
  // 4. stock GAT x2
  float* xc = xA; float* xn = xB;
  const ushort* btWl[2] = {bt_sWl0, bt_sWl1};
  const ushort* btWr[2] = {bt_sWr0, bt_sWr1};
  for (int l = 0; l < 2; l++) {
    const float* bl = stock_bl + (size_t)l * HD;
    const float* br = stock_br + (size_t)l * HD;
    const float* at = stock_att + (size_t)l * HD;
    const float* bi = stock_bias + (size_t)l * HD;
    const float* lg = stock_g + (size_t)l * HD;
    const float* lb = stock_b + (size_t)l * HD;
    gemm_b(xc, HD, btWl[l], bl, xlr_b, 512, N, 256, 256, ACT_NONE);
    gemm_b(xc, HD, btWr[l], br, xlr_b + 256, 512, N, 256, 256, ACT_NONE);
    k_gat_node<<<dim3(N), dim3(256), 0, stream>>>(xc, xlr_b, rowptr, esrc, at, bi, lg, lb,
                                                  xn, scbuf, N);
    float* tp = xc; xc = xn; xn = tp;
  }
  // 5. attention pooling to sectors
  gemm_f(xc, HD, bt_Wa1, ba1, hA, 128, N, 128, 256, ACT_TANH);
  k_rowdot<<<dim3((N + 3) / 4), dim3(256), 0, stream>>>(hA, Wa2, ba2, scpool, N, 128, 1, 0);
  k_hist_arr<<<dim3(512), dim3(256), 0, stream>>>(batch, N, bcnt);
  k_scan_excl<<<dim3(1), dim3(1024), 0, stream>>>(bcnt, bptr, S);
  k_sector_pool<<<dim3(S), dim3(256), 0, stream>>>(xc, scpool, bptr, seA, S);
  // 6. sector CSR + GAT x2
  k_hist_edges<<<dim3(64), dim3(256), 0, stream>>>(ei_sector + ES, ES, S, cntS);
  k_scan_excl<<<dim3(1), dim3(1024), 0, stream>>>(cntS, rptrS, S);
  k_scatter_edges<<<dim3(64), dim3(256), 0, stream>>>(ei_sector, ei_sector + ES, ES, S,
                                                      rptrS, fillS, esrcS);
  float* sec = seA; float* sen = seB;
  const ushort* btEl[2] = {bt_eWl0, bt_eWl1};
  const ushort* btEr[2] = {bt_eWr0, bt_eWr1};
  for (int l = 0; l < 2; l++) {
    const float* bl = sector_bl + (size_t)l * HD;
    const float* br = sector_br + (size_t)l * HD;
    const float* at = sector_att + (size_t)l * HD;
    const float* bi = sector_bias + (size_t)l * HD;
    const float* lg = sector_g + (size_t)l * HD;
    const float* lb = sector_b + (size_t)l * HD;
    gemm_b(sec, HD, btEl[l], bl, selr_b, 512, S, 256, 256, ACT_NONE);
    gemm_b(sec, HD, btEr[l], br, selr_b + 256, 512, S, 256, 256, ACT_NONE);
    k_gat_node<<<dim3(S), dim3(256), 0, stream>>>(sec, selr_b, rptrS, esrcS, at, bi, lg, lb,
                                                  sen, scbuf, S);
    float* tp = sec; sec = sen; sen = tp;
  }
  // 7. fusion -> c (output)
  k_comb<<<dim3(4096), dim3(256), 0, stream>>>(xc, sec, batch, comb, N);
  gemm_f(comb, 512, bt_Wf, bf, tmpY, HD, N, 256, 512, ACT_NONE);
  k_ln_rows<<<dim3(N), dim3(256), 0, stream>>>(tmpY, out_c, gf, bef, N, 2);
  // 8a. regression head
  gemm_f(out_c, HD, bt_Wreg, b_regf, tmpY, HD, N, 256, 256, ACT_NONE);
  k_ln_rows<<<dim3(N), dim3(256), 0, stream>>>(tmpY, headbuf, g_regf, be_regf, N, 1);
  gemm_f(headbuf, HD, bt_Wr1, br1, t128, 128, N, 128, 256, ACT_RELU);
  gemm_f(t128, 128, bt_Wr2, br2, t64, 64, N, 64, 128, ACT_RELU);
  k_rowdot<<<dim3((N + 3) / 4), dim3(256), 0, stream>>>(t64, Wr3, br3, out_ret, N, 64, 1, 3);
  // 8b. classification head
  gemm_f(out_c, HD, bt_Wclf, b_clff, tmpY, HD, N, 256, 256, ACT_NONE);
  k_ln_rows<<<dim3(N), dim3(256), 0, stream>>>(tmpY, headbuf, g_clff, be_clff, N, 1);
  gemm_f(headbuf, HD, bt_Wc1, bc1, t128, 128, N, 128, 256, ACT_RELU);
  k_rowdot<<<dim3((N + 3) / 4), dim3(256), 0, stream>>>(t128, Wc2, bc2, out_mov, N, 128, 2, 0);
  // 8c. ranking head
  gemm_f(out_c, HD, bt_Wrnk, b_rnkf, tmpY, HD, N, 256, 256, ACT_NONE);
  k_ln_rows<<<dim3(N), dim3(256), 0, stream>>>(tmpY, headbuf, g_rnkf, be_rnkf, N, 1);
  gemm_f(headbuf, HD, bt_Wk1, bk1, t128, 128, N, 128, 256, ACT_RELU);
  k_rowdot<<<dim3((N + 3) / 4), dim3(256), 0, stream>>>(t128, Wk2, bk2, out_rnk, N, 128, 1, 4);
}

// Round 4
// 3383.825 us; speedup vs baseline: 5.3031x; 1.1507x over previous
//
#include <hip/hip_runtime.h>
#include <stdint.h>

static constexpr int TT = 20;     // timesteps
static constexpr int FF = 64;     // input features
static constexpr int HD = 256;    // hidden dim

enum { ACT_NONE = 0, ACT_RELU = 1, ACT_TANH = 2 };

typedef __attribute__((ext_vector_type(8))) short short8;
typedef __attribute__((ext_vector_type(4))) float f32x4;

static __device__ __forceinline__ float sigf(float x) { return 1.f / (1.f + expf(-x)); }

static __device__ __forceinline__ ushort f2bf(float f) {
  uint32_t u = __float_as_uint(f);
  return (ushort)((u + 0x7fffu + ((u >> 16) & 1u)) >> 16);
}
static __device__ __forceinline__ float bf2f(ushort u) {
  return __uint_as_float(((uint32_t)u) << 16);
}
static __device__ __forceinline__ void gl16(const void* g, void* l) {
  __builtin_amdgcn_global_load_lds(
      (const __attribute__((address_space(1))) uint32_t*)g,
      (__attribute__((address_space(3))) uint32_t*)l, 16, 0, 0);
}

// ---------------- feature LN + bf16 convert: one wave per 64-wide row ----------------
__global__ void k_lncvt(const float* __restrict__ x, const float* __restrict__ g,
                        const float* __restrict__ b, ushort* __restrict__ y, int rows) {
  int row = blockIdx.x * 4 + (threadIdx.x >> 6);
  int lane = threadIdx.x & 63;
  if (row >= rows) return;
  float v = x[(size_t)row * 64 + lane];
  float s = v, s2 = v * v;
  for (int o = 32; o; o >>= 1) { s += __shfl_xor(s, o); s2 += __shfl_xor(s2, o); }
  float m = s * (1.f / 64.f);
  float var = s2 * (1.f / 64.f) - m * m;
  float rs = rsqrtf(var + 1e-5f);
  y[(size_t)row * 64 + lane] = f2bf((v - m) * rs * g[lane] + b[lane]);
}

// ---------------- build pre-tiled/swizzled bf16 gate weights (LSTM) ----------------
__global__ void k_build_wtile(const float* __restrict__ w_ih, const float* __restrict__ w_hh,
                              ushort* __restrict__ wt, int KI, int KT) {
  int total = 8 * KT * 512;
  for (int idx = blockIdx.x * blockDim.x + threadIdx.x; idx < total;
       idx += gridDim.x * blockDim.x) {
    int nb = idx / (KT * 512);
    int rem = idx % (KT * 512);
    int kt = rem / 512;
    int q = rem % 512;
    int r = q >> 2, csw = q & 3;
    int ch = csw ^ ((r >> 1) & 3);
    int col = nb * 128 + r;
    int hdblk = col >> 6, gg = (col >> 4) & 3, hd = hdblk * 16 + (col & 15);
    int orow = gg * HD + hd;
    int k = kt * 32 + ch * 8;
    const float* src = (k < KI) ? (w_ih + (size_t)orow * KI + k)
                                : (w_hh + (size_t)orow * HD + (k - KI));
    ushort* dst = wt + (size_t)idx * 8;
#pragma unroll
    for (int j = 0; j < 8; j++) dst[j] = f2bf(src[j]);
  }
}

__global__ void k_build_bcp(const float* __restrict__ bi, const float* __restrict__ bh,
                            float* __restrict__ bcp) {
  int col = blockIdx.x * blockDim.x + threadIdx.x;
  if (col >= 1024) return;
  int hdblk = col >> 6, gg = (col >> 4) & 3, hd = hdblk * 16 + (col & 15);
  int orow = gg * HD + hd;
  bcp[col] = bi[orow] + bh[orow];
}

// ---------------- build tiled bf16 B for generic GEMM ----------------
__global__ void k_build_btile(const float* __restrict__ B, ushort* __restrict__ bt,
                              int K, int Nn, int NB) {
  int KTb = K / 32;
  int total = NB * KTb * 512;
  for (int idx = blockIdx.x * blockDim.x + threadIdx.x; idx < total;
       idx += gridDim.x * blockDim.x) {
    int nb = idx / (KTb * 512);
    int rem = idx % (KTb * 512);
    int kt = rem / 512;
    int q = rem % 512;
    int r = q >> 2, csw = q & 3;
    int ch = csw ^ ((r >> 1) & 3);
    int col = nb * 128 + r;
    int k = kt * 32 + ch * 8;
    ushort* dst = bt + (size_t)idx * 8;
#pragma unroll
    for (int j = 0; j < 8; j++)
      dst[j] = (col < Nn) ? f2bf(B[(size_t)(k + j) * Nn + col]) : (ushort)0;
  }
}

// ---------------- MFMA LSTM step ----------------
template <int LAYER>
__global__ __launch_bounds__(256) void k_lstm_mfma(
    const ushort* __restrict__ a0, const ushort* __restrict__ a1,
    const ushort* __restrict__ wt, const float* __restrict__ bcp,
    float* __restrict__ cst, ushort* __restrict__ hnext, int M, int t) {
  constexpr int K = (LAYER == 0) ? 320 : 512;
  constexpr int KT = K / 32;
  constexpr int SEG0 = (LAYER == 0) ? 64 : 256;
  constexpr int LDA0 = (LAYER == 0) ? (TT * FF) : HD;
  __shared__ ushort At[128 * 32];
  __shared__ ushort Bt[128 * 32];
  const int tid = threadIdx.x;
  const int lane = tid & 63, wid = tid >> 6;
  const int wr = wid >> 1, wc = wid & 1;
  const int m0 = blockIdx.x * 128;
  const int nb = blockIdx.y;
  const int a0t = (LAYER == 0) ? t * FF : 0;

  f32x4 acc[4][4];
#pragma unroll
  for (int i = 0; i < 4; i++)
#pragma unroll
    for (int j = 0; j < 4; j++) acc[i][j] = (f32x4){0.f, 0.f, 0.f, 0.f};

  int rown[2], chn[2];
#pragma unroll
  for (int e = 0; e < 2; e++) {
    int q = e * 256 + tid;
    int r = q >> 2, csw = q & 3;
    rown[e] = r;
    chn[e] = csw ^ ((r >> 1) & 3);
  }
  const size_t wtbase = (size_t)nb * KT * 512;

  for (int kt = 0; kt < KT; ++kt) {
    __syncthreads();
    const int k0 = kt * 32;
#pragma unroll
    for (int e = 0; e < 2; e++) {
      int q = e * 256 + tid;
      int r = rown[e];
      int kg = k0 + chn[e] * 8;
      int grow = m0 + r;
      grow = (grow < M) ? grow : (M - 1);
      const ushort* src = (kg < SEG0)
                              ? (a0 + (size_t)grow * LDA0 + a0t + kg)
                              : (a1 + (size_t)grow * HD + (kg - SEG0));
      gl16(src, &At[q * 8]);
      gl16(wt + (wtbase + (size_t)kt * 512 + q) * 8, &Bt[q * 8]);
    }
    __syncthreads();
    short8 af[4], bfr[4];
#pragma unroll
    for (int i = 0; i < 4; i++) {
      int rA = wr * 64 + i * 16 + (lane & 15);
      int swa = (lane >> 4) ^ ((rA >> 1) & 3);
      af[i] = *(const short8*)&At[rA * 32 + swa * 8];
      int rB = wc * 64 + i * 16 + (lane & 15);
      int swb = (lane >> 4) ^ ((rB >> 1) & 3);
      bfr[i] = *(const short8*)&Bt[rB * 32 + swb * 8];
    }
#pragma unroll
    for (int i = 0; i < 4; i++)
#pragma unroll
      for (int j = 0; j < 4; j++)
        acc[i][j] = __builtin_amdgcn_mfma_f32_16x16x32_bf16(af[i], bfr[j], acc[i][j], 0, 0, 0);
  }
  const int hdlo = lane & 15;
  const int rb = (lane >> 4) * 4;
  const int colb = nb * 128 + wc * 64;
  const float bI = bcp[colb + hdlo];
  const float bF = bcp[colb + 16 + hdlo];
  const float bG = bcp[colb + 32 + hdlo];
  const float bO = bcp[colb + 48 + hdlo];
  const int hd = (nb * 2 + wc) * 16 + hdlo;
#pragma unroll
  for (int i = 0; i < 4; i++) {
#pragma unroll
    for (int r = 0; r < 4; r++) {
      int row = m0 + wr * 64 + i * 16 + rb + r;
      if (row >= M) continue;
      float gi = acc[i][0][r] + bI;
      float gf = acc[i][1][r] + bF;
      float gg = acc[i][2][r] + bG;
      float go = acc[i][3][r] + bO;
      size_t ix = (size_t)row * HD + hd;
      float c = sigf(gf) * cst[ix] + sigf(gi) * tanhf(gg);
      cst[ix] = c;
      hnext[ix] = f2bf(sigf(go) * tanhf(c));
    }
  }
}

// ---------------- generic bf16 MFMA GEMM: C = act(A@B + bias) ----------------
template <bool BF16OUT>
__global__ __launch_bounds__(256) void k_gemm_mfma(
    const float* __restrict__ A, int lda, const ushort* __restrict__ BtG,
    const float* __restrict__ bias, void* __restrict__ Cv, int ldc,
    int M, int Nn, int K, int act) {
  const int KTb = K / 32;
  __shared__ ushort At[128 * 32];
  __shared__ ushort Bts[128 * 32];
  const int tid = threadIdx.x;
  const int lane = tid & 63, wid = tid >> 6;
  const int wr = wid >> 1, wc = wid & 1;
  const int m0 = blockIdx.x * 128;
  const int nb = blockIdx.y;

  f32x4 acc[4][4];
#pragma unroll
  for (int i = 0; i < 4; i++)
#pragma unroll
    for (int j = 0; j < 4; j++) acc[i][j] = (f32x4){0.f, 0.f, 0.f, 0.f};

  const size_t btbase = (size_t)nb * KTb * 512;

  for (int kt = 0; kt < KTb; ++kt) {
    __syncthreads();
    const int k0 = kt * 32;
#pragma unroll
    for (int e = 0; e < 2; e++) {
      int q = e * 256 + tid;
      int r = q >> 2, csw = q & 3;
      int ch = csw ^ ((r >> 1) & 3);
      int row = m0 + r;
      row = (row < M) ? row : (M - 1);
      const float* src = A + (size_t)row * lda + k0 + ch * 8;
      float4 f0 = *(const float4*)src;
      float4 f1 = *(const float4*)(src + 4);
      short8 s;
      s[0] = (short)f2bf(f0.x); s[1] = (short)f2bf(f0.y);
      s[2] = (short)f2bf(f0.z); s[3] = (short)f2bf(f0.w);
      s[4] = (short)f2bf(f1.x); s[5] = (short)f2bf(f1.y);
      s[6] = (short)f2bf(f1.z); s[7] = (short)f2bf(f1.w);
      *(short8*)&At[q * 8] = s;
      gl16(BtG + (btbase + (size_t)kt * 512 + q) * 8, &Bts[q * 8]);
    }
    __syncthreads();
    short8 af[4], bfr[4];
#pragma unroll
    for (int i = 0; i < 4; i++) {
      int rA = wr * 64 + i * 16 + (lane & 15);
      int swa = (lane >> 4) ^ ((rA >> 1) & 3);
      af[i] = *(const short8*)&At[rA * 32 + swa * 8];
      int rB = wc * 64 + i * 16 + (lane & 15);
      int swb = (lane >> 4) ^ ((rB >> 1) & 3);
      bfr[i] = *(const short8*)&Bts[rB * 32 + swb * 8];
    }
#pragma unroll
    for (int i = 0; i < 4; i++)
#pragma unroll
      for (int j = 0; j < 4; j++)
        acc[i][j] = __builtin_amdgcn_mfma_f32_16x16x32_bf16(af[i], bfr[j], acc[i][j], 0, 0, 0);
  }
  const int rb = (lane >> 4) * 4;
  const int cl = lane & 15;
#pragma unroll
  for (int i = 0; i < 4; i++) {
#pragma unroll
    for (int j = 0; j < 4; j++) {
      int col = nb * 128 + wc * 64 + j * 16 + cl;
      if (col >= Nn) continue;
      float bv = bias[col];
#pragma unroll
      for (int r = 0; r < 4; r++) {
        int row = m0 + wr * 64 + i * 16 + rb + r;
        if (row >= M) continue;
        float v = acc[i][j][r] + bv;
        if (act == ACT_RELU) v = fmaxf(v, 0.f);
        else if (act == ACT_TANH) v = tanhf(v);
        if (BF16OUT) ((ushort*)Cv)[(size_t)row * ldc + col] = f2bf(v);
        else ((float*)Cv)[(size_t)row * ldc + col] = v;
      }
    }
  }
}

// ---------------- per-row LN over 256 + optional act ----------------
__global__ __launch_bounds__(256) void k_ln_rows(
    const float* __restrict__ in, float* __restrict__ out,
    const float* __restrict__ g, const float* __restrict__ b, int rows, int act) {
  int row = blockIdx.x;
  if (row >= rows) return;
  int tid = threadIdx.x, lane = tid & 63, wv = tid >> 6;
  float v = in[(size_t)row * HD + tid];
  float s = v, s2 = v * v;
  for (int o = 32; o; o >>= 1) { s += __shfl_xor(s, o); s2 += __shfl_xor(s2, o); }
  __shared__ float ws1[4], ws2[4];
  if (lane == 0) { ws1[wv] = s; ws2[wv] = s2; }
  __syncthreads();
  float S1 = ws1[0] + ws1[1] + ws1[2] + ws1[3];
  float S2 = ws2[0] + ws2[1] + ws2[2] + ws2[3];
  float m = S1 * (1.f / 256.f);
  float var = S2 * (1.f / 256.f) - m * m;
  float r = rsqrtf(var + 1e-5f);
  float y = (v - m) * r * g[tid] + b[tid];
  if (act == 1) y = fmaxf(y, 0.f);
  else if (act == 2) y = (y > 0.f) ? y : (expf(y) - 1.f);
  out[(size_t)row * HD + tid] = y;
}

__global__ __launch_bounds__(256) void k_ln_rows_b16(
    const ushort* __restrict__ in, float* __restrict__ out,
    const float* __restrict__ g, const float* __restrict__ b, int rows, int act) {
  int row = blockIdx.x;
  if (row >= rows) return;
  int tid = threadIdx.x, lane = tid & 63, wv = tid >> 6;
  float v = bf2f(in[(size_t)row * HD + tid]);
  float s = v, s2 = v * v;
  for (int o = 32; o; o >>= 1) { s += __shfl_xor(s, o); s2 += __shfl_xor(s2, o); }
  __shared__ float ws1[4], ws2[4];
  if (lane == 0) { ws1[wv] = s; ws2[wv] = s2; }
  __syncthreads();
  float S1 = ws1[0] + ws1[1] + ws1[2] + ws1[3];
  float S2 = ws2[0] + ws2[1] + ws2[2] + ws2[3];
  float m = S1 * (1.f / 256.f);
  float var = S2 * (1.f / 256.f) - m * m;
  float r = rsqrtf(var + 1e-5f);
  float y = (v - m) * r * g[tid] + b[tid];
  if (act == 1) y = fmaxf(y, 0.f);
  else if (act == 2) y = (y > 0.f) ? y : (expf(y) - 1.f);
  out[(size_t)row * HD + tid] = y;
}

// ---------------- CSR build ----------------
__global__ void k_hist_edges(const int* __restrict__ dst, int E, int n, int* __restrict__ cnt) {
  int tot = E + n;
  for (int i = blockIdx.x * blockDim.x + threadIdx.x; i < tot; i += gridDim.x * blockDim.x) {
    int d = (i < E) ? dst[i] : (i - E);
    atomicAdd(&cnt[d], 1);
  }
}

__global__ void k_hist_arr(const int* __restrict__ a, int n, int* __restrict__ cnt) {
  for (int i = blockIdx.x * blockDim.x + threadIdx.x; i < n; i += gridDim.x * blockDim.x)
    atomicAdd(&cnt[a[i]], 1);
}

__global__ void k_scan_excl(const int* __restrict__ cnt, int* __restrict__ ptr, int n) {
  __shared__ int sm[1024];
  __shared__ int carry_s;
  int tid = threadIdx.x;
  if (tid == 0) carry_s = 0;
  __syncthreads();
  for (int base = 0; base < n; base += 1024) {
    int i = base + tid;
    int v = (i < n) ? cnt[i] : 0;
    sm[tid] = v;
    __syncthreads();
    for (int off = 1; off < 1024; off <<= 1) {
      int tval = (tid >= off) ? sm[tid - off] : 0;
      __syncthreads();
      sm[tid] += tval;
      __syncthreads();
    }
    int carry = carry_s;
    if (i < n) ptr[i] = carry + sm[tid] - v;
    __syncthreads();
    if (tid == 1023) carry_s = carry + sm[1023];
    __syncthreads();
  }
  if (tid == 0) ptr[n] = carry_s;
}

__global__ void k_scatter_edges(const int* __restrict__ src, const int* __restrict__ dst,
                                int E, int n, const int* __restrict__ rowptr,
                                int* __restrict__ fill, int* __restrict__ esrc) {
  int tot = E + n;
  for (int i = blockIdx.x * blockDim.x + threadIdx.x; i < tot; i += gridDim.x * blockDim.x) {
    int d, s;
    if (i < E) { d = dst[i]; s = src[i]; } else { d = i - E; s = i - E; }
    int pos = rowptr[d] + atomicAdd(&fill[d], 1);
    esrc[pos] = s;
  }
}

// ---------------- flash-style GATv2: one wave per dst node, single pass ----------------
// lane = eg*16 + dq: eg = edge slot (4 edges/iter), dq = 16-dim chunk (head = dq>>2)
__global__ __launch_bounds__(256) void k_gat_wave(
    const float* __restrict__ xin, const ushort* __restrict__ xlr,
    const int* __restrict__ rowptr, const int* __restrict__ esrc,
    const float* __restrict__ att, const float* __restrict__ bias,
    const float* __restrict__ lng, const float* __restrict__ lnb,
    float* __restrict__ xout, int n_nodes) {
  const int wid = threadIdx.x >> 6;
  const int nd = blockIdx.x * 4 + wid;
  if (nd >= n_nodes) return;
  const int lane = threadIdx.x & 63;
  const int eg = lane >> 4;
  const int dq = lane & 15;
  const int dbase = dq * 16;

  float xr16[16], at16[16];
  {
    const ushort* xr = xlr + (size_t)nd * 512 + 256 + dbase;
    short8 a = *(const short8*)xr;
    short8 b = *(const short8*)(xr + 8);
#pragma unroll
    for (int j = 0; j < 8; j++) { xr16[j] = bf2f((ushort)a[j]); xr16[8 + j] = bf2f((ushort)b[j]); }
    const float* ap = att + dbase;
#pragma unroll
    for (int j = 0; j < 16; j++) at16[j] = ap[j];
  }
  const int rs = rowptr[nd];
  const int deg = rowptr[nd + 1] - rs;

  float m = -3e38f, z = 0.f;
  float acc[16];
#pragma unroll
  for (int j = 0; j < 16; j++) acc[j] = 0.f;

  for (int p = eg; p < deg; p += 4) {
    int src = esrc[rs + p];
    const ushort* xl = xlr + (size_t)src * 512 + dbase;
    short8 a = *(const short8*)xl;
    short8 b = *(const short8*)(xl + 8);
    float xv[16];
#pragma unroll
    for (int j = 0; j < 8; j++) { xv[j] = bf2f((ushort)a[j]); xv[8 + j] = bf2f((ushort)b[j]); }
    float sc = 0.f;
#pragma unroll
    for (int j = 0; j < 16; j++) {
      float v = xv[j] + xr16[j];
      v = (v > 0.f) ? v : 0.2f * v;  // leaky_relu 0.2
      sc = fmaf(v, at16[j], sc);
    }
    sc += __shfl_xor(sc, 1);
    sc += __shfl_xor(sc, 2);   // quad = one head's 64 dims
    // online softmax, deferred-max THR=8
    if (sc > m + 8.f) {
      float r = __expf(m - sc);
      z *= r;
#pragma unroll
      for (int j = 0; j < 16; j++) acc[j] *= r;
      m = sc;
    }
    float w = __expf(sc - m);
    z += w;
#pragma unroll
    for (int j = 0; j < 16; j++) acc[j] = fmaf(w, xv[j], acc[j]);
  }
  // merge across edge-groups (per head)
  float mt = fmaxf(m, __shfl_xor(m, 16));
  mt = fmaxf(mt, __shfl_xor(mt, 32));
  float r = __expf(m - mt);
  z *= r;
  z += __shfl_xor(z, 16);
  z += __shfl_xor(z, 32);
#pragma unroll
  for (int j = 0; j < 16; j++) {
    float a = acc[j] * r;
    a += __shfl_xor(a, 16);
    a += __shfl_xor(a, 32);
    acc[j] = a;
  }
  float zinv = 1.f / (z + 1e-16f);
  // epilogue: +bias +residual, LN over 256 (4x replicated in wave), ELU
  const float* xi = xin + (size_t)nd * 256 + dbase;
  const float* bp = bias + dbase;
  float v16[16];
  float s1 = 0.f, s2 = 0.f;
#pragma unroll
  for (int j = 0; j < 16; j++) {
    float v = acc[j] * zinv + bp[j] + xi[j];
    v16[j] = v;
    s1 += v;
    s2 += v * v;
  }
  for (int o = 32; o; o >>= 1) { s1 += __shfl_xor(s1, o); s2 += __shfl_xor(s2, o); }
  float mean = s1 * (1.f / 1024.f);
  float var = s2 * (1.f / 1024.f) - mean * mean;
  float rstd = rsqrtf(var + 1e-5f);
  const float* gp = lng + dbase + eg * 4;
  const float* bb = lnb + dbase + eg * 4;
  float4 o4;
#pragma unroll
  for (int jj = 0; jj < 4; jj++) {
    float y = (v16[eg * 4 + jj] - mean) * rstd * gp[jj] + bb[jj];
    y = (y > 0.f) ? y : (expf(y) - 1.f);
    (&o4.x)[jj] = y;
  }
  *(float4*)(xout + (size_t)nd * 256 + dbase + eg * 4) = o4;
}

// ---------------- small row-dot heads ----------------
__global__ void k_rowdot(const float* __restrict__ in, const float* __restrict__ W,
                         const float* __restrict__ bias, float* __restrict__ out,
                         int rows, int K, int OC, int act) {
  int row = blockIdx.x * 4 + (threadIdx.x >> 6);
  if (row >= rows) return;
  int lane = threadIdx.x & 63;
  for (int o = 0; o < OC; o++) {
    float s = 0.f;
    for (int k = lane; k < K; k += 64) s += in[(size_t)row * K + k] * W[(size_t)k * OC + o];
    for (int off = 32; off; off >>= 1) s += __shfl_xor(s, off);
    if (lane == 0) {
      float v = s + bias[o];
      if (act == 3) v = tanhf(v) * 0.1f;
      else if (act == 4) v = 1.f / (1.f + expf(-v));
      out[(size_t)row * OC + o] = v;
    }
  }
}

// ---------------- sector attention pooling ----------------
__global__ __launch_bounds__(256) void k_sector_pool(
    const float* __restrict__ x, const float* __restrict__ sc,
    const int* __restrict__ bptr, float* __restrict__ se, int S) {
  const int s = blockIdx.x, tid = threadIdx.x, lane = tid & 63, wv = tid >> 6;
  const int rs = bptr[s], re = bptr[s + 1];
  const int cnt = re - rs;
  __shared__ float r1[4], r2[4], wch[256];
  float mx = -3e38f;
  for (int i = rs + tid; i < re; i += 256) mx = fmaxf(mx, sc[i]);
  for (int o = 32; o; o >>= 1) mx = fmaxf(mx, __shfl_xor(mx, o));
  if (lane == 0) r1[wv] = mx;
  __syncthreads();
  float m = fmaxf(fmaxf(r1[0], r1[1]), fmaxf(r1[2], r1[3]));
  if (cnt == 0) m = 0.f;
  float z = 0.f;
  for (int i = rs + tid; i < re; i += 256) z += expf(sc[i] - m);
  for (int o = 32; o; o >>= 1) z += __shfl_xor(z, o);
  if (lane == 0) r2[wv] = z;
  __syncthreads();
  float zinv = 1.f / (r2[0] + r2[1] + r2[2] + r2[3] + 1e-16f);
  float acc = 0.f;
  for (int base = rs; base < re; base += 256) {
    int i = base + tid;
    wch[tid] = (i < re) ? expf(sc[i] - m) * zinv : 0.f;
    __syncthreads();
    int lim = re - base; if (lim > 256) lim = 256;
    for (int q = 0; q < lim; q++) acc += wch[q] * x[(size_t)(base + q) * HD + tid];
    __syncthreads();
  }
  se[(size_t)s * HD + tid] = acc / fmaxf((float)cnt, 1.f);
}

// ---------------- comb = [x | se[batch]] ----------------
__global__ void k_comb(const float* __restrict__ x, const float* __restrict__ se,
                       const int* __restrict__ batch, float* __restrict__ comb, int n) {
  int total = n * 512;
  for (int i = blockIdx.x * blockDim.x + threadIdx.x; i < total; i += gridDim.x * blockDim.x) {
    int row = i >> 9, col = i & 511;
    comb[i] = (col < HD) ? x[(size_t)row * HD + col]
                         : se[(size_t)batch[row] * HD + (col - HD)];
  }
}

extern "C" void kernel_launch(void* const* d_in, const int* in_sizes, int n_in,
                              void* d_out, int out_size, void* d_ws, size_t ws_size,
                              hipStream_t stream) {
  const float* x_stock   = (const float*)d_in[0];
  const int*   ei_stock  = (const int*)d_in[1];
  const int*   batch     = (const int*)d_in[2];
  const int*   ei_sector = (const int*)d_in[4];
  const float* ln_feat_g = (const float*)d_in[5];
  const float* ln_feat_b = (const float*)d_in[6];
  const float* w_ih0 = (const float*)d_in[7];
  const float* w_hh0 = (const float*)d_in[8];
  const float* b_ih0 = (const float*)d_in[9];
  const float* b_hh0 = (const float*)d_in[10];
  const float* w_ih1 = (const float*)d_in[11];
  const float* w_hh1 = (const float*)d_in[12];
  const float* b_ih1 = (const float*)d_in[13];
  const float* b_hh1 = (const float*)d_in[14];
  const float* ln_t_g = (const float*)d_in[15];
  const float* ln_t_b = (const float*)d_in[16];
  const float* W_in = (const float*)d_in[17];
  const float* b_in = (const float*)d_in[18];
  const float* stock_Wl = (const float*)d_in[19];
  const float* stock_bl = (const float*)d_in[20];
  const float* stock_Wr = (const float*)d_in[21];
  const float* stock_br = (const float*)d_in[22];
  const float* stock_att = (const float*)d_in[23];
  const float* stock_bias = (const float*)d_in[24];
  const float* stock_g = (const float*)d_in[25];
  const float* stock_b = (const float*)d_in[26];
  const float* sector_Wl = (const float*)d_in[27];
  const float* sector_bl = (const float*)d_in[28];
  const float* sector_Wr = (const float*)d_in[29];
  const float* sector_br = (const float*)d_in[30];
  const float* sector_att = (const float*)d_in[31];
  const float* sector_bias = (const float*)d_in[32];
  const float* sector_g = (const float*)d_in[33];
  const float* sector_b = (const float*)d_in[34];
  const float* Wa1 = (const float*)d_in[35];
  const float* ba1 = (const float*)d_in[36];
  const float* Wa2 = (const float*)d_in[37];
  const float* ba2 = (const float*)d_in[38];
  const float* Wf  = (const float*)d_in[39];
  const float* bf  = (const float*)d_in[40];
  const float* gf  = (const float*)d_in[41];
  const float* bef = (const float*)d_in[42];
  const float* W_regf = (const float*)d_in[43];
  const float* b_regf = (const float*)d_in[44];
  const float* g_regf = (const float*)d_in[45];
  const float* be_regf = (const float*)d_in[46];
  const float* W_clff = (const float*)d_in[47];
  const float* b_clff = (const float*)d_in[48];
  const float* g_clff = (const float*)d_in[49];
  const float* be_clff = (const float*)d_in[50];
  const float* W_rnkf = (const float*)d_in[51];
  const float* b_rnkf = (const float*)d_in[52];
  const float* g_rnkf = (const float*)d_in[53];
  const float* be_rnkf = (const float*)d_in[54];
  const float* Wr1 = (const float*)d_in[55];
  const float* br1 = (const float*)d_in[56];
  const float* Wr2 = (const float*)d_in[57];
  const float* br2 = (const float*)d_in[58];
  const float* Wr3 = (const float*)d_in[59];
  const float* br3 = (const float*)d_in[60];
  const float* Wc1 = (const float*)d_in[61];
  const float* bc1 = (const float*)d_in[62];
  const float* Wc2 = (const float*)d_in[63];
  const float* bc2 = (const float*)d_in[64];
  const float* Wk1 = (const float*)d_in[65];
  const float* bk1 = (const float*)d_in[66];
  const float* Wk2 = (const float*)d_in[67];
  const float* bk2 = (const float*)d_in[68];

  const int N  = in_sizes[0] / (TT * FF);
  const int E  = in_sizes[1] / 2;
  const int S  = in_sizes[3] / HD;
  const int ES = in_sizes[4] / 2;
  const int Ep = E + N, ESp = ES + S;
  const int NT = N * TT;
  const int KT0 = 10, KT1 = 16;

  char* wsb = (char*)d_ws;
  size_t off = 0;
  auto alloc = [&](size_t bytes) -> char* {
    char* p = wsb + off;
    off += (bytes + 255) & ~(size_t)255;
    return p;
  };
  // zero-init group (h/c states)
  ushort* h0a = (ushort*)alloc((size_t)N * HD * 2);
  ushort* h1a = (ushort*)alloc((size_t)N * HD * 2);
  float*  c0  = (float*)alloc((size_t)N * HD * 4);
  float*  c1  = (float*)alloc((size_t)N * HD * 4);
  size_t zf_bytes = off;
  ushort* h0b = (ushort*)alloc((size_t)N * HD * 2);
  ushort* h1b = (ushort*)alloc((size_t)N * HD * 2);
  ushort* wt0 = (ushort*)alloc((size_t)8 * KT0 * 512 * 16);
  ushort* wt1 = (ushort*)alloc((size_t)8 * KT1 * 512 * 16);
  float* bcp0 = (float*)alloc(1024 * 4);
  float* bcp1 = (float*)alloc(1024 * 4);
  float* xA  = (float*)alloc((size_t)N * HD * 4);
  float* xB  = (float*)alloc((size_t)N * HD * 4);
  char*  xlr_raw = alloc((size_t)N * 512 * 4);          // bf16 xl|xr; later f32 comb
  float* scbuf = (float*)alloc((size_t)N * 128 * 4);    // hA buffer
  char*  selr_raw = alloc((size_t)S * 512 * 4);
  float* seA  = (float*)alloc((size_t)S * HD * 4);
  float* seB  = (float*)alloc((size_t)S * HD * 4);
  float* scpool = (float*)alloc((size_t)N * 4);
  // big region: xln (LSTM phase) then tmpY+headbuf (post-LSTM)
  char* bigraw = alloc((size_t)N * TT * FF * 2);
  ushort* xln    = (ushort*)bigraw;
  float*  tmpY   = (float*)bigraw;
  float*  headbuf = (float*)(bigraw + (size_t)N * HD * 4);
  // tiled bf16 weights for generic GEMMs
  auto alloc_bt = [&](int K, int Nn) -> ushort* {
    int NB = (Nn + 127) / 128;
    return (ushort*)alloc((size_t)NB * (K / 32) * 512 * 16);
  };
  ushort* bt_Win  = alloc_bt(256, 256);
  ushort* bt_sWl0 = alloc_bt(256, 256);
  ushort* bt_sWr0 = alloc_bt(256, 256);
  ushort* bt_sWl1 = alloc_bt(256, 256);
  ushort* bt_sWr1 = alloc_bt(256, 256);
  ushort* bt_eWl0 = alloc_bt(256, 256);
  ushort* bt_eWr0 = alloc_bt(256, 256);
  ushort* bt_eWl1 = alloc_bt(256, 256);
  ushort* bt_eWr1 = alloc_bt(256, 256);
  ushort* bt_Wa1  = alloc_bt(256, 128);
  ushort* bt_Wf   = alloc_bt(512, 256);
  ushort* bt_Wreg = alloc_bt(256, 256);
  ushort* bt_Wclf = alloc_bt(256, 256);
  ushort* bt_Wrnk = alloc_bt(256, 256);
  ushort* bt_Wr1  = alloc_bt(256, 128);
  ushort* bt_Wr2  = alloc_bt(128, 64);
  ushort* bt_Wc1  = alloc_bt(256, 128);
  ushort* bt_Wk1  = alloc_bt(256, 128);
  size_t zi_start = off;
  int* cnt   = (int*)alloc((size_t)(N + 1) * 4);
  int* fill  = (int*)alloc((size_t)N * 4);
  int* cntS  = (int*)alloc((size_t)(S + 1) * 4);
  int* fillS = (int*)alloc((size_t)S * 4);
  int* bcnt  = (int*)alloc((size_t)(S + 1) * 4);
  size_t zi_bytes = off - zi_start;
  int* rowptr = (int*)alloc((size_t)(N + 1) * 4);
  int* esrc   = (int*)alloc((size_t)Ep * 4);
  int* rptrS  = (int*)alloc((size_t)(S + 1) * 4);
  int* esrcS  = (int*)alloc((size_t)ESp * 4);
  int* bptr   = (int*)alloc((size_t)(S + 1) * 4);

  ushort* xlr_b = (ushort*)xlr_raw;
  float*  comb  = (float*)xlr_raw;
  ushort* selr_b = (ushort*)selr_raw;
  float* hA   = scbuf;
  float* t128 = tmpY;
  float* t64  = tmpY + (size_t)N * 128;
  float* out_ret = (float*)d_out;
  float* out_mov = out_ret + N;
  float* out_rnk = out_ret + 3 * (size_t)N;
  float* out_c   = out_ret + 4 * (size_t)N;

  hipMemsetAsync(d_ws, 0, zf_bytes, stream);
  hipMemsetAsync(wsb + zi_start, 0, zi_bytes, stream);

  auto build_bt = [&](const float* W, ushort* bt, int K, int Nn) {
    int NB = (Nn + 127) / 128;
    int total = NB * (K / 32) * 512;
    k_build_btile<<<dim3((total + 255) / 256), dim3(256), 0, stream>>>(W, bt, K, Nn, NB);
  };
  auto gemm_f = [&](const float* A, int lda, const ushort* bt, const float* bias,
                    float* C, int ldc, int M, int Nn, int K, int act) {
    dim3 g((M + 127) / 128, (Nn + 127) / 128);
    k_gemm_mfma<false><<<g, dim3(256), 0, stream>>>(A, lda, bt, bias, C, ldc, M, Nn, K, act);
  };
  auto gemm_b = [&](const float* A, int lda, const ushort* bt, const float* bias,
                    ushort* C, int ldc, int M, int Nn, int K, int act) {
    dim3 g((M + 127) / 128, (Nn + 127) / 128);
    k_gemm_mfma<true><<<g, dim3(256), 0, stream>>>(A, lda, bt, bias, C, ldc, M, Nn, K, act);
  };

  // 1. feature-LN + bf16 convert; prebuild all tiled bf16 weights
  k_lncvt<<<dim3((NT + 3) / 4), dim3(256), 0, stream>>>(x_stock, ln_feat_g, ln_feat_b, xln, NT);
  k_build_wtile<<<dim3((8 * KT0 * 512 + 255) / 256), dim3(256), 0, stream>>>(w_ih0, w_hh0, wt0, FF, KT0);
  k_build_wtile<<<dim3((8 * KT1 * 512 + 255) / 256), dim3(256), 0, stream>>>(w_ih1, w_hh1, wt1, HD, KT1);
  k_build_bcp<<<dim3(4), dim3(256), 0, stream>>>(b_ih0, b_hh0, bcp0);
  k_build_bcp<<<dim3(4), dim3(256), 0, stream>>>(b_ih1, b_hh1, bcp1);
  build_bt(W_in, bt_Win, 256, 256);
  build_bt(stock_Wl, bt_sWl0, 256, 256);
  build_bt(stock_Wr, bt_sWr0, 256, 256);
  build_bt(stock_Wl + HD * HD, bt_sWl1, 256, 256);
  build_bt(stock_Wr + HD * HD, bt_sWr1, 256, 256);
  build_bt(sector_Wl, bt_eWl0, 256, 256);
  build_bt(sector_Wr, bt_eWr0, 256, 256);
  build_bt(sector_Wl + HD * HD, bt_eWl1, 256, 256);
  build_bt(sector_Wr + HD * HD, bt_eWr1, 256, 256);
  build_bt(Wa1, bt_Wa1, 256, 128);
  build_bt(Wf, bt_Wf, 512, 256);
  build_bt(W_regf, bt_Wreg, 256, 256);
  build_bt(W_clff, bt_Wclf, 256, 256);
  build_bt(W_rnkf, bt_Wrnk, 256, 256);
  build_bt(Wr1, bt_Wr1, 256, 128);
  build_bt(Wr2, bt_Wr2, 128, 64);
  build_bt(Wc1, bt_Wc1, 256, 128);
  build_bt(Wk1, bt_Wk1, 256, 128);

  // 2. LSTM via MFMA
  {
    const int MB = (N + 127) / 128;
    dim3 gl(MB, 8);
    ushort *h0c = h0a, *h0n = h0b, *h1c = h1a, *h1n = h1b;
    for (int t = 0; t < TT; t++) {
      k_lstm_mfma<0><<<gl, dim3(256), 0, stream>>>(xln, h0c, wt0, bcp0, c0, h0n, N, t);
      k_lstm_mfma<1><<<gl, dim3(256), 0, stream>>>(h0n, h1c, wt1, bcp1, c1, h1n, N, 0);
      ushort* tp = h0c; h0c = h0n; h0n = tp;
      tp = h1c; h1c = h1n; h1n = tp;
    }
    k_ln_rows_b16<<<dim3(N), dim3(256), 0, stream>>>(h1c, tmpY, ln_t_g, ln_t_b, N, 0);
  }
  gemm_f(tmpY, HD, bt_Win, b_in, xA, HD, N, 256, 256, ACT_NONE);

  // 3. stock CSR (with self loops)
  k_hist_edges<<<dim3(2048), dim3(256), 0, stream>>>(ei_stock + E, E, N, cnt);
  k_scan_excl<<<dim3(1), dim3(1024), 0, stream>>>(cnt, rowptr, N);
  k_scatter_edges<<<dim3(2048), dim3(256), 0, stream>>>(ei_stock, ei_stock + E, E, N,
                                                        rowptr, fill, esrc);
  // 4. stock GAT x2
  float* xc = xA; float* xn = xB;
  const ushort* btWl[2] = {bt_sWl0, bt_sWl1};
  const ushort* btWr[2] = {bt_sWr0, bt_sWr1};
  for (int l = 0; l < 2; l++) {
    const float* bl = stock_bl + (size_t)l * HD;
    const float* br = stock_br + (size_t)l * HD;
    const float* at = stock_att + (size_t)l * HD;
    const float* bi = stock_bias + (size_t)l * HD;
    const float* lg = stock_g + (size_t)l * HD;
    const float* lb = stock_b + (size_t)l * HD;
    gemm_b(xc, HD, btWl[l], bl, xlr_b, 512, N, 256, 256, ACT_NONE);
    gemm_b(xc, HD, btWr[l], br, xlr_b + 256, 512, N, 256, 256, ACT_NONE);
    k_gat_wave<<<dim3((N + 3) / 4), dim3(256), 0, stream>>>(xc, xlr_b, rowptr, esrc,
                                                            at, bi, lg, lb, xn, N);
    float* tp = xc; xc = xn; xn = tp;
  }
  // 5. attention pooling to sectors
  gemm_f(xc, HD, bt_Wa1, ba1, hA, 128, N, 128, 256, ACT_TANH);
  k_rowdot<<<dim3((N + 3) / 4), dim3(256), 0, stream>>>(hA, Wa2, ba2, scpool, N, 128, 1, 0);
  k_hist_arr<<<dim3(512), dim3(256), 0, stream>>>(batch, N, bcnt);
  k_scan_excl<<<dim3(1), dim3(1024), 0, stream>>>(bcnt, bptr, S);
  k_sector_pool<<<dim3(S), dim3(256), 0, stream>>>(xc, scpool, bptr, seA, S);
  // 6. sector CSR + GAT x2
  k_hist_edges<<<dim3(64), dim3(256), 0, stream>>>(ei_sector + ES, ES, S, cntS);
  k_scan_excl<<<dim3(1), dim3(1024), 0, stream>>>(cntS, rptrS, S);
  k_scatter_edges<<<dim3(64), dim3(256), 0, stream>>>(ei_sector, ei_sector + ES, ES, S,
                                                      rptrS, fillS, esrcS);
  float* sec = seA; float* sen = seB;
  const ushort* btEl[2] = {bt_eWl0, bt_eWl1};
  const ushort* btEr[2] = {bt_eWr0, bt_eWr1};
  for (int l = 0; l < 2; l++) {
    const float* bl = sector_bl + (size_t)l * HD;
    const float* br = sector_br + (size_t)l * HD;
    const float* at = sector_att + (size_t)l * HD;
    const float* bi = sector_bias + (size_t)l * HD;
    const float* lg = sector_g + (size_t)l * HD;
    const float* lb = sector_b + (size_t)l * HD;
    gemm_b(sec, HD, btEl[l], bl, selr_b, 512, S, 256, 256, ACT_NONE);
    gemm_b(sec, HD, btEr[l], br, selr_b + 256, 512, S, 256, 256, ACT_NONE);
    k_gat_wave<<<dim3((S + 3) / 4), dim3(256), 0, stream>>>(sec, selr_b, rptrS, esrcS,
                                                            at, bi, lg, lb, sen, S);
    float* tp = sec; sec = sen; sen = tp;
  }
  // 7. fusion -> c (output)
  k_comb<<<dim3(4096), dim3(256), 0, stream>>>(xc, sec, batch, comb, N);
  gemm_f(comb, 512, bt_Wf, bf, tmpY, HD, N, 256, 512, ACT_NONE);
  k_ln_rows<<<dim3(N), dim3(256), 0, stream>>>(tmpY, out_c, gf, bef, N, 2);
  // 8a. regression head
  gemm_f(out_c, HD, bt_Wreg, b_regf, tmpY, HD, N, 256, 256, ACT_NONE);
  k_ln_rows<<<dim3(N), dim3(256), 0, stream>>>(tmpY, headbuf, g_regf, be_regf, N, 1);
  gemm_f(headbuf, HD, bt_Wr1, br1, t128, 128, N, 128, 256, ACT_RELU);
  gemm_f(t128, 128, bt_Wr2, br2, t64, 64, N, 64, 128, ACT_RELU);
  k_rowdot<<<dim3((N + 3) / 4), dim3(256), 0, stream>>>(t64, Wr3, br3, out_ret, N, 64, 1, 3);
  // 8b. classification head
  gemm_f(out_c, HD, bt_Wclf, b_clff, tmpY, HD, N, 256, 256, ACT_NONE);
  k_ln_rows<<<dim3(N), dim3(256), 0, stream>>>(tmpY, headbuf, g_clff, be_clff, N, 1);
  gemm_f(headbuf, HD, bt_Wc1, bc1, t128, 128, N, 128, 256, ACT_RELU);
  k_rowdot<<<dim3((N + 3) / 4), dim3(256), 0, stream>>>(t128, Wc2, bc2, out_mov, N, 128, 2, 0);
  // 8c. ranking head
  gemm_f(out_c, HD, bt_Wrnk, b_rnkf, tmpY, HD, N, 256, 256, ACT_NONE);
  k_ln_rows<<<dim3(N), dim3(256), 0, stream>>>(tmpY, headbuf, g_rnkf, be_rnkf, N, 1);
  gemm_f(headbuf, HD, bt_Wk1, bk1, t128, 128, N, 128, 256, ACT_RELU);
  k_rowdot<<<dim3((N + 3) / 4), dim3(256), 0, stream>>>(t128, Wk2, bk2, out_rnk, N, 128, 1, 4);
}

// Round 6
// 3070.670 us; speedup vs baseline: 5.8439x; 1.1020x over previous
//
#include <hip/hip_runtime.h>
#include <stdint.h>

static constexpr int TT = 20;     // timesteps
static constexpr int FF = 64;     // input features
static constexpr int HD = 256;    // hidden dim

enum { ACT_NONE = 0, ACT_RELU = 1, ACT_TANH = 2 };

typedef __attribute__((ext_vector_type(8))) short short8;
typedef __attribute__((ext_vector_type(4))) float f32x4;

static __device__ __forceinline__ float sigf(float x) { return 1.f / (1.f + expf(-x)); }

static __device__ __forceinline__ ushort f2bf(float f) {
  uint32_t u = __float_as_uint(f);
  return (ushort)((u + 0x7fffu + ((u >> 16) & 1u)) >> 16);
}
static __device__ __forceinline__ float bf2f(ushort u) {
  return __uint_as_float(((uint32_t)u) << 16);
}
static __device__ __forceinline__ void gl16(const void* g, void* l) {
  __builtin_amdgcn_global_load_lds(
      (const __attribute__((address_space(1))) uint32_t*)g,
      (__attribute__((address_space(3))) uint32_t*)l, 16, 0, 0);
}

// ---------------- feature LN + bf16 convert ----------------
__global__ void k_lncvt(const float* __restrict__ x, const float* __restrict__ g,
                        const float* __restrict__ b, ushort* __restrict__ y, int rows) {
  int row = blockIdx.x * 4 + (threadIdx.x >> 6);
  int lane = threadIdx.x & 63;
  if (row >= rows) return;
  float v = x[(size_t)row * 64 + lane];
  float s = v, s2 = v * v;
  for (int o = 32; o; o >>= 1) { s += __shfl_xor(s, o); s2 += __shfl_xor(s2, o); }
  float m = s * (1.f / 64.f);
  float var = s2 * (1.f / 64.f) - m * m;
  float rs = rsqrtf(var + 1e-5f);
  y[(size_t)row * 64 + lane] = f2bf((v - m) * rs * g[lane] + b[lane]);
}

// ---------------- build pre-tiled/swizzled bf16 gate weights (LSTM) ----------------
__global__ void k_build_wtile(const float* __restrict__ w_ih, const float* __restrict__ w_hh,
                              ushort* __restrict__ wt, int KI, int KT) {
  int total = 8 * KT * 512;
  for (int idx = blockIdx.x * blockDim.x + threadIdx.x; idx < total;
       idx += gridDim.x * blockDim.x) {
    int nb = idx / (KT * 512);
    int rem = idx % (KT * 512);
    int kt = rem / 512;
    int q = rem % 512;
    int r = q >> 2, csw = q & 3;
    int ch = csw ^ ((r >> 1) & 3);
    int col = nb * 128 + r;
    int hdblk = col >> 6, gg = (col >> 4) & 3, hd = hdblk * 16 + (col & 15);
    int orow = gg * HD + hd;
    int k = kt * 32 + ch * 8;
    const float* src = (k < KI) ? (w_ih + (size_t)orow * KI + k)
                                : (w_hh + (size_t)orow * HD + (k - KI));
    ushort* dst = wt + (size_t)idx * 8;
#pragma unroll
    for (int j = 0; j < 8; j++) dst[j] = f2bf(src[j]);
  }
}

__global__ void k_build_bcp(const float* __restrict__ bi, const float* __restrict__ bh,
                            float* __restrict__ bcp) {
  int col = blockIdx.x * blockDim.x + threadIdx.x;
  if (col >= 1024) return;
  int hdblk = col >> 6, gg = (col >> 4) & 3, hd = hdblk * 16 + (col & 15);
  int orow = gg * HD + hd;
  bcp[col] = bi[orow] + bh[orow];
}

// ---------------- build tiled bf16 B for generic GEMM ----------------
__global__ void k_build_btile(const float* __restrict__ B, ushort* __restrict__ bt,
                              int K, int Nn, int NB) {
  int KTb = K / 32;
  int total = NB * KTb * 512;
  for (int idx = blockIdx.x * blockDim.x + threadIdx.x; idx < total;
       idx += gridDim.x * blockDim.x) {
    int nb = idx / (KTb * 512);
    int rem = idx % (KTb * 512);
    int kt = rem / 512;
    int q = rem % 512;
    int r = q >> 2, csw = q & 3;
    int ch = csw ^ ((r >> 1) & 3);
    int col = nb * 128 + r;
    int k = kt * 32 + ch * 8;
    ushort* dst = bt + (size_t)idx * 8;
#pragma unroll
    for (int j = 0; j < 8; j++)
      dst[j] = (col < Nn) ? f2bf(B[(size_t)(k + j) * Nn + col]) : (ushort)0;
  }
}

__global__ void k_cat2(const float* __restrict__ a, const float* __restrict__ b,
                       float* __restrict__ o) {
  int i = blockIdx.x * 256 + threadIdx.x;
  if (i < 256) o[i] = a[i];
  else if (i < 512) o[i] = b[i - 256];
}

// ---------------- LSTM MFMA body (shared by single + pair kernels) ----------------
template <int LAYER>
__device__ __forceinline__ void lstm_body(
    ushort* At, ushort* Bt,
    const ushort* __restrict__ a0, const ushort* __restrict__ a1,
    const ushort* __restrict__ wt, const float* __restrict__ bcp,
    float* __restrict__ cst, ushort* __restrict__ hnext, int M, int t) {
  constexpr int K = (LAYER == 0) ? 320 : 512;
  constexpr int KT = K / 32;
  constexpr int SEG0 = (LAYER == 0) ? 64 : 256;
  constexpr int LDA0 = (LAYER == 0) ? (TT * FF) : HD;
  const int tid = threadIdx.x;
  const int lane = tid & 63, wid = tid >> 6;
  const int wr = wid >> 1, wc = wid & 1;
  const int m0 = blockIdx.x * 128;
  const int nb = blockIdx.y;
  const int a0t = (LAYER == 0) ? t * FF : 0;

  f32x4 acc[4][4];
#pragma unroll
  for (int i = 0; i < 4; i++)
#pragma unroll
    for (int j = 0; j < 4; j++) acc[i][j] = (f32x4){0.f, 0.f, 0.f, 0.f};

  int rown[2], chn[2];
#pragma unroll
  for (int e = 0; e < 2; e++) {
    int q = e * 256 + tid;
    int r = q >> 2, csw = q & 3;
    rown[e] = r;
    chn[e] = csw ^ ((r >> 1) & 3);
  }
  const size_t wtbase = (size_t)nb * KT * 512;

  for (int kt = 0; kt < KT; ++kt) {
    __syncthreads();
    const int k0 = kt * 32;
#pragma unroll
    for (int e = 0; e < 2; e++) {
      int q = e * 256 + tid;
      int r = rown[e];
      int kg = k0 + chn[e] * 8;
      int grow = m0 + r;
      grow = (grow < M) ? grow : (M - 1);
      const ushort* src = (kg < SEG0)
                              ? (a0 + (size_t)grow * LDA0 + a0t + kg)
                              : (a1 + (size_t)grow * HD + (kg - SEG0));
      gl16(src, &At[q * 8]);
      gl16(wt + (wtbase + (size_t)kt * 512 + q) * 8, &Bt[q * 8]);
    }
    __syncthreads();
    short8 af[4], bfr[4];
#pragma unroll
    for (int i = 0; i < 4; i++) {
      int rA = wr * 64 + i * 16 + (lane & 15);
      int swa = (lane >> 4) ^ ((rA >> 1) & 3);
      af[i] = *(const short8*)&At[rA * 32 + swa * 8];
      int rB = wc * 64 + i * 16 + (lane & 15);
      int swb = (lane >> 4) ^ ((rB >> 1) & 3);
      bfr[i] = *(const short8*)&Bt[rB * 32 + swb * 8];
    }
#pragma unroll
    for (int i = 0; i < 4; i++)
#pragma unroll
      for (int j = 0; j < 4; j++)
        acc[i][j] = __builtin_amdgcn_mfma_f32_16x16x32_bf16(af[i], bfr[j], acc[i][j], 0, 0, 0);
  }
  const int hdlo = lane & 15;
  const int rb = (lane >> 4) * 4;
  const int colb = nb * 128 + wc * 64;
  const float bI = bcp[colb + hdlo];
  const float bF = bcp[colb + 16 + hdlo];
  const float bG = bcp[colb + 32 + hdlo];
  const float bO = bcp[colb + 48 + hdlo];
  const int hd = (nb * 2 + wc) * 16 + hdlo;
#pragma unroll
  for (int i = 0; i < 4; i++) {
#pragma unroll
    for (int r = 0; r < 4; r++) {
      int row = m0 + wr * 64 + i * 16 + rb + r;
      if (row >= M) continue;
      float gi = acc[i][0][r] + bI;
      float gf = acc[i][1][r] + bF;
      float gg = acc[i][2][r] + bG;
      float go = acc[i][3][r] + bO;
      size_t ix = (size_t)row * HD + hd;
      float c = sigf(gf) * cst[ix] + sigf(gi) * tanhf(gg);
      cst[ix] = c;
      hnext[ix] = f2bf(sigf(go) * tanhf(c));
    }
  }
}

template <int LAYER>
__global__ __launch_bounds__(256) void k_lstm_single(
    const ushort* __restrict__ a0, const ushort* __restrict__ a1,
    const ushort* __restrict__ wt, const float* __restrict__ bcp,
    float* __restrict__ cst, ushort* __restrict__ hnext, int M, int t) {
  __shared__ ushort At[128 * 32];
  __shared__ ushort Bt[128 * 32];
  lstm_body<LAYER>(At, Bt, a0, a1, wt, bcp, cst, hnext, M, t);
}

// blockIdx.z == 0: layer1 step t (reads h0cur,h1cur -> h1next)
// blockIdx.z == 1: layer0 step tnext (reads xln,h0cur -> h0next)
__global__ __launch_bounds__(256) void k_lstm_pair(
    const ushort* __restrict__ xln,
    const ushort* __restrict__ h0cur, const ushort* __restrict__ h1cur,
    const ushort* __restrict__ wt0, const float* __restrict__ bcp0,
    const ushort* __restrict__ wt1, const float* __restrict__ bcp1,
    float* __restrict__ c0, float* __restrict__ c1,
    ushort* __restrict__ h0next, ushort* __restrict__ h1next,
    int M, int tnext) {
  __shared__ ushort At[128 * 32];
  __shared__ ushort Bt[128 * 32];
  if (blockIdx.z == 0)
    lstm_body<1>(At, Bt, h0cur, h1cur, wt1, bcp1, c1, h1next, M, 0);
  else
    lstm_body<0>(At, Bt, xln, h0cur, wt0, bcp0, c0, h0next, M, tnext);
}

// ---------------- generic bf16 MFMA GEMM: C = act(A@B + bias) ----------------
template <bool BF16OUT>
__global__ __launch_bounds__(256) void k_gemm_mfma(
    const float* __restrict__ A, int lda, const ushort* __restrict__ BtG,
    const float* __restrict__ bias, void* __restrict__ Cv, int ldc,
    int M, int Nn, int K, int act) {
  const int KTb = K / 32;
  __shared__ ushort At[128 * 32];
  __shared__ ushort Bts[128 * 32];
  const int tid = threadIdx.x;
  const int lane = tid & 63, wid = tid >> 6;
  const int wr = wid >> 1, wc = wid & 1;
  const int m0 = blockIdx.x * 128;
  const int nb = blockIdx.y;

  f32x4 acc[4][4];
#pragma unroll
  for (int i = 0; i < 4; i++)
#pragma unroll
    for (int j = 0; j < 4; j++) acc[i][j] = (f32x4){0.f, 0.f, 0.f, 0.f};

  const size_t btbase = (size_t)nb * KTb * 512;

  for (int kt = 0; kt < KTb; ++kt) {
    __syncthreads();
    const int k0 = kt * 32;
#pragma unroll
    for (int e = 0; e < 2; e++) {
      int q = e * 256 + tid;
      int r = q >> 2, csw = q & 3;
      int ch = csw ^ ((r >> 1) & 3);
      int row = m0 + r;
      row = (row < M) ? row : (M - 1);
      const float* src = A + (size_t)row * lda + k0 + ch * 8;
      float4 f0 = *(const float4*)src;
      float4 f1 = *(const float4*)(src + 4);
      short8 s;
      s[0] = (short)f2bf(f0.x); s[1] = (short)f2bf(f0.y);
      s[2] = (short)f2bf(f0.z); s[3] = (short)f2bf(f0.w);
      s[4] = (short)f2bf(f1.x); s[5] = (short)f2bf(f1.y);
      s[6] = (short)f2bf(f1.z); s[7] = (short)f2bf(f1.w);
      *(short8*)&At[q * 8] = s;
      gl16(BtG + (btbase + (size_t)kt * 512 + q) * 8, &Bts[q * 8]);
    }
    __syncthreads();
    short8 af[4], bfr[4];
#pragma unroll
    for (int i = 0; i < 4; i++) {
      int rA = wr * 64 + i * 16 + (lane & 15);
      int swa = (lane >> 4) ^ ((rA >> 1) & 3);
      af[i] = *(const short8*)&At[rA * 32 + swa * 8];
      int rB = wc * 64 + i * 16 + (lane & 15);
      int swb = (lane >> 4) ^ ((rB >> 1) & 3);
      bfr[i] = *(const short8*)&Bts[rB * 32 + swb * 8];
    }
#pragma unroll
    for (int i = 0; i < 4; i++)
#pragma unroll
      for (int j = 0; j < 4; j++)
        acc[i][j] = __builtin_amdgcn_mfma_f32_16x16x32_bf16(af[i], bfr[j], acc[i][j], 0, 0, 0);
  }
  const int rb = (lane >> 4) * 4;
  const int cl = lane & 15;
#pragma unroll
  for (int i = 0; i < 4; i++) {
#pragma unroll
    for (int j = 0; j < 4; j++) {
      int col = nb * 128 + wc * 64 + j * 16 + cl;
      if (col >= Nn) continue;
      float bv = bias[col];
#pragma unroll
      for (int r = 0; r < 4; r++) {
        int row = m0 + wr * 64 + i * 16 + rb + r;
        if (row >= M) continue;
        float v = acc[i][j][r] + bv;
        if (act == ACT_RELU) v = fmaxf(v, 0.f);
        else if (act == ACT_TANH) v = tanhf(v);
        if (BF16OUT) ((ushort*)Cv)[(size_t)row * ldc + col] = f2bf(v);
        else ((float*)Cv)[(size_t)row * ldc + col] = v;
      }
    }
  }
}

// ---------------- per-row LN over 256 + optional act ----------------
__global__ __launch_bounds__(256) void k_ln_rows(
    const float* __restrict__ in, float* __restrict__ out,
    const float* __restrict__ g, const float* __restrict__ b, int rows, int act) {
  int row = blockIdx.x;
  if (row >= rows) return;
  int tid = threadIdx.x, lane = tid & 63, wv = tid >> 6;
  float v = in[(size_t)row * HD + tid];
  float s = v, s2 = v * v;
  for (int o = 32; o; o >>= 1) { s += __shfl_xor(s, o); s2 += __shfl_xor(s2, o); }
  __shared__ float ws1[4], ws2[4];
  if (lane == 0) { ws1[wv] = s; ws2[wv] = s2; }
  __syncthreads();
  float S1 = ws1[0] + ws1[1] + ws1[2] + ws1[3];
  float S2 = ws2[0] + ws2[1] + ws2[2] + ws2[3];
  float m = S1 * (1.f / 256.f);
  float var = S2 * (1.f / 256.f) - m * m;
  float r = rsqrtf(var + 1e-5f);
  float y = (v - m) * r * g[tid] + b[tid];
  if (act == 1) y = fmaxf(y, 0.f);
  else if (act == 2) y = (y > 0.f) ? y : (expf(y) - 1.f);
  out[(size_t)row * HD + tid] = y;
}

__global__ __launch_bounds__(256) void k_ln_rows_b16(
    const ushort* __restrict__ in, float* __restrict__ out,
    const float* __restrict__ g, const float* __restrict__ b, int rows, int act) {
  int row = blockIdx.x;
  if (row >= rows) return;
  int tid = threadIdx.x, lane = tid & 63, wv = tid >> 6;
  float v = bf2f(in[(size_t)row * HD + tid]);
  float s = v, s2 = v * v;
  for (int o = 32; o; o >>= 1) { s += __shfl_xor(s, o); s2 += __shfl_xor(s2, o); }
  __shared__ float ws1[4], ws2[4];
  if (lane == 0) { ws1[wv] = s; ws2[wv] = s2; }
  __syncthreads();
  float S1 = ws1[0] + ws1[1] + ws1[2] + ws1[3];
  float S2 = ws2[0] + ws2[1] + ws2[2] + ws2[3];
  float m = S1 * (1.f / 256.f);
  float var = S2 * (1.f / 256.f) - m * m;
  float r = rsqrtf(var + 1e-5f);
  float y = (v - m) * r * g[tid] + b[tid];
  if (act == 1) y = fmaxf(y, 0.f);
  else if (act == 2) y = (y > 0.f) ? y : (expf(y) - 1.f);
  out[(size_t)row * HD + tid] = y;
}

// ---------------- CSR build ----------------
__global__ void k_hist_edges(const int* __restrict__ dst, int E, int n, int* __restrict__ cnt) {
  int tot = E + n;
  for (int i = blockIdx.x * blockDim.x + threadIdx.x; i < tot; i += gridDim.x * blockDim.x) {
    int d = (i < E) ? dst[i] : (i - E);
    atomicAdd(&cnt[d], 1);
  }
}

// 3-pass exclusive scan (chunk = 1024)
__global__ void k_scan1(const int* __restrict__ cnt, int* __restrict__ ptr,
                        int* __restrict__ bsum, int n) {
  __shared__ int sm[1024];
  int tid = threadIdx.x, i = blockIdx.x * 1024 + tid;
  int v = (i < n) ? cnt[i] : 0;
  sm[tid] = v;
  __syncthreads();
  for (int off = 1; off < 1024; off <<= 1) {
    int t = (tid >= off) ? sm[tid - off] : 0;
    __syncthreads();
    sm[tid] += t;
    __syncthreads();
  }
  if (i < n) ptr[i] = sm[tid] - v;
  if (tid == 1023) bsum[blockIdx.x] = sm[1023];
}

__global__ void k_scan2(int* __restrict__ bsum, int nb) {
  __shared__ int sm[256];
  int tid = threadIdx.x;
  int v = (tid < nb) ? bsum[tid] : 0;
  sm[tid] = v;
  __syncthreads();
  for (int off = 1; off < 256; off <<= 1) {
    int t = (tid >= off) ? sm[tid - off] : 0;
    __syncthreads();
    sm[tid] += t;
    __syncthreads();
  }
  if (tid < nb) bsum[tid] = sm[tid] - v;
  if (tid == 0) bsum[nb] = sm[255];
}

__global__ void k_scan3(int* __restrict__ ptr, const int* __restrict__ bsum, int n, int nb) {
  int i = blockIdx.x * blockDim.x + threadIdx.x;
  if (i < n) ptr[i] += bsum[i >> 10];
  if (i == n) ptr[n] = bsum[nb];
}

__global__ void k_scatter_edges(const int* __restrict__ src, const int* __restrict__ dst,
                                int E, int n, const int* __restrict__ rowptr,
                                int* __restrict__ fill, int* __restrict__ esrc) {
  int tot = E + n;
  for (int i = blockIdx.x * blockDim.x + threadIdx.x; i < tot; i += gridDim.x * blockDim.x) {
    int d, s;
    if (i < E) { d = dst[i]; s = src[i]; } else { d = i - E; s = i - E; }
    int pos = rowptr[d] + atomicAdd(&fill[d], 1);
    esrc[pos] = s;
  }
}

// ---------------- sorted-batch boundaries: bptr[s] = first i with batch[i] >= s ----------------
__global__ void k_batch_bounds(const int* __restrict__ batch, int* __restrict__ bptr,
                               int n, int S) {
  int i = blockIdx.x * blockDim.x + threadIdx.x;
  if (i > n) return;
  if (i == 0) {
    int b0 = batch[0];
    for (int s = 0; s <= b0; s++) bptr[s] = 0;
  } else if (i == n) {
    int bl = batch[n - 1];
    for (int s = bl + 1; s <= S; s++) bptr[s] = n;
  } else {
    int a = batch[i - 1], b = batch[i];
    for (int s = a + 1; s <= b; s++) bptr[s] = i;
  }
}

// ---------------- flash-style GATv2: one wave per dst node, single pass ----------------
__global__ __launch_bounds__(256) void k_gat_wave(
    const float* __restrict__ xin, const ushort* __restrict__ xlr,
    const int* __restrict__ rowptr, const int* __restrict__ esrc,
    const float* __restrict__ att, const float* __restrict__ bias,
    const float* __restrict__ lng, const float* __restrict__ lnb,
    float* __restrict__ xout, int n_nodes) {
  const int wid = threadIdx.x >> 6;
  const int nd = blockIdx.x * 4 + wid;
  if (nd >= n_nodes) return;
  const int lane = threadIdx.x & 63;
  const int eg = lane >> 4;
  const int dq = lane & 15;
  const int dbase = dq * 16;

  float xr16[16], at16[16];
  {
    const ushort* xr = xlr + (size_t)nd * 512 + 256 + dbase;
    short8 a = *(const short8*)xr;
    short8 b = *(const short8*)(xr + 8);
#pragma unroll
    for (int j = 0; j < 8; j++) { xr16[j] = bf2f((ushort)a[j]); xr16[8 + j] = bf2f((ushort)b[j]); }
    const float* ap = att + dbase;
#pragma unroll
    for (int j = 0; j < 16; j++) at16[j] = ap[j];
  }
  const int rs = rowptr[nd];
  const int deg = rowptr[nd + 1] - rs;

  float m = -3e38f, z = 0.f;
  float acc[16];
#pragma unroll
  for (int j = 0; j < 16; j++) acc[j] = 0.f;

  for (int p = eg; p < deg; p += 4) {
    int src = esrc[rs + p];
    const ushort* xl = xlr + (size_t)src * 512 + dbase;
    short8 a = *(const short8*)xl;
    short8 b = *(const short8*)(xl + 8);
    float xv[16];
#pragma unroll
    for (int j = 0; j < 8; j++) { xv[j] = bf2f((ushort)a[j]); xv[8 + j] = bf2f((ushort)b[j]); }
    float sc = 0.f;
#pragma unroll
    for (int j = 0; j < 16; j++) {
      float v = xv[j] + xr16[j];
      v = (v > 0.f) ? v : 0.2f * v;  // leaky_relu 0.2
      sc = fmaf(v, at16[j], sc);
    }
    sc += __shfl_xor(sc, 1);
    sc += __shfl_xor(sc, 2);
    if (sc > m + 8.f) {
      float r = __expf(m - sc);
      z *= r;
#pragma unroll
      for (int j = 0; j < 16; j++) acc[j] *= r;
      m = sc;
    }
    float w = __expf(sc - m);
    z += w;
#pragma unroll
    for (int j = 0; j < 16; j++) acc[j] = fmaf(w, xv[j], acc[j]);
  }
  float mt = fmaxf(m, __shfl_xor(m, 16));
  mt = fmaxf(mt, __shfl_xor(mt, 32));
  float r = __expf(m - mt);
  z *= r;
  z += __shfl_xor(z, 16);
  z += __shfl_xor(z, 32);
#pragma unroll
  for (int j = 0; j < 16; j++) {
    float a = acc[j] * r;
    a += __shfl_xor(a, 16);
    a += __shfl_xor(a, 32);
    acc[j] = a;
  }
  float zinv = 1.f / (z + 1e-16f);
  const float* xi = xin + (size_t)nd * 256 + dbase;
  const float* bp = bias + dbase;
  float v16[16];
  float s1 = 0.f, s2 = 0.f;
#pragma unroll
  for (int j = 0; j < 16; j++) {
    float v = acc[j] * zinv + bp[j] + xi[j];
    v16[j] = v;
    s1 += v;
    s2 += v * v;
  }
  for (int o = 32; o; o >>= 1) { s1 += __shfl_xor(s1, o); s2 += __shfl_xor(s2, o); }
  float mean = s1 * (1.f / 1024.f);
  float var = s2 * (1.f / 1024.f) - mean * mean;
  float rstd = rsqrtf(var + 1e-5f);
  const float* gp = lng + dbase + eg * 4;
  const float* bb = lnb + dbase + eg * 4;
  float4 o4;
#pragma unroll
  for (int jj = 0; jj < 4; jj++) {
    float y = (v16[eg * 4 + jj] - mean) * rstd * gp[jj] + bb[jj];
    y = (y > 0.f) ? y : (expf(y) - 1.f);
    (&o4.x)[jj] = y;
  }
  *(float4*)(xout + (size_t)nd * 256 + dbase + eg * 4) = o4;
}

// ---------------- small row-dot heads ----------------
__global__ void k_rowdot(const float* __restrict__ in, const float* __restrict__ W,
                         const float* __restrict__ bias, float* __restrict__ out,
                         int rows, int K, int OC, int act) {
  int row = blockIdx.x * 4 + (threadIdx.x >> 6);
  if (row >= rows) return;
  int lane = threadIdx.x & 63;
  for (int o = 0; o < OC; o++) {
    float s = 0.f;
    for (int k = lane; k < K; k += 64) s += in[(size_t)row * K + k] * W[(size_t)k * OC + o];
    for (int off = 32; off; off >>= 1) s += __shfl_xor(s, off);
    if (lane == 0) {
      float v = s + bias[o];
      if (act == 3) v = tanhf(v) * 0.1f;
      else if (act == 4) v = 1.f / (1.f + expf(-v));
      out[(size_t)row * OC + o] = v;
    }
  }
}

// ---------------- sector attention pooling ----------------
__global__ __launch_bounds__(256) void k_sector_pool(
    const float* __restrict__ x, const float* __restrict__ sc,
    const int* __restrict__ bptr, float* __restrict__ se, int S) {
  const int s = blockIdx.x, tid = threadIdx.x, lane = tid & 63, wv = tid >> 6;
  const int rs = bptr[s], re = bptr[s + 1];
  const int cnt = re - rs;
  __shared__ float r1[4], r2[4], wch[256];
  float mx = -3e38f;
  for (int i = rs + tid; i < re; i += 256) mx = fmaxf(mx, sc[i]);
  for (int o = 32; o; o >>= 1) mx = fmaxf(mx, __shfl_xor(mx, o));
  if (lane == 0) r1[wv] = mx;
  __syncthreads();
  float m = fmaxf(fmaxf(r1[0], r1[1]), fmaxf(r1[2], r1[3]));
  if (cnt == 0) m = 0.f;
  float z = 0.f;
  for (int i = rs + tid; i < re; i += 256) z += expf(sc[i] - m);
  for (int o = 32; o; o >>= 1) z += __shfl_xor(z, o);
  if (lane == 0) r2[wv] = z;
  __syncthreads();
  float zinv = 1.f / (r2[0] + r2[1] + r2[2] + r2[3] + 1e-16f);
  float acc = 0.f;
  for (int base = rs; base < re; base += 256) {
    int i = base + tid;
    wch[tid] = (i < re) ? expf(sc[i] - m) * zinv : 0.f;
    __syncthreads();
    int lim = re - base; if (lim > 256) lim = 256;
    for (int q = 0; q < lim; q++) acc += wch[q] * x[(size_t)(base + q) * HD + tid];
    __syncthreads();
  }
  se[(size_t)s * HD + tid] = acc / fmaxf((float)cnt, 1.f);
}

// ---------------- comb = [x | se[batch]] ----------------
__global__ void k_comb(const float* __restrict__ x, const float* __restrict__ se,
                       const int* __restrict__ batch, float* __restrict__ comb, int n) {
  int total = n * 512;
  for (int i = blockIdx.x * blockDim.x + threadIdx.x; i < total; i += gridDim.x * blockDim.x) {
    int row = i >> 9, col = i & 511;
    comb[i] = (col < HD) ? x[(size_t)row * HD + col]
                         : se[(size_t)batch[row] * HD + (col - HD)];
  }
}

extern "C" void kernel_launch(void* const* d_in, const int* in_sizes, int n_in,
                              void* d_out, int out_size, void* d_ws, size_t ws_size,
                              hipStream_t stream) {
  const float* x_stock   = (const float*)d_in[0];
  const int*   ei_stock  = (const int*)d_in[1];
  const int*   batch     = (const int*)d_in[2];
  const int*   ei_sector = (const int*)d_in[4];
  const float* ln_feat_g = (const float*)d_in[5];
  const float* ln_feat_b = (const float*)d_in[6];
  const float* w_ih0 = (const float*)d_in[7];
  const float* w_hh0 = (const float*)d_in[8];
  const float* b_ih0 = (const float*)d_in[9];
  const float* b_hh0 = (const float*)d_in[10];
  const float* w_ih1 = (const float*)d_in[11];
  const float* w_hh1 = (const float*)d_in[12];
  const float* b_ih1 = (const float*)d_in[13];
  const float* b_hh1 = (const float*)d_in[14];
  const float* ln_t_g = (const float*)d_in[15];
  const float* ln_t_b = (const float*)d_in[16];
  const float* W_in = (const float*)d_in[17];
  const float* b_in = (const float*)d_in[18];
  const float* stock_Wl = (const float*)d_in[19];
  const float* stock_bl = (const float*)d_in[20];
  const float* stock_Wr = (const float*)d_in[21];
  const float* stock_br = (const float*)d_in[22];
  const float* stock_att = (const float*)d_in[23];
  const float* stock_bias = (const float*)d_in[24];
  const float* stock_g = (const float*)d_in[25];
  const float* stock_b = (const float*)d_in[26];
  const float* sector_Wl = (const float*)d_in[27];
  const float* sector_bl = (const float*)d_in[28];
  const float* sector_Wr = (const float*)d_in[29];
  const float* sector_br = (const float*)d_in[30];
  const float* sector_att = (const float*)d_in[31];
  const float* sector_bias = (const float*)d_in[32];
  const float* sector_g = (const float*)d_in[33];
  const float* sector_b = (const float*)d_in[34];
  const float* Wa1 = (const float*)d_in[35];
  const float* ba1 = (const float*)d_in[36];
  const float* Wa2 = (const float*)d_in[37];
  const float* ba2 = (const float*)d_in[38];
  const float* Wf  = (const float*)d_in[39];
  const float* bf  = (const float*)d_in[40];
  const float* gf  = (const float*)d_in[41];
  const float* bef = (const float*)d_in[42];
  const float* W_regf = (const float*)d_in[43];
  const float* b_regf = (const float*)d_in[44];
  const float* g_regf = (const float*)d_in[45];
  const float* be_regf = (const float*)d_in[46];
  const float* W_clff = (const float*)d_in[47];
  const float* b_clff = (const float*)d_in[48];
  const float* g_clff = (const float*)d_in[49];
  const float* be_clff = (const float*)d_in[50];
  const float* W_rnkf = (const float*)d_in[51];
  const float* b_rnkf = (const float*)d_in[52];
  const float* g_rnkf = (const float*)d_in[53];
  const float* be_rnkf = (const float*)d_in[54];
  const float* Wr1 = (const float*)d_in[55];
  const float* br1 = (const float*)d_in[56];
  const float* Wr2 = (const float*)d_in[57];
  const float* br2 = (const float*)d_in[58];
  const float* Wr3 = (const float*)d_in[59];
  const float* br3 = (const float*)d_in[60];
  const float* Wc1 = (const float*)d_in[61];
  const float* bc1 = (const float*)d_in[62];
  const float* Wc2 = (const float*)d_in[63];
  const float* bc2 = (const float*)d_in[64];
  const float* Wk1 = (const float*)d_in[65];
  const float* bk1 = (const float*)d_in[66];
  const float* Wk2 = (const float*)d_in[67];
  const float* bk2 = (const float*)d_in[68];

  const int N  = in_sizes[0] / (TT * FF);
  const int E  = in_sizes[1] / 2;
  const int S  = in_sizes[3] / HD;
  const int ES = in_sizes[4] / 2;
  const int Ep = E + N, ESp = ES + S;
  const int NT = N * TT;
  const int KT0 = 10, KT1 = 16;

  char* wsb = (char*)d_ws;
  size_t off = 0;
  auto alloc = [&](size_t bytes) -> char* {
    char* p = wsb + off;
    off += (bytes + 255) & ~(size_t)255;
    return p;
  };
  // zero-init group (h/c states)
  ushort* h0a = (ushort*)alloc((size_t)N * HD * 2);
  ushort* h1a = (ushort*)alloc((size_t)N * HD * 2);
  float*  c0  = (float*)alloc((size_t)N * HD * 4);
  float*  c1  = (float*)alloc((size_t)N * HD * 4);
  size_t zf_bytes = off;
  ushort* h0b = (ushort*)alloc((size_t)N * HD * 2);
  ushort* h1b = (ushort*)alloc((size_t)N * HD * 2);
  ushort* wt0 = (ushort*)alloc((size_t)8 * KT0 * 512 * 16);
  ushort* wt1 = (ushort*)alloc((size_t)8 * KT1 * 512 * 16);
  float* bcp0 = (float*)alloc(1024 * 4);
  float* bcp1 = (float*)alloc(1024 * 4);
  float* xA  = (float*)alloc((size_t)N * HD * 4);
  float* xB  = (float*)alloc((size_t)N * HD * 4);
  char*  xlr_raw = alloc((size_t)N * 512 * 4);          // bf16 xl|xr; later f32 comb
  float* scbuf = (float*)alloc((size_t)N * 128 * 4);    // hA buffer
  char*  selr_raw = alloc((size_t)S * 512 * 4);
  float* seA  = (float*)alloc((size_t)S * HD * 4);
  float* seB  = (float*)alloc((size_t)S * HD * 4);
  float* scpool = (float*)alloc((size_t)N * 4);
  char* bigraw = alloc((size_t)N * TT * FF * 2);
  ushort* xln    = (ushort*)bigraw;
  float*  tmpY   = (float*)bigraw;
  float*  headbuf = (float*)(bigraw + (size_t)N * HD * 4);
  // tiled bf16 weights
  auto alloc_bt = [&](int K, int Nn) -> ushort* {
    int NB = (Nn + 127) / 128;
    return (ushort*)alloc((size_t)NB * (K / 32) * 512 * 16);
  };
  ushort* bt_Win  = alloc_bt(256, 256);
  ushort* bt_slr0 = alloc_bt(256, 512);   // [Wl|Wr] stock layer0
  ushort* bt_slr1 = alloc_bt(256, 512);
  ushort* bt_elr0 = alloc_bt(256, 512);
  ushort* bt_elr1 = alloc_bt(256, 512);
  ushort* bt_Wa1  = alloc_bt(256, 128);
  ushort* bt_Wf   = alloc_bt(512, 256);
  ushort* bt_Wreg = alloc_bt(256, 256);
  ushort* bt_Wclf = alloc_bt(256, 256);
  ushort* bt_Wrnk = alloc_bt(256, 256);
  ushort* bt_Wr1  = alloc_bt(256, 128);
  ushort* bt_Wr2  = alloc_bt(128, 64);
  ushort* bt_Wc1  = alloc_bt(256, 128);
  ushort* bt_Wk1  = alloc_bt(256, 128);
  float* bc_slr0 = (float*)alloc(512 * 4);
  float* bc_slr1 = (float*)alloc(512 * 4);
  float* bc_elr0 = (float*)alloc(512 * 4);
  float* bc_elr1 = (float*)alloc(512 * 4);
  size_t zi_start = off;
  int* cnt   = (int*)alloc((size_t)(N + 1) * 4);
  int* fill  = (int*)alloc((size_t)N * 4);
  int* cntS  = (int*)alloc((size_t)(S + 1) * 4);
  int* fillS = (int*)alloc((size_t)S * 4);
  size_t zi_bytes = off - zi_start;
  int* rowptr = (int*)alloc((size_t)(N + 1) * 4);
  int* esrc   = (int*)alloc((size_t)Ep * 4);
  int* rptrS  = (int*)alloc((size_t)(S + 1) * 4);
  int* esrcS  = (int*)alloc((size_t)ESp * 4);
  int* bptr   = (int*)alloc((size_t)(S + 1) * 4);
  int* bsum1  = (int*)alloc(64 * 4);
  int* bsum2  = (int*)alloc(64 * 4);

  ushort* xlr_b = (ushort*)xlr_raw;
  float*  comb  = (float*)xlr_raw;
  ushort* selr_b = (ushort*)selr_raw;
  float* hA   = scbuf;
  float* t128 = tmpY;
  float* t64  = tmpY + (size_t)N * 128;
  float* out_ret = (float*)d_out;
  float* out_mov = out_ret + N;
  float* out_rnk = out_ret + 3 * (size_t)N;
  float* out_c   = out_ret + 4 * (size_t)N;

  hipMemsetAsync(d_ws, 0, zf_bytes, stream);
  hipMemsetAsync(wsb + zi_start, 0, zi_bytes, stream);

  auto build_bt = [&](const float* W, ushort* bt, int K, int Nn) {
    int NB = (Nn + 127) / 128;
    int total = NB * (K / 32) * 512;
    k_build_btile<<<dim3((total + 255) / 256), dim3(256), 0, stream>>>(W, bt, K, Nn, NB);
  };
  auto gemm_f = [&](const float* A, int lda, const ushort* bt, const float* bias,
                    float* C, int ldc, int M, int Nn, int K, int act) {
    dim3 g((M + 127) / 128, (Nn + 127) / 128);
    k_gemm_mfma<false><<<g, dim3(256), 0, stream>>>(A, lda, bt, bias, C, ldc, M, Nn, K, act);
  };
  auto gemm_b = [&](const float* A, int lda, const ushort* bt, const float* bias,
                    ushort* C, int ldc, int M, int Nn, int K, int act) {
    dim3 g((M + 127) / 128, (Nn + 127) / 128);
    k_gemm_mfma<true><<<g, dim3(256), 0, stream>>>(A, lda, bt, bias, C, ldc, M, Nn, K, act);
  };
  const int TILE2 = 2 * 8 * 512 * 8;  // elems per 2-tile (Nn=256) btile block

  // 1. feature-LN + bf16 convert; prebuild all tiled bf16 weights
  k_lncvt<<<dim3((NT + 3) / 4), dim3(256), 0, stream>>>(x_stock, ln_feat_g, ln_feat_b, xln, NT);
  k_build_wtile<<<dim3((8 * KT0 * 512 + 255) / 256), dim3(256), 0, stream>>>(w_ih0, w_hh0, wt0, FF, KT0);
  k_build_wtile<<<dim3((8 * KT1 * 512 + 255) / 256), dim3(256), 0, stream>>>(w_ih1, w_hh1, wt1, HD, KT1);
  k_build_bcp<<<dim3(4), dim3(256), 0, stream>>>(b_ih0, b_hh0, bcp0);
  k_build_bcp<<<dim3(4), dim3(256), 0, stream>>>(b_ih1, b_hh1, bcp1);
  build_bt(W_in, bt_Win, 256, 256);
  build_bt(stock_Wl, bt_slr0, 256, 256);
  build_bt(stock_Wr, bt_slr0 + TILE2, 256, 256);
  build_bt(stock_Wl + HD * HD, bt_slr1, 256, 256);
  build_bt(stock_Wr + HD * HD, bt_slr1 + TILE2, 256, 256);
  build_bt(sector_Wl, bt_elr0, 256, 256);
  build_bt(sector_Wr, bt_elr0 + TILE2, 256, 256);
  build_bt(sector_Wl + HD * HD, bt_elr1, 256, 256);
  build_bt(sector_Wr + HD * HD, bt_elr1 + TILE2, 256, 256);
  k_cat2<<<dim3(2), dim3(256), 0, stream>>>(stock_bl, stock_br, bc_slr0);
  k_cat2<<<dim3(2), dim3(256), 0, stream>>>(stock_bl + HD, stock_br + HD, bc_slr1);
  k_cat2<<<dim3(2), dim3(256), 0, stream>>>(sector_bl, sector_br, bc_elr0);
  k_cat2<<<dim3(2), dim3(256), 0, stream>>>(sector_bl + HD, sector_br + HD, bc_elr1);
  build_bt(Wa1, bt_Wa1, 256, 128);
  build_bt(Wf, bt_Wf, 512, 256);
  build_bt(W_regf, bt_Wreg, 256, 256);
  build_bt(W_clff, bt_Wclf, 256, 256);
  build_bt(W_rnkf, bt_Wrnk, 256, 256);
  build_bt(Wr1, bt_Wr1, 256, 128);
  build_bt(Wr2, bt_Wr2, 128, 64);
  build_bt(Wc1, bt_Wc1, 256, 128);
  build_bt(Wk1, bt_Wk1, 256, 128);

  // 2. LSTM via MFMA: L0[0]; 19x pair(L1[t] || L0[t+1]); L1[19]
  {
    const int MB = (N + 127) / 128;
    ushort *h0c = h0a, *h0n = h0b, *h1c = h1a, *h1n = h1b;
    k_lstm_single<0><<<dim3(MB, 8), dim3(256), 0, stream>>>(xln, h0c, wt0, bcp0, c0, h0n, N, 0);
    { ushort* tp = h0c; h0c = h0n; h0n = tp; }   // h0c = h0[0]
    for (int t = 0; t < TT - 1; t++) {
      k_lstm_pair<<<dim3(MB, 8, 2), dim3(256), 0, stream>>>(
          xln, h0c, h1c, wt0, bcp0, wt1, bcp1, c0, c1, h0n, h1n, N, t + 1);
      ushort* tp = h0c; h0c = h0n; h0n = tp;     // h0c = h0[t+1]
      tp = h1c; h1c = h1n; h1n = tp;             // h1c = h1[t]
    }
    k_lstm_single<1><<<dim3(MB, 8), dim3(256), 0, stream>>>(h0c, h1c, wt1, bcp1, c1, h1n, N, 0);
    k_ln_rows_b16<<<dim3(N), dim3(256), 0, stream>>>(h1n, tmpY, ln_t_g, ln_t_b, N, 0);
  }
  gemm_f(tmpY, HD, bt_Win, b_in, xA, HD, N, 256, 256, ACT_NONE);

  // 3. stock CSR (with self loops)
  {
    int nb1 = (N + 1023) / 1024;
    k_hist_edges<<<dim3(2048), dim3(256), 0, stream>>>(ei_stock + E, E, N, cnt);
    k_scan1<<<dim3(nb1), dim3(1024), 0, stream>>>(cnt, rowptr, bsum1, N);
    k_scan2<<<dim3(1), dim3(256), 0, stream>>>(bsum1, nb1);
    k_scan3<<<dim3((N + 256) / 256), dim3(256), 0, stream>>>(rowptr, bsum1, N, nb1);
    k_scatter_edges<<<dim3(2048), dim3(256), 0, stream>>>(ei_stock, ei_stock + E, E, N,
                                                          rowptr, fill, esrc);
  }
  // 4. stock GAT x2 (fused [Wl|Wr] projection)
  float* xc = xA; float* xn = xB;
  const ushort* btS[2] = {bt_slr0, bt_slr1};
  const float*  bcS[2] = {bc_slr0, bc_slr1};
  for (int l = 0; l < 2; l++) {
    const float* at = stock_att + (size_t)l * HD;
    const float* bi = stock_bias + (size_t)l * HD;
    const float* lg = stock_g + (size_t)l * HD;
    const float* lb = stock_b + (size_t)l * HD;
    gemm_b(xc, HD, btS[l], bcS[l], xlr_b, 512, N, 512, 256, ACT_NONE);
    k_gat_wave<<<dim3((N + 3) / 4), dim3(256), 0, stream>>>(xc, xlr_b, rowptr, esrc,
                                                            at, bi, lg, lb, xn, N);
    float* tp = xc; xc = xn; xn = tp;
  }
  // 5. attention pooling to sectors (bptr from sorted batch, no atomics)
  gemm_f(xc, HD, bt_Wa1, ba1, hA, 128, N, 128, 256, ACT_TANH);
  k_rowdot<<<dim3((N + 3) / 4), dim3(256), 0, stream>>>(hA, Wa2, ba2, scpool, N, 128, 1, 0);
  k_batch_bounds<<<dim3((N + 256) / 256), dim3(256), 0, stream>>>(batch, bptr, N, S);
  k_sector_pool<<<dim3(S), dim3(256), 0, stream>>>(xc, scpool, bptr, seA, S);
  // 6. sector CSR + GAT x2
  {
    int nb1 = (S + 1023) / 1024;
    k_hist_edges<<<dim3(64), dim3(256), 0, stream>>>(ei_sector + ES, ES, S, cntS);
    k_scan1<<<dim3(nb1), dim3(1024), 0, stream>>>(cntS, rptrS, bsum2, S);
    k_scan2<<<dim3(1), dim3(256), 0, stream>>>(bsum2, nb1);
    k_scan3<<<dim3((S + 256) / 256), dim3(256), 0, stream>>>(rptrS, bsum2, S, nb1);
    k_scatter_edges<<<dim3(64), dim3(256), 0, stream>>>(ei_sector, ei_sector + ES, ES, S,
                                                        rptrS, fillS, esrcS);
  }
  float* sec = seA; float* sen = seB;
  const ushort* btE[2] = {bt_elr0, bt_elr1};
  const float*  bcE[2] = {bc_elr0, bc_elr1};
  for (int l = 0; l < 2; l++) {
    const float* at = sector_att + (size_t)l * HD;
    const float* bi = sector_bias + (size_t)l * HD;
    const float* lg = sector_g + (size_t)l * HD;
    const float* lb = sector_b + (size_t)l * HD;
    gemm_b(sec, HD, btE[l], bcE[l], selr_b, 512, S, 512, 256, ACT_NONE);
    k_gat_wave<<<dim3((S + 3) / 4), dim3(256), 0, stream>>>(sec, selr_b, rptrS, esrcS,
                                                            at, bi, lg, lb, sen, S);
    float* tp = sec; sec = sen; sen = tp;
  }
  // 7. fusion -> c (output)
  k_comb<<<dim3(4096), dim3(256), 0, stream>>>(xc, sec, batch, comb, N);
  gemm_f(comb, 512, bt_Wf, bf, tmpY, HD, N, 256, 512, ACT_NONE);
  k_ln_rows<<<dim3(N), dim3(256), 0, stream>>>(tmpY, out_c, gf, bef, N, 2);
  // 8a. regression head
  gemm_f(out_c, HD, bt_Wreg, b_regf, tmpY, HD, N, 256, 256, ACT_NONE);
  k_ln_rows<<<dim3(N), dim3(256), 0, stream>>>(tmpY, headbuf, g_regf, be_regf, N, 1);
  gemm_f(headbuf, HD, bt_Wr1, br1, t128, 128, N, 128, 256, ACT_RELU);
  gemm_f(t128, 128, bt_Wr2, br2, t64, 64, N, 64, 128, ACT_RELU);
  k_rowdot<<<dim3((N + 3) / 4), dim3(256), 0, stream>>>(t64, Wr3, br3, out_ret, N, 64, 1, 3);
  // 8b. classification head
  gemm_f(out_c, HD, bt_Wclf, b_clff, tmpY, HD, N, 256, 256, ACT_NONE);
  k_ln_rows<<<dim3(N), dim3(256), 0, stream>>>(tmpY, headbuf, g_clff, be_clff, N, 1);
  gemm_f(headbuf, HD, bt_Wc1, bc1, t128, 128, N, 128, 256, ACT_RELU);
  k_rowdot<<<dim3((N + 3) / 4), dim3(256), 0, stream>>>(t128, Wc2, bc2, out_mov, N, 128, 2, 0);
  // 8c. ranking head
  gemm_f(out_c, HD, bt_Wrnk, b_rnkf, tmpY, HD, N, 256, 256, ACT_NONE);
  k_ln_rows<<<dim3(N), dim3(256), 0, stream>>>(tmpY, headbuf, g_rnkf, be_rnkf, N, 1);
  gemm_f(headbuf, HD, bt_Wk1, bk1, t128, 128, N, 128, 256, ACT_RELU);
  k_rowdot<<<dim3((N + 3) / 4), dim3(256), 0, stream>>>(t128, Wk2, bk2, out_rnk, N, 128, 1, 4);
}

// Round 7
// 2626.801 us; speedup vs baseline: 6.8314x; 1.1690x over previous
//
#include <hip/hip_runtime.h>
#include <stdint.h>

static constexpr int TT = 20;     // timesteps
static constexpr int FF = 64;     // input features
static constexpr int HD = 256;    // hidden dim

enum { ACT_NONE = 0, ACT_RELU = 1, ACT_TANH = 2 };

typedef __attribute__((ext_vector_type(8))) short short8;
typedef __attribute__((ext_vector_type(4))) float f32x4;

static __device__ __forceinline__ float sigf(float x) { return 1.f / (1.f + expf(-x)); }

static __device__ __forceinline__ ushort f2bf(float f) {
  uint32_t u = __float_as_uint(f);
  return (ushort)((u + 0x7fffu + ((u >> 16) & 1u)) >> 16);
}
static __device__ __forceinline__ float bf2f(ushort u) {
  return __uint_as_float(((uint32_t)u) << 16);
}
static __device__ __forceinline__ void gl16(const void* g, void* l) {
  __builtin_amdgcn_global_load_lds(
      (const __attribute__((address_space(1))) uint32_t*)g,
      (__attribute__((address_space(3))) uint32_t*)l, 16, 0, 0);
}

// ---------------- feature LN + bf16 convert ----------------
__global__ void k_lncvt(const float* __restrict__ x, const float* __restrict__ g,
                        const float* __restrict__ b, ushort* __restrict__ y, int rows) {
  int row = blockIdx.x * 4 + (threadIdx.x >> 6);
  int lane = threadIdx.x & 63;
  if (row >= rows) return;
  float v = x[(size_t)row * 64 + lane];
  float s = v, s2 = v * v;
  for (int o = 32; o; o >>= 1) { s += __shfl_xor(s, o); s2 += __shfl_xor(s2, o); }
  float m = s * (1.f / 64.f);
  float var = s2 * (1.f / 64.f) - m * m;
  float rs = rsqrtf(var + 1e-5f);
  y[(size_t)row * 64 + lane] = f2bf((v - m) * rs * g[lane] + b[lane]);
}

// ---------------- build pre-tiled/swizzled bf16 gate weights (LSTM) ----------------
// NEW layout: 4 tiles of 256 cols: chunk idx = ((nb*KT + kt)*1024 + r*4 + csw), 16B each.
// column permutation: col = hdblk*64 + g*16 + hdlo  (hd = hdblk*16 + hdlo)
__global__ void k_build_wtile(const float* __restrict__ w_ih, const float* __restrict__ w_hh,
                              ushort* __restrict__ wt, int KI, int KT) {
  int total = 4 * KT * 1024;
  for (int idx = blockIdx.x * blockDim.x + threadIdx.x; idx < total;
       idx += gridDim.x * blockDim.x) {
    int nb = idx / (KT * 1024);
    int rem = idx % (KT * 1024);
    int kt = rem / 1024;
    int q = rem % 1024;
    int r = q >> 2, csw = q & 3;
    int ch = csw ^ ((r >> 1) & 3);
    int col = nb * 256 + r;
    int hdblk = col >> 6, gg = (col >> 4) & 3, hd = hdblk * 16 + (col & 15);
    int orow = gg * HD + hd;
    int k = kt * 32 + ch * 8;
    const float* src = (k < KI) ? (w_ih + (size_t)orow * KI + k)
                                : (w_hh + (size_t)orow * HD + (k - KI));
    ushort* dst = wt + (size_t)idx * 8;
#pragma unroll
    for (int j = 0; j < 8; j++) dst[j] = f2bf(src[j]);
  }
}

__global__ void k_build_bcp(const float* __restrict__ bi, const float* __restrict__ bh,
                            float* __restrict__ bcp) {
  int col = blockIdx.x * blockDim.x + threadIdx.x;
  if (col >= 1024) return;
  int hdblk = col >> 6, gg = (col >> 4) & 3, hd = hdblk * 16 + (col & 15);
  int orow = gg * HD + hd;
  bcp[col] = bi[orow] + bh[orow];
}

// ---------------- build tiled bf16 B for generic GEMM (128-col tiles) ----------------
__global__ void k_build_btile(const float* __restrict__ B, ushort* __restrict__ bt,
                              int K, int Nn, int NB) {
  int KTb = K / 32;
  int total = NB * KTb * 512;
  for (int idx = blockIdx.x * blockDim.x + threadIdx.x; idx < total;
       idx += gridDim.x * blockDim.x) {
    int nb = idx / (KTb * 512);
    int rem = idx % (KTb * 512);
    int kt = rem / 512;
    int q = rem % 512;
    int r = q >> 2, csw = q & 3;
    int ch = csw ^ ((r >> 1) & 3);
    int col = nb * 128 + r;
    int k = kt * 32 + ch * 8;
    ushort* dst = bt + (size_t)idx * 8;
#pragma unroll
    for (int j = 0; j < 8; j++)
      dst[j] = (col < Nn) ? f2bf(B[(size_t)(k + j) * Nn + col]) : (ushort)0;
  }
}

__global__ void k_cat2(const float* __restrict__ a, const float* __restrict__ b,
                       float* __restrict__ o) {
  int i = blockIdx.x * 256 + threadIdx.x;
  if (i < 256) o[i] = a[i];
  else if (i < 512) o[i] = b[i - 256];
}

// ---------------- LSTM MFMA body: 512 threads, tile 128x256, nb in [0,4) ----------------
template <int LAYER>
__device__ __forceinline__ void lstm_body8(
    ushort* At, ushort* Bt,
    const ushort* __restrict__ a0, const ushort* __restrict__ a1,
    const ushort* __restrict__ wt, const float* __restrict__ bcp,
    float* __restrict__ cst, ushort* __restrict__ hnext, int M, int t) {
  constexpr int K = (LAYER == 0) ? 320 : 512;
  constexpr int KT = K / 32;
  constexpr int SEG0 = (LAYER == 0) ? 64 : 256;
  constexpr int LDA0 = (LAYER == 0) ? (TT * FF) : HD;
  const int tid = threadIdx.x;
  const int lane = tid & 63, wid = tid >> 6;
  const int wr = wid >> 2, wc = wid & 3;     // 2x4 waves: 64 rows x 64 cols each
  const int m0 = blockIdx.x * 128;
  const int nb = blockIdx.y;                 // [0,4): 256-col tile
  const int a0t = (LAYER == 0) ? t * FF : 0;

  f32x4 acc[4][4];
#pragma unroll
  for (int i = 0; i < 4; i++)
#pragma unroll
    for (int j = 0; j < 4; j++) acc[i][j] = (f32x4){0.f, 0.f, 0.f, 0.f};

  // A staging: one 16B chunk per thread (512 chunks)
  const int rA_ = tid >> 2, cswA = tid & 3;
  const int chA = cswA ^ ((rA_ >> 1) & 3);
  int growA = m0 + rA_;
  growA = (growA < M) ? growA : (M - 1);
  const size_t wtbase = (size_t)nb * KT * 1024;

  for (int kt = 0; kt < KT; ++kt) {
    __syncthreads();
    const int k0 = kt * 32;
    {
      int kg = k0 + chA * 8;
      const ushort* src = (kg < SEG0)
                              ? (a0 + (size_t)growA * LDA0 + a0t + kg)
                              : (a1 + (size_t)growA * HD + (kg - SEG0));
      gl16(src, &At[tid * 8]);
    }
#pragma unroll
    for (int e = 0; e < 2; e++) {
      int q = e * 512 + tid;
      gl16(wt + (wtbase + (size_t)kt * 1024 + q) * 8, &Bt[q * 8]);
    }
    __syncthreads();
    short8 af[4], bfr[4];
#pragma unroll
    for (int i = 0; i < 4; i++) {
      int rA = wr * 64 + i * 16 + (lane & 15);
      int swa = (lane >> 4) ^ ((rA >> 1) & 3);
      af[i] = *(const short8*)&At[rA * 32 + swa * 8];
      int rB = wc * 64 + i * 16 + (lane & 15);
      int swb = (lane >> 4) ^ ((rB >> 1) & 3);
      bfr[i] = *(const short8*)&Bt[rB * 32 + swb * 8];
    }
#pragma unroll
    for (int i = 0; i < 4; i++)
#pragma unroll
      for (int j = 0; j < 4; j++)
        acc[i][j] = __builtin_amdgcn_mfma_f32_16x16x32_bf16(af[i], bfr[j], acc[i][j], 0, 0, 0);
  }
  const int hdlo = lane & 15;
  const int rb = (lane >> 4) * 4;
  const int colb = nb * 256 + wc * 64;
  const float bI = bcp[colb + hdlo];
  const float bF = bcp[colb + 16 + hdlo];
  const float bG = bcp[colb + 32 + hdlo];
  const float bO = bcp[colb + 48 + hdlo];
  const int hd = (nb * 4 + wc) * 16 + hdlo;
#pragma unroll
  for (int i = 0; i < 4; i++) {
#pragma unroll
    for (int r = 0; r < 4; r++) {
      int row = m0 + wr * 64 + i * 16 + rb + r;
      if (row >= M) continue;
      float gi = acc[i][0][r] + bI;
      float gf = acc[i][1][r] + bF;
      float gg = acc[i][2][r] + bG;
      float go = acc[i][3][r] + bO;
      size_t ix = (size_t)row * HD + hd;
      float c = sigf(gf) * cst[ix] + sigf(gi) * tanhf(gg);
      cst[ix] = c;
      hnext[ix] = f2bf(sigf(go) * tanhf(c));
    }
  }
}

template <int LAYER>
__global__ __launch_bounds__(512) void k_lstm_single(
    const ushort* __restrict__ a0, const ushort* __restrict__ a1,
    const ushort* __restrict__ wt, const float* __restrict__ bcp,
    float* __restrict__ cst, ushort* __restrict__ hnext, int M, int t) {
  __shared__ ushort At[128 * 32];
  __shared__ ushort Bt[256 * 32];
  lstm_body8<LAYER>(At, Bt, a0, a1, wt, bcp, cst, hnext, M, t);
}

// blockIdx.z == 0: layer1 step t (reads h0cur,h1cur -> h1next)
// blockIdx.z == 1: layer0 step tnext (reads xln,h0cur -> h0next)
__global__ __launch_bounds__(512) void k_lstm_pair(
    const ushort* __restrict__ xln,
    const ushort* __restrict__ h0cur, const ushort* __restrict__ h1cur,
    const ushort* __restrict__ wt0, const float* __restrict__ bcp0,
    const ushort* __restrict__ wt1, const float* __restrict__ bcp1,
    float* __restrict__ c0, float* __restrict__ c1,
    ushort* __restrict__ h0next, ushort* __restrict__ h1next,
    int M, int tnext) {
  __shared__ ushort At[128 * 32];
  __shared__ ushort Bt[256 * 32];
  if (blockIdx.z == 0)
    lstm_body8<1>(At, Bt, h0cur, h1cur, wt1, bcp1, c1, h1next, M, 0);
  else
    lstm_body8<0>(At, Bt, xln, h0cur, wt0, bcp0, c0, h0next, M, tnext);
}

// ---------------- generic bf16 MFMA GEMM: C = act(A@B + bias) ----------------
template <bool BF16OUT>
__global__ __launch_bounds__(256) void k_gemm_mfma(
    const float* __restrict__ A, int lda, const ushort* __restrict__ BtG,
    const float* __restrict__ bias, void* __restrict__ Cv, int ldc,
    int M, int Nn, int K, int act) {
  const int KTb = K / 32;
  __shared__ ushort At[128 * 32];
  __shared__ ushort Bts[128 * 32];
  const int tid = threadIdx.x;
  const int lane = tid & 63, wid = tid >> 6;
  const int wr = wid >> 1, wc = wid & 1;
  const int m0 = blockIdx.x * 128;
  const int nb = blockIdx.y;

  f32x4 acc[4][4];
#pragma unroll
  for (int i = 0; i < 4; i++)
#pragma unroll
    for (int j = 0; j < 4; j++) acc[i][j] = (f32x4){0.f, 0.f, 0.f, 0.f};

  const size_t btbase = (size_t)nb * KTb * 512;

  for (int kt = 0; kt < KTb; ++kt) {
    __syncthreads();
    const int k0 = kt * 32;
#pragma unroll
    for (int e = 0; e < 2; e++) {
      int q = e * 256 + tid;
      int r = q >> 2, csw = q & 3;
      int ch = csw ^ ((r >> 1) & 3);
      int row = m0 + r;
      row = (row < M) ? row : (M - 1);
      const float* src = A + (size_t)row * lda + k0 + ch * 8;
      float4 f0 = *(const float4*)src;
      float4 f1 = *(const float4*)(src + 4);
      short8 s;
      s[0] = (short)f2bf(f0.x); s[1] = (short)f2bf(f0.y);
      s[2] = (short)f2bf(f0.z); s[3] = (short)f2bf(f0.w);
      s[4] = (short)f2bf(f1.x); s[5] = (short)f2bf(f1.y);
      s[6] = (short)f2bf(f1.z); s[7] = (short)f2bf(f1.w);
      *(short8*)&At[q * 8] = s;
      gl16(BtG + (btbase + (size_t)kt * 512 + q) * 8, &Bts[q * 8]);
    }
    __syncthreads();
    short8 af[4], bfr[4];
#pragma unroll
    for (int i = 0; i < 4; i++) {
      int rA = wr * 64 + i * 16 + (lane & 15);
      int swa = (lane >> 4) ^ ((rA >> 1) & 3);
      af[i] = *(const short8*)&At[rA * 32 + swa * 8];
      int rB = wc * 64 + i * 16 + (lane & 15);
      int swb = (lane >> 4) ^ ((rB >> 1) & 3);
      bfr[i] = *(const short8*)&Bts[rB * 32 + swb * 8];
    }
#pragma unroll
    for (int i = 0; i < 4; i++)
#pragma unroll
      for (int j = 0; j < 4; j++)
        acc[i][j] = __builtin_amdgcn_mfma_f32_16x16x32_bf16(af[i], bfr[j], acc[i][j], 0, 0, 0);
  }
  const int rb = (lane >> 4) * 4;
  const int cl = lane & 15;
#pragma unroll
  for (int i = 0; i < 4; i++) {
#pragma unroll
    for (int j = 0; j < 4; j++) {
      int col = nb * 128 + wc * 64 + j * 16 + cl;
      if (col >= Nn) continue;
      float bv = bias[col];
#pragma unroll
      for (int r = 0; r < 4; r++) {
        int row = m0 + wr * 64 + i * 16 + rb + r;
        if (row >= M) continue;
        float v = acc[i][j][r] + bv;
        if (act == ACT_RELU) v = fmaxf(v, 0.f);
        else if (act == ACT_TANH) v = tanhf(v);
        if (BF16OUT) ((ushort*)Cv)[(size_t)row * ldc + col] = f2bf(v);
        else ((float*)Cv)[(size_t)row * ldc + col] = v;
      }
    }
  }
}

// ---------------- per-row LN over 256 + optional act ----------------
__global__ __launch_bounds__(256) void k_ln_rows(
    const float* __restrict__ in, float* __restrict__ out,
    const float* __restrict__ g, const float* __restrict__ b, int rows, int act) {
  int row = blockIdx.x;
  if (row >= rows) return;
  int tid = threadIdx.x, lane = tid & 63, wv = tid >> 6;
  float v = in[(size_t)row * HD + tid];
  float s = v, s2 = v * v;
  for (int o = 32; o; o >>= 1) { s += __shfl_xor(s, o); s2 += __shfl_xor(s2, o); }
  __shared__ float ws1[4], ws2[4];
  if (lane == 0) { ws1[wv] = s; ws2[wv] = s2; }
  __syncthreads();
  float S1 = ws1[0] + ws1[1] + ws1[2] + ws1[3];
  float S2 = ws2[0] + ws2[1] + ws2[2] + ws2[3];
  float m = S1 * (1.f / 256.f);
  float var = S2 * (1.f / 256.f) - m * m;
  float r = rsqrtf(var + 1e-5f);
  float y = (v - m) * r * g[tid] + b[tid];
  if (act == 1) y = fmaxf(y, 0.f);
  else if (act == 2) y = (y > 0.f) ? y : (expf(y) - 1.f);
  out[(size_t)row * HD + tid] = y;
}

__global__ __launch_bounds__(256) void k_ln_rows_b16(
    const ushort* __restrict__ in, float* __restrict__ out,
    const float* __restrict__ g, const float* __restrict__ b, int rows, int act) {
  int row = blockIdx.x;
  if (row >= rows) return;
  int tid = threadIdx.x, lane = tid & 63, wv = tid >> 6;
  float v = bf2f(in[(size_t)row * HD + tid]);
  float s = v, s2 = v * v;
  for (int o = 32; o; o >>= 1) { s += __shfl_xor(s, o); s2 += __shfl_xor(s2, o); }
  __shared__ float ws1[4], ws2[4];
  if (lane == 0) { ws1[wv] = s; ws2[wv] = s2; }
  __syncthreads();
  float S1 = ws1[0] + ws1[1] + ws1[2] + ws1[3];
  float S2 = ws2[0] + ws2[1] + ws2[2] + ws2[3];
  float m = S1 * (1.f / 256.f);
  float var = S2 * (1.f / 256.f) - m * m;
  float r = rsqrtf(var + 1e-5f);
  float y = (v - m) * r * g[tid] + b[tid];
  if (act == 1) y = fmaxf(y, 0.f);
  else if (act == 2) y = (y > 0.f) ? y : (expf(y) - 1.f);
  out[(size_t)row * HD + tid] = y;
}

// ---------------- CSR build ----------------
__global__ void k_hist_edges(const int* __restrict__ dst, int E, int n, int* __restrict__ cnt) {
  int tot = E + n;
  for (int i = blockIdx.x * blockDim.x + threadIdx.x; i < tot; i += gridDim.x * blockDim.x) {
    int d = (i < E) ? dst[i] : (i - E);
    atomicAdd(&cnt[d], 1);
  }
}

// 3-pass exclusive scan (chunk = 1024)
__global__ void k_scan1(const int* __restrict__ cnt, int* __restrict__ ptr,
                        int* __restrict__ bsum, int n) {
  __shared__ int sm[1024];
  int tid = threadIdx.x, i = blockIdx.x * 1024 + tid;
  int v = (i < n) ? cnt[i] : 0;
  sm[tid] = v;
  __syncthreads();
  for (int off = 1; off < 1024; off <<= 1) {
    int t = (tid >= off) ? sm[tid - off] : 0;
    __syncthreads();
    sm[tid] += t;
    __syncthreads();
  }
  if (i < n) ptr[i] = sm[tid] - v;
  if (tid == 1023) bsum[blockIdx.x] = sm[1023];
}

__global__ void k_scan2(int* __restrict__ bsum, int nb) {
  __shared__ int sm[256];
  int tid = threadIdx.x;
  int v = (tid < nb) ? bsum[tid] : 0;
  sm[tid] = v;
  __syncthreads();
  for (int off = 1; off < 256; off <<= 1) {
    int t = (tid >= off) ? sm[tid - off] : 0;
    __syncthreads();
    sm[tid] += t;
    __syncthreads();
  }
  if (tid < nb) bsum[tid] = sm[tid] - v;
  if (tid == 0) bsum[nb] = sm[255];
}

__global__ void k_scan3(int* __restrict__ ptr, const int* __restrict__ bsum, int n, int nb) {
  int i = blockIdx.x * blockDim.x + threadIdx.x;
  if (i < n) ptr[i] += bsum[i >> 10];
  if (i == n) ptr[n] = bsum[nb];
}

__global__ void k_scatter_edges(const int* __restrict__ src, const int* __restrict__ dst,
                                int E, int n, const int* __restrict__ rowptr,
                                int* __restrict__ fill, int* __restrict__ esrc) {
  int tot = E + n;
  for (int i = blockIdx.x * blockDim.x + threadIdx.x; i < tot; i += gridDim.x * blockDim.x) {
    int d, s;
    if (i < E) { d = dst[i]; s = src[i]; } else { d = i - E; s = i - E; }
    int pos = rowptr[d] + atomicAdd(&fill[d], 1);
    esrc[pos] = s;
  }
}

// ---------------- sorted-batch boundaries ----------------
__global__ void k_batch_bounds(const int* __restrict__ batch, int* __restrict__ bptr,
                               int n, int S) {
  int i = blockIdx.x * blockDim.x + threadIdx.x;
  if (i > n) return;
  if (i == 0) {
    int b0 = batch[0];
    for (int s = 0; s <= b0; s++) bptr[s] = 0;
  } else if (i == n) {
    int bl = batch[n - 1];
    for (int s = bl + 1; s <= S; s++) bptr[s] = n;
  } else {
    int a = batch[i - 1], b = batch[i];
    for (int s = a + 1; s <= b; s++) bptr[s] = i;
  }
}

// ---------------- flash-style GATv2: one wave per dst node, single pass ----------------
__global__ __launch_bounds__(256) void k_gat_wave(
    const float* __restrict__ xin, const ushort* __restrict__ xlr,
    const int* __restrict__ rowptr, const int* __restrict__ esrc,
    const float* __restrict__ att, const float* __restrict__ bias,
    const float* __restrict__ lng, const float* __restrict__ lnb,
    float* __restrict__ xout, int n_nodes) {
  const int wid = threadIdx.x >> 6;
  const int nd = blockIdx.x * 4 + wid;
  if (nd >= n_nodes) return;
  const int lane = threadIdx.x & 63;
  const int eg = lane >> 4;
  const int dq = lane & 15;
  const int dbase = dq * 16;

  float xr16[16], at16[16];
  {
    const ushort* xr = xlr + (size_t)nd * 512 + 256 + dbase;
    short8 a = *(const short8*)xr;
    short8 b = *(const short8*)(xr + 8);
#pragma unroll
    for (int j = 0; j < 8; j++) { xr16[j] = bf2f((ushort)a[j]); xr16[8 + j] = bf2f((ushort)b[j]); }
    const float* ap = att + dbase;
#pragma unroll
    for (int j = 0; j < 16; j++) at16[j] = ap[j];
  }
  const int rs = rowptr[nd];
  const int deg = rowptr[nd + 1] - rs;

  float m = -3e38f, z = 0.f;
  float acc[16];
#pragma unroll
  for (int j = 0; j < 16; j++) acc[j] = 0.f;

  for (int p = eg; p < deg; p += 4) {
    int src = esrc[rs + p];
    const ushort* xl = xlr + (size_t)src * 512 + dbase;
    short8 a = *(const short8*)xl;
    short8 b = *(const short8*)(xl + 8);
    float xv[16];
#pragma unroll
    for (int j = 0; j < 8; j++) { xv[j] = bf2f((ushort)a[j]); xv[8 + j] = bf2f((ushort)b[j]); }
    float sc = 0.f;
#pragma unroll
    for (int j = 0; j < 16; j++) {
      float v = xv[j] + xr16[j];
      v = (v > 0.f) ? v : 0.2f * v;  // leaky_relu 0.2
      sc = fmaf(v, at16[j], sc);
    }
    sc += __shfl_xor(sc, 1);
    sc += __shfl_xor(sc, 2);
    if (sc > m + 8.f) {
      float r = __expf(m - sc);
      z *= r;
#pragma unroll
      for (int j = 0; j < 16; j++) acc[j] *= r;
      m = sc;
    }
    float w = __expf(sc - m);
    z += w;
#pragma unroll
    for (int j = 0; j < 16; j++) acc[j] = fmaf(w, xv[j], acc[j]);
  }
  float mt = fmaxf(m, __shfl_xor(m, 16));
  mt = fmaxf(mt, __shfl_xor(mt, 32));
  float r = __expf(m - mt);
  z *= r;
  z += __shfl_xor(z, 16);
  z += __shfl_xor(z, 32);
#pragma unroll
  for (int j = 0; j < 16; j++) {
    float a = acc[j] * r;
    a += __shfl_xor(a, 16);
    a += __shfl_xor(a, 32);
    acc[j] = a;
  }
  float zinv = 1.f / (z + 1e-16f);
  const float* xi = xin + (size_t)nd * 256 + dbase;
  const float* bp = bias + dbase;
  float v16[16];
  float s1 = 0.f, s2 = 0.f;
#pragma unroll
  for (int j = 0; j < 16; j++) {
    float v = acc[j] * zinv + bp[j] + xi[j];
    v16[j] = v;
    s1 += v;
    s2 += v * v;
  }
  for (int o = 32; o; o >>= 1) { s1 += __shfl_xor(s1, o); s2 += __shfl_xor(s2, o); }
  float mean = s1 * (1.f / 1024.f);
  float var = s2 * (1.f / 1024.f) - mean * mean;
  float rstd = rsqrtf(var + 1e-5f);
  const float* gp = lng + dbase + eg * 4;
  const float* bb = lnb + dbase + eg * 4;
  float4 o4;
#pragma unroll
  for (int jj = 0; jj < 4; jj++) {
    float y = (v16[eg * 4 + jj] - mean) * rstd * gp[jj] + bb[jj];
    y = (y > 0.f) ? y : (expf(y) - 1.f);
    (&o4.x)[jj] = y;
  }
  *(float4*)(xout + (size_t)nd * 256 + dbase + eg * 4) = o4;
}

// ---------------- small row-dot heads ----------------
__global__ void k_rowdot(const float* __restrict__ in, const float* __restrict__ W,
                         const float* __restrict__ bias, float* __restrict__ out,
                         int rows, int K, int OC, int act) {
  int row = blockIdx.x * 4 + (threadIdx.x >> 6);
  if (row >= rows) return;
  int lane = threadIdx.x & 63;
  for (int o = 0; o < OC; o++) {
    float s = 0.f;
    for (int k = lane; k < K; k += 64) s += in[(size_t)row * K + k] * W[(size_t)k * OC + o];
    for (int off = 32; off; off >>= 1) s += __shfl_xor(s, off);
    if (lane == 0) {
      float v = s + bias[o];
      if (act == 3) v = tanhf(v) * 0.1f;
      else if (act == 4) v = 1.f / (1.f + expf(-v));
      out[(size_t)row * OC + o] = v;
    }
  }
}

// ---------------- sector attention pooling ----------------
__global__ __launch_bounds__(256) void k_sector_pool(
    const float* __restrict__ x, const float* __restrict__ sc,
    const int* __restrict__ bptr, float* __restrict__ se, int S) {
  const int s = blockIdx.x, tid = threadIdx.x, lane = tid & 63, wv = tid >> 6;
  const int rs = bptr[s], re = bptr[s + 1];
  const int cnt = re - rs;
  __shared__ float r1[4], r2[4], wch[256];
  float mx = -3e38f;
  for (int i = rs + tid; i < re; i += 256) mx = fmaxf(mx, sc[i]);
  for (int o = 32; o; o >>= 1) mx = fmaxf(mx, __shfl_xor(mx, o));
  if (lane == 0) r1[wv] = mx;
  __syncthreads();
  float m = fmaxf(fmaxf(r1[0], r1[1]), fmaxf(r1[2], r1[3]));
  if (cnt == 0) m = 0.f;
  float z = 0.f;
  for (int i = rs + tid; i < re; i += 256) z += expf(sc[i] - m);
  for (int o = 32; o; o >>= 1) z += __shfl_xor(z, o);
  if (lane == 0) r2[wv] = z;
  __syncthreads();
  float zinv = 1.f / (r2[0] + r2[1] + r2[2] + r2[3] + 1e-16f);
  float acc = 0.f;
  for (int base = rs; base < re; base += 256) {
    int i = base + tid;
    wch[tid] = (i < re) ? expf(sc[i] - m) * zinv : 0.f;
    __syncthreads();
    int lim = re - base; if (lim > 256) lim = 256;
    for (int q = 0; q < lim; q++) acc += wch[q] * x[(size_t)(base + q) * HD + tid];
    __syncthreads();
  }
  se[(size_t)s * HD + tid] = acc / fmaxf((float)cnt, 1.f);
}

// ---------------- comb = [x | se[batch]] ----------------
__global__ void k_comb(const float* __restrict__ x, const float* __restrict__ se,
                       const int* __restrict__ batch, float* __restrict__ comb, int n) {
  int total = n * 512;
  for (int i = blockIdx.x * blockDim.x + threadIdx.x; i < total; i += gridDim.x * blockDim.x) {
    int row = i >> 9, col = i & 511;
    comb[i] = (col < HD) ? x[(size_t)row * HD + col]
                         : se[(size_t)batch[row] * HD + (col - HD)];
  }
}

extern "C" void kernel_launch(void* const* d_in, const int* in_sizes, int n_in,
                              void* d_out, int out_size, void* d_ws, size_t ws_size,
                              hipStream_t stream) {
  const float* x_stock   = (const float*)d_in[0];
  const int*   ei_stock  = (const int*)d_in[1];
  const int*   batch     = (const int*)d_in[2];
  const int*   ei_sector = (const int*)d_in[4];
  const float* ln_feat_g = (const float*)d_in[5];
  const float* ln_feat_b = (const float*)d_in[6];
  const float* w_ih0 = (const float*)d_in[7];
  const float* w_hh0 = (const float*)d_in[8];
  const float* b_ih0 = (const float*)d_in[9];
  const float* b_hh0 = (const float*)d_in[10];
  const float* w_ih1 = (const float*)d_in[11];
  const float* w_hh1 = (const float*)d_in[12];
  const float* b_ih1 = (const float*)d_in[13];
  const float* b_hh1 = (const float*)d_in[14];
  const float* ln_t_g = (const float*)d_in[15];
  const float* ln_t_b = (const float*)d_in[16];
  const float* W_in = (const float*)d_in[17];
  const float* b_in = (const float*)d_in[18];
  const float* stock_Wl = (const float*)d_in[19];
  const float* stock_bl = (const float*)d_in[20];
  const float* stock_Wr = (const float*)d_in[21];
  const float* stock_br = (const float*)d_in[22];
  const float* stock_att = (const float*)d_in[23];
  const float* stock_bias = (const float*)d_in[24];
  const float* stock_g = (const float*)d_in[25];
  const float* stock_b = (const float*)d_in[26];
  const float* sector_Wl = (const float*)d_in[27];
  const float* sector_bl = (const float*)d_in[28];
  const float* sector_Wr = (const float*)d_in[29];
  const float* sector_br = (const float*)d_in[30];
  const float* sector_att = (const float*)d_in[31];
  const float* sector_bias = (const float*)d_in[32];
  const float* sector_g = (const float*)d_in[33];
  const float* sector_b = (const float*)d_in[34];
  const float* Wa1 = (const float*)d_in[35];
  const float* ba1 = (const float*)d_in[36];
  const float* Wa2 = (const float*)d_in[37];
  const float* ba2 = (const float*)d_in[38];
  const float* Wf  = (const float*)d_in[39];
  const float* bf  = (const float*)d_in[40];
  const float* gf  = (const float*)d_in[41];
  const float* bef = (const float*)d_in[42];
  const float* W_regf = (const float*)d_in[43];
  const float* b_regf = (const float*)d_in[44];
  const float* g_regf = (const float*)d_in[45];
  const float* be_regf = (const float*)d_in[46];
  const float* W_clff = (const float*)d_in[47];
  const float* b_clff = (const float*)d_in[48];
  const float* g_clff = (const float*)d_in[49];
  const float* be_clff = (const float*)d_in[50];
  const float* W_rnkf = (const float*)d_in[51];
  const float* b_rnkf = (const float*)d_in[52];
  const float* g_rnkf = (const float*)d_in[53];
  const float* be_rnkf = (const float*)d_in[54];
  const float* Wr1 = (const float*)d_in[55];
  const float* br1 = (const float*)d_in[56];
  const float* Wr2 = (const float*)d_in[57];
  const float* br2 = (const float*)d_in[58];
  const float* Wr3 = (const float*)d_in[59];
  const float* br3 = (const float*)d_in[60];
  const float* Wc1 = (const float*)d_in[61];
  const float* bc1 = (const float*)d_in[62];
  const float* Wc2 = (const float*)d_in[63];
  const float* bc2 = (const float*)d_in[64];
  const float* Wk1 = (const float*)d_in[65];
  const float* bk1 = (const float*)d_in[66];
  const float* Wk2 = (const float*)d_in[67];
  const float* bk2 = (const float*)d_in[68];

  const int N  = in_sizes[0] / (TT * FF);
  const int E  = in_sizes[1] / 2;
  const int S  = in_sizes[3] / HD;
  const int ES = in_sizes[4] / 2;
  const int Ep = E + N, ESp = ES + S;
  const int NT = N * TT;
  const int KT0 = 10, KT1 = 16;

  char* wsb = (char*)d_ws;
  size_t off = 0;
  auto alloc = [&](size_t bytes) -> char* {
    char* p = wsb + off;
    off += (bytes + 255) & ~(size_t)255;
    return p;
  };
  // zero-init group (h/c states)
  ushort* h0a = (ushort*)alloc((size_t)N * HD * 2);
  ushort* h1a = (ushort*)alloc((size_t)N * HD * 2);
  float*  c0  = (float*)alloc((size_t)N * HD * 4);
  float*  c1  = (float*)alloc((size_t)N * HD * 4);
  size_t zf_bytes = off;
  ushort* h0b = (ushort*)alloc((size_t)N * HD * 2);
  ushort* h1b = (ushort*)alloc((size_t)N * HD * 2);
  ushort* wt0 = (ushort*)alloc((size_t)4 * KT0 * 1024 * 16);
  ushort* wt1 = (ushort*)alloc((size_t)4 * KT1 * 1024 * 16);
  float* bcp0 = (float*)alloc(1024 * 4);
  float* bcp1 = (float*)alloc(1024 * 4);
  float* xA  = (float*)alloc((size_t)N * HD * 4);
  float* xB  = (float*)alloc((size_t)N * HD * 4);
  char*  xlr_raw = alloc((size_t)N * 512 * 4);          // bf16 xl|xr; later f32 comb
  float* scbuf = (float*)alloc((size_t)N * 128 * 4);    // hA buffer
  char*  selr_raw = alloc((size_t)S * 512 * 4);
  float* seA  = (float*)alloc((size_t)S * HD * 4);
  float* seB  = (float*)alloc((size_t)S * HD * 4);
  float* scpool = (float*)alloc((size_t)N * 4);
  char* bigraw = alloc((size_t)N * TT * FF * 2);
  ushort* xln    = (ushort*)bigraw;
  float*  tmpY   = (float*)bigraw;
  float*  headbuf = (float*)(bigraw + (size_t)N * HD * 4);
  // tiled bf16 weights (generic GEMM, 128-col tiles)
  auto alloc_bt = [&](int K, int Nn) -> ushort* {
    int NB = (Nn + 127) / 128;
    return (ushort*)alloc((size_t)NB * (K / 32) * 512 * 16);
  };
  ushort* bt_Win  = alloc_bt(256, 256);
  ushort* bt_slr0 = alloc_bt(256, 512);   // [Wl|Wr] stock layer0
  ushort* bt_slr1 = alloc_bt(256, 512);
  ushort* bt_elr0 = alloc_bt(256, 512);
  ushort* bt_elr1 = alloc_bt(256, 512);
  ushort* bt_Wa1  = alloc_bt(256, 128);
  ushort* bt_Wf   = alloc_bt(512, 256);
  ushort* bt_Wreg = alloc_bt(256, 256);
  ushort* bt_Wclf = alloc_bt(256, 256);
  ushort* bt_Wrnk = alloc_bt(256, 256);
  ushort* bt_Wr1  = alloc_bt(256, 128);
  ushort* bt_Wr2  = alloc_bt(128, 64);
  ushort* bt_Wc1  = alloc_bt(256, 128);
  ushort* bt_Wk1  = alloc_bt(256, 128);
  float* bc_slr0 = (float*)alloc(512 * 4);
  float* bc_slr1 = (float*)alloc(512 * 4);
  float* bc_elr0 = (float*)alloc(512 * 4);
  float* bc_elr1 = (float*)alloc(512 * 4);
  size_t zi_start = off;
  int* cnt   = (int*)alloc((size_t)(N + 1) * 4);
  int* fill  = (int*)alloc((size_t)N * 4);
  int* cntS  = (int*)alloc((size_t)(S + 1) * 4);
  int* fillS = (int*)alloc((size_t)S * 4);
  size_t zi_bytes = off - zi_start;
  int* rowptr = (int*)alloc((size_t)(N + 1) * 4);
  int* esrc   = (int*)alloc((size_t)Ep * 4);
  int* rptrS  = (int*)alloc((size_t)(S + 1) * 4);
  int* esrcS  = (int*)alloc((size_t)ESp * 4);
  int* bptr   = (int*)alloc((size_t)(S + 1) * 4);
  int* bsum1  = (int*)alloc(64 * 4);
  int* bsum2  = (int*)alloc(64 * 4);

  ushort* xlr_b = (ushort*)xlr_raw;
  float*  comb  = (float*)xlr_raw;
  ushort* selr_b = (ushort*)selr_raw;
  float* hA   = scbuf;
  float* t128 = tmpY;
  float* t64  = tmpY + (size_t)N * 128;
  float* out_ret = (float*)d_out;
  float* out_mov = out_ret + N;
  float* out_rnk = out_ret + 3 * (size_t)N;
  float* out_c   = out_ret + 4 * (size_t)N;

  hipMemsetAsync(d_ws, 0, zf_bytes, stream);
  hipMemsetAsync(wsb + zi_start, 0, zi_bytes, stream);

  auto build_bt = [&](const float* W, ushort* bt, int K, int Nn) {
    int NB = (Nn + 127) / 128;
    int total = NB * (K / 32) * 512;
    k_build_btile<<<dim3((total + 255) / 256), dim3(256), 0, stream>>>(W, bt, K, Nn, NB);
  };
  auto gemm_f = [&](const float* A, int lda, const ushort* bt, const float* bias,
                    float* C, int ldc, int M, int Nn, int K, int act) {
    dim3 g((M + 127) / 128, (Nn + 127) / 128);
    k_gemm_mfma<false><<<g, dim3(256), 0, stream>>>(A, lda, bt, bias, C, ldc, M, Nn, K, act);
  };
  auto gemm_b = [&](const float* A, int lda, const ushort* bt, const float* bias,
                    ushort* C, int ldc, int M, int Nn, int K, int act) {
    dim3 g((M + 127) / 128, (Nn + 127) / 128);
    k_gemm_mfma<true><<<g, dim3(256), 0, stream>>>(A, lda, bt, bias, C, ldc, M, Nn, K, act);
  };
  const int TILE2 = 2 * 8 * 512 * 8;  // elems per 2-tile (Nn=256) btile block

  // 1. feature-LN + bf16 convert; prebuild all tiled bf16 weights
  k_lncvt<<<dim3((NT + 3) / 4), dim3(256), 0, stream>>>(x_stock, ln_feat_g, ln_feat_b, xln, NT);
  k_build_wtile<<<dim3((4 * KT0 * 1024 + 255) / 256), dim3(256), 0, stream>>>(w_ih0, w_hh0, wt0, FF, KT0);
  k_build_wtile<<<dim3((4 * KT1 * 1024 + 255) / 256), dim3(256), 0, stream>>>(w_ih1, w_hh1, wt1, HD, KT1);
  k_build_bcp<<<dim3(4), dim3(256), 0, stream>>>(b_ih0, b_hh0, bcp0);
  k_build_bcp<<<dim3(4), dim3(256), 0, stream>>>(b_ih1, b_hh1, bcp1);
  build_bt(W_in, bt_Win, 256, 256);
  build_bt(stock_Wl, bt_slr0, 256, 256);
  build_bt(stock_Wr, bt_slr0 + TILE2, 256, 256);
  build_bt(stock_Wl + HD * HD, bt_slr1, 256, 256);
  build_bt(stock_Wr + HD * HD, bt_slr1 + TILE2, 256, 256);
  build_bt(sector_Wl, bt_elr0, 256, 256);
  build_bt(sector_Wr, bt_elr0 + TILE2, 256, 256);
  build_bt(sector_Wl + HD * HD, bt_elr1, 256, 256);
  build_bt(sector_Wr + HD * HD, bt_elr1 + TILE2, 256, 256);
  k_cat2<<<dim3(2), dim3(256), 0, stream>>>(stock_bl, stock_br, bc_slr0);
  k_cat2<<<dim3(2), dim3(256), 0, stream>>>(stock_bl + HD, stock_br + HD, bc_slr1);
  k_cat2<<<dim3(2), dim3(256), 0, stream>>>(sector_bl, sector_br, bc_elr0);
  k_cat2<<<dim3(2), dim3(256), 0, stream>>>(sector_bl + HD, sector_br + HD, bc_elr1);
  build_bt(Wa1, bt_Wa1, 256, 128);
  build_bt(Wf, bt_Wf, 512, 256);
  build_bt(W_regf, bt_Wreg, 256, 256);
  build_bt(W_clff, bt_Wclf, 256, 256);
  build_bt(W_rnkf, bt_Wrnk, 256, 256);
  build_bt(Wr1, bt_Wr1, 256, 128);
  build_bt(Wr2, bt_Wr2, 128, 64);
  build_bt(Wc1, bt_Wc1, 256, 128);
  build_bt(Wk1, bt_Wk1, 256, 128);

  // 2. LSTM via MFMA: L0[0]; 19x pair(L1[t] || L0[t+1]); L1[19]
  {
    const int MB = (N + 127) / 128;
    ushort *h0c = h0a, *h0n = h0b, *h1c = h1a, *h1n = h1b;
    k_lstm_single<0><<<dim3(MB, 4), dim3(512), 0, stream>>>(xln, h0c, wt0, bcp0, c0, h0n, N, 0);
    { ushort* tp = h0c; h0c = h0n; h0n = tp; }   // h0c = h0[0]
    for (int t = 0; t < TT - 1; t++) {
      k_lstm_pair<<<dim3(MB, 4, 2), dim3(512), 0, stream>>>(
          xln, h0c, h1c, wt0, bcp0, wt1, bcp1, c0, c1, h0n, h1n, N, t + 1);
      ushort* tp = h0c; h0c = h0n; h0n = tp;     // h0c = h0[t+1]
      tp = h1c; h1c = h1n; h1n = tp;             // h1c = h1[t]
    }
    k_lstm_single<1><<<dim3(MB, 4), dim3(512), 0, stream>>>(h0c, h1c, wt1, bcp1, c1, h1n, N, 0);
    k_ln_rows_b16<<<dim3(N), dim3(256), 0, stream>>>(h1n, tmpY, ln_t_g, ln_t_b, N, 0);
  }
  gemm_f(tmpY, HD, bt_Win, b_in, xA, HD, N, 256, 256, ACT_NONE);

  // 3. stock CSR (with self loops)
  {
    int nb1 = (N + 1023) / 1024;
    k_hist_edges<<<dim3(2048), dim3(256), 0, stream>>>(ei_stock + E, E, N, cnt);
    k_scan1<<<dim3(nb1), dim3(1024), 0, stream>>>(cnt, rowptr, bsum1, N);
    k_scan2<<<dim3(1), dim3(256), 0, stream>>>(bsum1, nb1);
    k_scan3<<<dim3((N + 256) / 256), dim3(256), 0, stream>>>(rowptr, bsum1, N, nb1);
    k_scatter_edges<<<dim3(2048), dim3(256), 0, stream>>>(ei_stock, ei_stock + E, E, N,
                                                          rowptr, fill, esrc);
  }
  // 4. stock GAT x2 (fused [Wl|Wr] projection)
  float* xc = xA; float* xn = xB;
  const ushort* btS[2] = {bt_slr0, bt_slr1};
  const float*  bcS[2] = {bc_slr0, bc_slr1};
  for (int l = 0; l < 2; l++) {
    const float* at = stock_att + (size_t)l * HD;
    const float* bi = stock_bias + (size_t)l * HD;
    const float* lg = stock_g + (size_t)l * HD;
    const float* lb = stock_b + (size_t)l * HD;
    gemm_b(xc, HD, btS[l], bcS[l], xlr_b, 512, N, 512, 256, ACT_NONE);
    k_gat_wave<<<dim3((N + 3) / 4), dim3(256), 0, stream>>>(xc, xlr_b, rowptr, esrc,
                                                            at, bi, lg, lb, xn, N);
    float* tp = xc; xc = xn; xn = tp;
  }
  // 5. attention pooling to sectors (bptr from sorted batch, no atomics)
  gemm_f(xc, HD, bt_Wa1, ba1, hA, 128, N, 128, 256, ACT_TANH);
  k_rowdot<<<dim3((N + 3) / 4), dim3(256), 0, stream>>>(hA, Wa2, ba2, scpool, N, 128, 1, 0);
  k_batch_bounds<<<dim3((N + 256) / 256), dim3(256), 0, stream>>>(batch, bptr, N, S);
  k_sector_pool<<<dim3(S), dim3(256), 0, stream>>>(xc, scpool, bptr, seA, S);
  // 6. sector CSR + GAT x2
  {
    int nb1 = (S + 1023) / 1024;
    k_hist_edges<<<dim3(64), dim3(256), 0, stream>>>(ei_sector + ES, ES, S, cntS);
    k_scan1<<<dim3(nb1), dim3(1024), 0, stream>>>(cntS, rptrS, bsum2, S);
    k_scan2<<<dim3(1), dim3(256), 0, stream>>>(bsum2, nb1);
    k_scan3<<<dim3((S + 256) / 256), dim3(256), 0, stream>>>(rptrS, bsum2, S, nb1);
    k_scatter_edges<<<dim3(64), dim3(256), 0, stream>>>(ei_sector, ei_sector + ES, ES, S,
                                                        rptrS, fillS, esrcS);
  }
  float* sec = seA; float* sen = seB;
  const ushort* btE[2] = {bt_elr0, bt_elr1};
  const float*  bcE[2] = {bc_elr0, bc_elr1};
  for (int l = 0; l < 2; l++) {
    const float* at = sector_att + (size_t)l * HD;
    const float* bi = sector_bias + (size_t)l * HD;
    const float* lg = sector_g + (size_t)l * HD;
    const float* lb = sector_b + (size_t)l * HD;
    gemm_b(sec, HD, btE[l], bcE[l], selr_b, 512, S, 512, 256, ACT_NONE);
    k_gat_wave<<<dim3((S + 3) / 4), dim3(256), 0, stream>>>(sec, selr_b, rptrS, esrcS,
                                                            at, bi, lg, lb, sen, S);
    float* tp = sec; sec = sen; sen = tp;
  }
  // 7. fusion -> c (output)
  k_comb<<<dim3(4096), dim3(256), 0, stream>>>(xc, sec, batch, comb, N);
  gemm_f(comb, 512, bt_Wf, bf, tmpY, HD, N, 256, 512, ACT_NONE);
  k_ln_rows<<<dim3(N), dim3(256), 0, stream>>>(tmpY, out_c, gf, bef, N, 2);
  // 8a. regression head
  gemm_f(out_c, HD, bt_Wreg, b_regf, tmpY, HD, N, 256, 256, ACT_NONE);
  k_ln_rows<<<dim3(N), dim3(256), 0, stream>>>(tmpY, headbuf, g_regf, be_regf, N, 1);
  gemm_f(headbuf, HD, bt_Wr1, br1, t128, 128, N, 128, 256, ACT_RELU);
  gemm_f(t128, 128, bt_Wr2, br2, t64, 64, N, 64, 128, ACT_RELU);
  k_rowdot<<<dim3((N + 3) / 4), dim3(256), 0, stream>>>(t64, Wr3, br3, out_ret, N, 64, 1, 3);
  // 8b. classification head
  gemm_f(out_c, HD, bt_Wclf, b_clff, tmpY, HD, N, 256, 256, ACT_NONE);
  k_ln_rows<<<dim3(N), dim3(256), 0, stream>>>(tmpY, headbuf, g_clff, be_clff, N, 1);
  gemm_f(headbuf, HD, bt_Wc1, bc1, t128, 128, N, 128, 256, ACT_RELU);
  k_rowdot<<<dim3((N + 3) / 4), dim3(256), 0, stream>>>(t128, Wc2, bc2, out_mov, N, 128, 2, 0);
  // 8c. ranking head
  gemm_f(out_c, HD, bt_Wrnk, b_rnkf, tmpY, HD, N, 256, 256, ACT_NONE);
  k_ln_rows<<<dim3(N), dim3(256), 0, stream>>>(tmpY, headbuf, g_rnkf, be_rnkf, N, 1);
  gemm_f(headbuf, HD, bt_Wk1, bk1, t128, 128, N, 128, 256, ACT_RELU);
  k_rowdot<<<dim3((N + 3) / 4), dim3(256), 0, stream>>>(t128, Wk2, bk2, out_rnk, N, 128, 1, 4);
}